// Round 11
// baseline (211.003 us; speedup 1.0000x reference)
//
#include <hip/hip_runtime.h>

typedef _Float16 f16;
typedef _Float16 f16x4 __attribute__((ext_vector_type(4)));
typedef _Float16 f16x8 __attribute__((ext_vector_type(8)));
typedef float f32x4 __attribute__((ext_vector_type(4)));

// ---------------------------------------------------------------- weight repacks (MFMA fragments)
// w1c (conv1): [mt2][lane64][8] ; co = mt*16+(l&15) (<24), K COLUMN-major taps: k -> (kw=k/5, kh=k%5)
__global__ __launch_bounds__(256) void repack1m_k(f16* __restrict__ dst, const float* __restrict__ src){
  int idx = blockIdx.x*256 + threadIdx.x;
  if (idx >= 1024) return;
  int i = idx & 7, l = (idx >> 3) & 63, mt = idx >> 9;
  int co = mt*16 + (l & 15);
  int k = (l >> 4)*8 + i;
  f16 v = (f16)0.0f;
  if (co < 24 && k < 25){
    int kw = k / 5, kh = k - kw*5;
    v = (f16)src[co*25 + kh*5 + kw];
  }
  dst[idx] = v;
}
// w2c (conv2, K-packed): [s19][mt3][lane64][8] ; k<600: tap=k/24, ci=k%24
__global__ __launch_bounds__(256) void repack2c_k(f16* __restrict__ dst, const float* __restrict__ src){
  for (int idx = blockIdx.x*256 + threadIdx.x; idx < 29184; idx += gridDim.x*256){
    int i = idx & 7, l = (idx >> 3) & 63, rest = idx >> 9;
    int mt = rest % 3, s = rest / 3;
    int co = mt*16 + (l & 15);
    int k = s*32 + (l >> 4)*8 + i;
    f16 v = (f16)0.0f;
    if (co < 36 && k < 600){
      int tap = k / 24, ci = k - tap*24;
      v = (f16)src[(co*24 + ci)*25 + tap];
    }
    dst[idx] = v;
  }
}
// w3m: [s29][mt3][lane64][8]
__global__ __launch_bounds__(256) void repack3m_k(f16* __restrict__ dst, const float* __restrict__ src){
  for (int idx = blockIdx.x*256 + threadIdx.x; idx < 44544; idx += gridDim.x*256){
    int i = idx & 7, l = (idx >> 3) & 63, rest = idx >> 9;
    int mt = rest % 3, s = rest / 3;
    int co = mt*16 + (l & 15);
    f16 v = (f16)0.0f;
    if (s < 25){
      int ci = (l >> 4)*8 + i;
      v = (f16)src[(co*36 + ci)*25 + s];
    } else {
      int ke = (s - 25)*32 + (l >> 4)*8 + i;
      if (ke < 100){
        int p = ke >> 2, ci = 32 + (ke & 3);
        v = (f16)src[(co*36 + ci)*25 + p];
      }
    }
    dst[idx] = v;
  }
}
// w4m: [s14][mt4][lane64][8]
__global__ __launch_bounds__(256) void repack4m_k(f16* __restrict__ dst, const float* __restrict__ src){
  for (int idx = blockIdx.x*256 + threadIdx.x; idx < 28672; idx += gridDim.x*256){
    int i = idx & 7, l = (idx >> 3) & 63, rest = idx >> 9;
    int mt = rest & 3, s = rest >> 2;
    int co = mt*16 + (l & 15);
    int k = s*32 + (l >> 4)*8 + i;
    f16 v = (f16)0.0f;
    if (k < 432){
      int pos = k / 48, ci = k - pos*48;
      v = (f16)src[(co*48 + ci)*9 + pos];
    }
    dst[idx] = v;
  }
}
// w1m (fc1): B-fragments [s160][nt7][lane64][8]
__global__ __launch_bounds__(256) void repackfc1_k(f16* __restrict__ dst, const float* __restrict__ src){
  for (int t = blockIdx.x*256 + threadIdx.x; t < 71680; t += gridDim.x*256){
    int l = t & 63, rest = t >> 6;
    int nt = rest % 7, s = rest / 7;
    int j = nt*16 + (l & 15);
    int kb = s*32 + (l >> 4)*8;
    union { f16 h[8]; f16x8 v; } pk;
    #pragma unroll
    for (int i=0;i<8;++i){
      int k = kb + i;
      int row = (k & 63)*80 + (k >> 6);
      pk.h[i] = (j < 100) ? (f16)src[(size_t)row*100 + j] : (f16)0.0f;
    }
    *(f16x8*)(dst + (size_t)t*8) = pk.v;
  }
}

// ---------------------------------------------------------------- conv1+conv2 fused (both MFMA, 16-row tiles)
// rgb (B,15000) f32 [w75][h200] -> a2 NHWC (Bc,47,16,36). grid=Bc*3 (oh tiles of 16), block=256 (4 waves).
// Phase 0: stage+binarize rgb slab [w75][hh76] (h0 = 64t, 73 rows used).
// Phase 1: conv1 MFMA -> xt [par2][rr35][colp18][ci24] (1260 px = 79 N-tiles over 4 waves).
// Phase 2: conv2 MFMA K-packed (19 steps), wave wv -> oh_l {4wv..4wv+3}.
__global__ __launch_bounds__(256) void conv12_k(const float* __restrict__ rgb, const f16* __restrict__ w1m,
                                                const float* __restrict__ b1, const f16* __restrict__ w2c,
                                                const float* __restrict__ b2, f16* __restrict__ a2, int ib){
  __shared__ __align__(16) f16 xb[75*76];          // 11400 B
  __shared__ __align__(16) f16 xt[2*35*18*24];     // 60480 B
  const int tid = threadIdx.x, bx = blockIdx.x;
  const int i = bx / 3, t = bx - i*3;
  const int h0 = t*64, oh0 = t*16;
  const float* img = rgb + (size_t)(ib + i)*15000;
  // phase 0: vectorized binarize staging (75 w x 19 h4-groups)
  for (int idx = tid; idx < 1425; idx += 256){
    int w = idx / 19, h4 = idx - w*19;
    int hh = h4*4, h = h0 + hh;
    union { f16 hv[4]; uint2 u; } pk;
    if (h < 200){
      float4 v = *(const float4*)(img + w*200 + h);
      pk.hv[0] = (v.x > 0.f) ? (f16)1.0f : (f16)0.0f;
      pk.hv[1] = (v.y > 0.f) ? (f16)1.0f : (f16)0.0f;
      pk.hv[2] = (v.z > 0.f) ? (f16)1.0f : (f16)0.0f;
      pk.hv[3] = (v.w > 0.f) ? (f16)1.0f : (f16)0.0f;
    } else {
      pk.u.x = 0u; pk.u.y = 0u;
    }
    *(uint2*)(xb + w*76 + hh) = pk.u;
  }
  __syncthreads();
  const int wv = tid >> 6, lane = tid & 63;
  const int jgrp = lane >> 4, npx = lane & 15;
  // ---- phase 1: conv1 MFMA into xt (35 rows x 36 cols)
  {
    f16x8 a1f0 = *(const f16x8*)(w1m + (size_t)lane*8);
    f16x8 a1f1 = *(const f16x8*)(w1m + (size_t)(64 + lane)*8);
    int koff[8];
    #pragma unroll
    for (int ii=0; ii<8; ++ii){
      int k = jgrp*8 + ii;
      if (k >= 25) k = 0;
      int kw = k / 5, kh = k - kw*5;
      koff[ii] = kw*76 + kh;
    }
    f32x4 bv0, bv1;
    #pragma unroll
    for (int reg=0; reg<4; ++reg){
      int c0 = jgrp*4 + reg;
      int c1 = 16 + jgrp*4 + reg;
      bv0[reg] = b1[c0];
      bv1[reg] = (c1 < 24) ? b1[c1] : 0.f;
    }
    for (int q=0; q<20; ++q){
      int nt = wv + 4*q;
      if (nt > 78) break;
      int pxt = nt*16 + npx;
      int px = (pxt > 1259) ? 1259 : pxt;
      int rr = px/36, ow = px - rr*36;
      const f16* gp = xb + 2*(ow*76 + rr);
      union { f16 h[8]; f16x8 v; } bq;
      #pragma unroll
      for (int ii=0; ii<8; ++ii) bq.h[ii] = gp[koff[ii]];
      f32x4 c0 = __builtin_amdgcn_mfma_f32_16x16x32_f16(a1f0, bq.v, bv0, 0, 0, 0);
      f32x4 c1 = __builtin_amdgcn_mfma_f32_16x16x32_f16(a1f1, bq.v, bv1, 0, 0, 0);
      if (pxt <= 1259){
        f16* dst = xt + (((ow & 1)*35 + rr)*18 + (ow >> 1))*24;
        union { f16 h[4]; uint2 q2; } pk;
        #pragma unroll
        for (int reg=0; reg<4; ++reg){ float r = c0[reg]; if (r<0.f) r=0.f; pk.h[reg]=(f16)r; }
        *(uint2*)(dst + jgrp*4) = pk.q2;
        if (jgrp < 2){
          #pragma unroll
          for (int reg=0; reg<4; ++reg){ float r = c1[reg]; if (r<0.f) r=0.f; pk.h[reg]=(f16)r; }
          *(uint2*)(dst + 16 + jgrp*4) = pk.q2;
        }
      }
    }
  }
  __syncthreads();
  // ---- phase 2: conv2 MFMA, K-packed (19 steps of 32 over k = tap*24 + ci)
  int baddr[19];
  #pragma unroll
  for (int s=0; s<19; ++s){
    int m = s*4 + jgrp;
    int tap = m / 3, r3 = m - tap*3;
    if (m >= 75){ tap = 24; r3 = 0; }
    int kh = tap / 5, kw = tap - kh*5;
    int par = kw & 1, kws = kw >> 1;
    baddr[s] = ((par*35 + kh)*18 + npx + kws)*24 + r3*8;
  }
  f32x4 acc2[3][4];
  #pragma unroll
  for (int mt=0; mt<3; ++mt){
    f32x4 bv;
    #pragma unroll
    for (int reg=0; reg<4; ++reg){
      int co = mt*16 + jgrp*4 + reg;
      bv[reg] = (co < 36) ? b2[co] : 0.0f;
    }
    #pragma unroll
    for (int u=0; u<4; ++u) acc2[mt][u] = bv;
  }
  const f16* agl = w2c + (size_t)lane*8;
  const int rowo = 8*wv*432;
  #pragma unroll
  for (int s=0; s<19; ++s){
    f16x8 af[3];
    #pragma unroll
    for (int mt=0; mt<3; ++mt)
      af[mt] = *(const f16x8*)(agl + (size_t)(s*3 + mt)*512);
    const f16* bb0 = xt + baddr[s] + rowo;
    f16x8 bf[4];
    #pragma unroll
    for (int u=0; u<4; ++u)
      bf[u] = *(const f16x8*)(bb0 + 2*u*432);
    #pragma unroll
    for (int mt=0; mt<3; ++mt)
      #pragma unroll
      for (int u=0; u<4; ++u)
        acc2[mt][u] = __builtin_amdgcn_mfma_f32_16x16x32_f16(af[mt], bf[u], acc2[mt][u], 0, 0, 0);
  }
  #pragma unroll
  for (int u=0; u<4; ++u){
    const int oh = oh0 + 4*wv + u;
    if (oh >= 47) continue;
    #pragma unroll
    for (int mt=0; mt<3; ++mt){
      const int co0s = mt*16 + jgrp*4;
      if (co0s >= 36) continue;
      union { f16 h[4]; uint2 q; } pk;
      #pragma unroll
      for (int reg=0; reg<4; ++reg){
        float r = acc2[mt][u][reg]; if (r < 0.f) r = 0.f;
        pk.h[reg] = (f16)r;
      }
      *(uint2*)(a2 + (((size_t)i*47 + oh)*16 + npx)*36 + co0s) = pk.q;
    }
  }
}

// ---------------------------------------------------------------- conv3+conv4 fused (per half-image)
__global__ __launch_bounds__(256) void conv34_k(const f16* __restrict__ a2, const f16* __restrict__ w3m,
                                                const float* __restrict__ b3, const f16* __restrict__ w4m,
                                                const float* __restrict__ b4, f16* __restrict__ a4){
  __shared__ __align__(16) f16 xt[27*680];     // 36720 B
  __shared__ __align__(16) f16 a3t[12*6*56];   // 8064 B
  const int tid = threadIdx.x, bx = blockIdx.x;
  const int i = bx >> 1, t = bx & 1;
  const int r0 = t*20, obase = t*10;
  {
    const uint2* s2 = (const uint2*)((const uint*)a2 + (size_t)i*13536);
    uint2* d = (uint2*)xt;
    for (int idx = tid; idx < 3888; idx += 256){
      int d2 = idx % 9, rc = idx / 9;
      int c = rc & 15, r = rc >> 4;
      int dwi = d2*2, jg = dwi >> 2, part = dwi & 3;
      d[(r*340 + jg*68 + c*4 + part) >> 1] = s2[((size_t)(r0 + r)*16 + c)*9 + d2];
    }
  }
  __syncthreads();
  const int wv = tid >> 6, lane = tid & 63;
  const int npx = lane & 15, jg = lane >> 4;
  {
    int baseq[2], ohl[2], owl[2];
    #pragma unroll
    for (int q=0;q<2;++q){
      int px = (wv*2+q)*16 + npx; if (px > 71) px = 71;
      ohl[q] = px/6; owl[q] = px - ohl[q]*6;
      baseq[q] = 2*ohl[q]*680 + jg*136 + 2*owl[q]*8;
    }
    f32x4 acc[3][2];
    #pragma unroll
    for (int mt=0;mt<3;++mt){
      f32x4 bv;
      #pragma unroll
      for (int reg=0;reg<4;++reg) bv[reg] = b3[mt*16 + jg*4 + reg];
      acc[mt][0]=bv; acc[mt][1]=bv;
    }
    const f16* agl = w3m + (size_t)lane*8;
    #pragma unroll 1
    for (int kh=0; kh<5; ++kh){
      #pragma unroll
      for (int kw=0; kw<5; ++kw){
        const int s = kh*5 + kw;
        f16x8 af[3];
        #pragma unroll
        for (int mt=0;mt<3;++mt)
          af[mt] = *(const f16x8*)(agl + (size_t)(s*3 + mt)*512);
        f16x8 bf[2];
        #pragma unroll
        for (int q=0;q<2;++q)
          bf[q] = *(const f16x8*)(xt + baseq[q] + kh*680 + kw*8);
        #pragma unroll
        for (int mt=0;mt<3;++mt)
          #pragma unroll
          for (int q=0;q<2;++q)
            acc[mt][q] = __builtin_amdgcn_mfma_f32_16x16x32_f16(af[mt], bf[q], acc[mt][q], 0, 0, 0);
      }
    }
    #pragma unroll
    for (int e=0;e<4;++e){
      const int s = 25 + e;
      f16x8 af[3];
      #pragma unroll
      for (int mt=0;mt<3;++mt)
        af[mt] = *(const f16x8*)(agl + (size_t)(s*3 + mt)*512);
      int p1 = e*8 + jg*2; int p2 = p1 + 1;
      if (p1 > 24) p1 = 24;
      if (p2 > 24) p2 = 24;
      const int kh1 = p1/5, kw1 = p1 - kh1*5;
      const int kh2 = p2/5, kw2 = p2 - kh2*5;
      #pragma unroll
      for (int q=0;q<2;++q){
        f16x4 lo = *(const f16x4*)(xt + (2*ohl[q]+kh1)*680 + 544 + (2*owl[q]+kw1)*8);
        f16x4 hi = *(const f16x4*)(xt + (2*ohl[q]+kh2)*680 + 544 + (2*owl[q]+kw2)*8);
        f16x8 bq = __builtin_shufflevector(lo, hi, 0,1,2,3,4,5,6,7);
        #pragma unroll
        for (int mt=0;mt<3;++mt)
          acc[mt][q] = __builtin_amdgcn_mfma_f32_16x16x32_f16(af[mt], bq, acc[mt][q], 0, 0, 0);
      }
    }
    #pragma unroll
    for (int q=0;q<2;++q){
      int px = (wv*2+q)*16 + npx;
      if (px >= 72) continue;
      #pragma unroll
      for (int mt=0;mt<3;++mt){
        union { f16 h[4]; uint2 q2; } pk;
        #pragma unroll
        for (int reg=0;reg<4;++reg){
          float r = acc[mt][q][reg]; if (r < 0.f) r = 0.f;
          pk.h[reg] = (f16)r;
        }
        *(uint2*)(a3t + px*56 + mt*16 + jg*4) = pk.q2;
      }
    }
  }
  __syncthreads();
  {
    f32x4 acc4[3];
    {
      f32x4 bv;
      #pragma unroll
      for (int reg=0;reg<4;++reg) bv[reg] = b4[wv*16 + jg*4 + reg];
      acc4[0]=bv; acc4[1]=bv; acc4[2]=bv;
    }
    int ohn[3], own[3];
    #pragma unroll
    for (int nt=0;nt<3;++nt){
      int px = nt*16 + npx; if (px > 39) px = 39;
      ohn[nt] = px >> 2; own[nt] = px & 3;
    }
    const f16* agl = w4m + (size_t)lane*8;
    #pragma unroll 1
    for (int s=0; s<14; ++s){
      f16x8 af = *(const f16x8*)(agl + (size_t)(s*4 + wv)*512);
      int k8 = s*32 + jg*8;
      int pos, ci0;
      if (k8 >= 432){ pos = 8; ci0 = 40; }
      else { pos = k8 / 48; ci0 = k8 - pos*48; }
      const int kh = pos/3, kw = pos - kh*3;
      #pragma unroll
      for (int nt=0;nt<3;++nt){
        const int r = ohn[nt] + kh, c = own[nt] + kw;
        f16x8 bq = *(const f16x8*)(a3t + (r*6 + c)*56 + ci0);
        acc4[nt] = __builtin_amdgcn_mfma_f32_16x16x32_f16(af, bq, acc4[nt], 0, 0, 0);
      }
    }
    #pragma unroll
    for (int nt=0;nt<3;++nt){
      int px = nt*16 + npx;
      if (px >= 40) continue;
      union { f16 h[4]; uint2 q2; } pk;
      #pragma unroll
      for (int reg=0;reg<4;++reg){
        float r = acc4[nt][reg]; if (r < 0.f) r = 0.f;
        pk.h[reg] = (f16)r;
      }
      *(uint2*)(a4 + ((size_t)i*80 + obase*4 + px)*64 + wv*16 + jg*4) = pk.q2;
    }
  }
}

// ---------------------------------------------------------------- fc1 (MFMA) + fc2..fc4 + AEBS fused
__global__ __launch_bounds__(256) void fc1tail_k(const f16* __restrict__ a4, const f16* __restrict__ w1m,
    const float* __restrict__ fc1b, const float* __restrict__ dist, const float* __restrict__ speed,
    const float* __restrict__ fW2, const float* __restrict__ fb2,
    const float* __restrict__ fW3, const float* __restrict__ fb3,
    const float* __restrict__ fW4, const float* __restrict__ fb4,
    const float* __restrict__ aW1, const float* __restrict__ ab1,
    const float* __restrict__ aW2, const float* __restrict__ ab2,
    const float* __restrict__ aW3, const float* __restrict__ ab3,
    float* __restrict__ out, int ib){
  __shared__ float red[4][64][28];
  __shared__ float x1s[16][100];
  __shared__ float h2s[16][50];
  __shared__ float h3s[16][10];
  __shared__ float stg[16];
  __shared__ float hb1[16][12];
  __shared__ float hb2[16][24];
  const int tid = threadIdx.x;
  const int wv = tid >> 6, lane = tid & 63;
  const int img0 = blockIdx.x*16;
  f32x4 acc[7];
  #pragma unroll
  for (int nt=0;nt<7;++nt) acc[nt] = (f32x4){0.f,0.f,0.f,0.f};
  const f16* ap = a4 + (size_t)(img0 + (lane & 15))*5120 + (lane >> 4)*8;
  const f16* bp = w1m + (size_t)lane*8;
  #pragma unroll 1
  for (int s = wv*40; s < wv*40 + 40; ++s){
    f16x8 av = *(const f16x8*)(ap + s*32);
    #pragma unroll
    for (int nt=0;nt<7;++nt){
      f16x8 bv = *(const f16x8*)(bp + (size_t)(s*7 + nt)*512);
      acc[nt] = __builtin_amdgcn_mfma_f32_16x16x32_f16(av, bv, acc[nt], 0, 0, 0);
    }
  }
  #pragma unroll
  for (int nt=0;nt<7;++nt)
    #pragma unroll
    for (int reg=0;reg<4;++reg)
      red[wv][lane][nt*4+reg] = acc[nt][reg];
  __syncthreads();
  for (int idx = tid; idx < 1792; idx += 256){
    int imgl = idx / 112, j = idx - imgl*112;
    if (j >= 100) continue;
    int l = ((imgl >> 2) << 4) | (j & 15);
    int c = (j >> 4)*4 + (imgl & 3);
    float s = red[0][l][c] + red[1][l][c] + red[2][l][c] + red[3][l][c] + fc1b[j];
    x1s[imgl][j] = s > 0.f ? s : 0.f;
  }
  __syncthreads();
  const int g = tid >> 4, l16 = tid & 15;
  const int img = ib + img0 + g;
  for (int j = l16; j < 50; j += 16){
    float s = fb2[j];
    #pragma unroll 4
    for (int k = 0; k < 100; ++k) s = fmaf(x1s[g][k], fW2[k*50+j], s);
    h2s[g][j] = s > 0.f ? s : 0.f;
  }
  __syncthreads();
  if (l16 < 10){
    float s = fb3[l16];
    #pragma unroll
    for (int k = 0; k < 50; ++k) s = fmaf(h2s[g][k], fW3[k*10+l16], s);
    h3s[g][l16] = s > 0.f ? s : 0.f;
  }
  __syncthreads();
  if (l16 == 0){
    float s = fb4[0];
    #pragma unroll
    for (int k = 0; k < 10; ++k) s = fmaf(h3s[g][k], fW4[k], s);
    stg[g] = s;
  }
  __syncthreads();
  if (l16 < 12){
    float s0 = stg[g], dd = dist[img], sp = speed[img];
    float s = ab1[l16] + s0*aW1[l16] + dd*aW1[12+l16] + sp*aW1[24+l16];
    hb1[g][l16] = s > 0.f ? s : 0.f;
  }
  __syncthreads();
  for (int j = l16; j < 24; j += 16){
    float s = ab2[j];
    #pragma unroll
    for (int k=0;k<12;++k) s = fmaf(hb1[g][k], aW2[k*24+j], s);
    hb2[g][j] = s > 0.f ? s : 0.f;
  }
  __syncthreads();
  if (l16 < 4){
    float s = ab3[l16];
    #pragma unroll
    for (int k=0;k<24;++k) s = fmaf(hb2[g][k], aW3[k*4+l16], s);
    out[(size_t)img*4 + l16] = s;
  }
}

// ================================================================ host
extern "C" void kernel_launch(void* const* d_in, const int* in_sizes, int n_in,
                              void* d_out, int out_size, void* d_ws, size_t ws_size,
                              hipStream_t stream){
  const float* rgb   = (const float*)d_in[0];
  const float* dist  = (const float*)d_in[1];
  const float* speed = (const float*)d_in[2];
  const float* cw1 = (const float*)d_in[3];
  const float* cb1 = (const float*)d_in[4];
  const float* cw2 = (const float*)d_in[5];
  const float* cb2 = (const float*)d_in[6];
  const float* cw3 = (const float*)d_in[7];
  const float* cb3 = (const float*)d_in[8];
  const float* cw4 = (const float*)d_in[9];
  const float* cb4 = (const float*)d_in[10];
  const float* fW1 = (const float*)d_in[11];
  const float* fb1 = (const float*)d_in[12];
  const float* fW2 = (const float*)d_in[13];
  const float* fb2 = (const float*)d_in[14];
  const float* fW3 = (const float*)d_in[15];
  const float* fb3 = (const float*)d_in[16];
  const float* fW4 = (const float*)d_in[17];
  const float* fb4 = (const float*)d_in[18];
  const float* aW1 = (const float*)d_in[19];
  const float* ab1 = (const float*)d_in[20];
  const float* aW2 = (const float*)d_in[21];
  const float* ab2 = (const float*)d_in[22];
  const float* aW3 = (const float*)d_in[23];
  const float* ab3 = (const float*)d_in[24];
  float* out = (float*)d_out;
  const int B = in_sizes[0] / 15000;

  auto ALN = [](size_t x){ return (x + 255) & ~(size_t)255; };
  const size_t fixed = ALN(2048) + ALN(58368) + ALN(89088) + ALN(57344) + ALN(1146880);

  int nc = 1;
  while (nc < 32){
    size_t Bc = (size_t)(B / nc);
    size_t need = fixed + ALN(Bc*54144) + ALN(Bc*10240);
    if (need <= ws_size) break;
    nc *= 2;
  }
  const int Bc = B / nc;

  char* ws = (char*)d_ws;
  size_t o = 0;
  auto alloc = [&](size_t bytes)->char*{ char* p = ws + o; o += ALN(bytes); return p; };
  f16* w1c = (f16*)alloc(2048);
  f16* w2c = (f16*)alloc(58368);
  f16* w3m = (f16*)alloc(89088);
  f16* w4m = (f16*)alloc(57344);
  f16* w1m = (f16*)alloc(1146880);
  f16* a2  = (f16*)alloc((size_t)Bc*54144);
  f16* a4  = (f16*)alloc((size_t)Bc*10240);

  repack1m_k<<<dim3(4),   dim3(256), 0, stream>>>(w1c, cw1);
  repack2c_k<<<dim3(114), dim3(256), 0, stream>>>(w2c, cw2);
  repack3m_k<<<dim3(174), dim3(256), 0, stream>>>(w3m, cw3);
  repack4m_k<<<dim3(112), dim3(256), 0, stream>>>(w4m, cw4);
  repackfc1_k<<<dim3(280), dim3(256), 0, stream>>>(w1m, fW1);

  for (int c = 0; c < nc; ++c){
    const int ib = c*Bc;
    conv12_k<<<dim3(Bc*3),   dim3(256), 0, stream>>>(rgb, w1c, cb1, w2c, cb2, a2, ib);
    conv34_k<<<dim3(Bc*2),   dim3(256), 0, stream>>>(a2, w3m, cb3, w4m, cb4, a4);
    fc1tail_k<<<dim3(Bc/16), dim3(256), 0, stream>>>(a4, w1m, fb1, dist, speed,
        fW2, fb2, fW3, fb3, fW4, fb4, aW1, ab1, aW2, ab2, aW3, ab3, out, ib);
  }
}

// Round 12
// 184.728 us; speedup vs baseline: 1.1422x; 1.1422x over previous
//
#include <hip/hip_runtime.h>

typedef _Float16 f16;
typedef _Float16 f16x4 __attribute__((ext_vector_type(4)));
typedef _Float16 f16x8 __attribute__((ext_vector_type(8)));
typedef float f32x4 __attribute__((ext_vector_type(4)));

// ---------------------------------------------------------------- merged weight repack (all MFMA fragments)
// w1c: [mt2][lane64][8], K col-major taps (k -> kw=k/5, kh=k%5). cw1 (24,1,5,5)
// w2c: [s19][mt3][lane64][8], k<600: tap=k/24, ci=k%24. cw2 (36,24,5,5)
// w3m: [s29][mt3][lane64][8]. cw3 (48,36,5,5)
// w4m: [s14][mt4][lane64][8]. cw4 (64,48,3,3)
// wfc: [s160][nt7][lane64][8], fc1W rows NHWC-permuted
__global__ __launch_bounds__(256) void repack_all_k(
    f16* __restrict__ w1c, f16* __restrict__ w2c, f16* __restrict__ w3m,
    f16* __restrict__ w4m, f16* __restrict__ wfc,
    const float* __restrict__ s1, const float* __restrict__ s2, const float* __restrict__ s3,
    const float* __restrict__ s4, const float* __restrict__ sf){
  const int tid0 = blockIdx.x*256 + threadIdx.x, stride = gridDim.x*256;
  for (int idx = tid0; idx < 1024; idx += stride){
    int i = idx & 7, l = (idx >> 3) & 63, mt = idx >> 9;
    int co = mt*16 + (l & 15);
    int k = (l >> 4)*8 + i;
    f16 v = (f16)0.0f;
    if (co < 24 && k < 25){
      int kw = k / 5, kh = k - kw*5;
      v = (f16)s1[co*25 + kh*5 + kw];
    }
    w1c[idx] = v;
  }
  for (int idx = tid0; idx < 29184; idx += stride){
    int i = idx & 7, l = (idx >> 3) & 63, rest = idx >> 9;
    int mt = rest % 3, s = rest / 3;
    int co = mt*16 + (l & 15);
    int k = s*32 + (l >> 4)*8 + i;
    f16 v = (f16)0.0f;
    if (co < 36 && k < 600){
      int tap = k / 24, ci = k - tap*24;
      v = (f16)s2[(co*24 + ci)*25 + tap];
    }
    w2c[idx] = v;
  }
  for (int idx = tid0; idx < 44544; idx += stride){
    int i = idx & 7, l = (idx >> 3) & 63, rest = idx >> 9;
    int mt = rest % 3, s = rest / 3;
    int co = mt*16 + (l & 15);
    f16 v = (f16)0.0f;
    if (s < 25){
      int ci = (l >> 4)*8 + i;
      v = (f16)s3[(co*36 + ci)*25 + s];
    } else {
      int ke = (s - 25)*32 + (l >> 4)*8 + i;
      if (ke < 100){
        int p = ke >> 2, ci = 32 + (ke & 3);
        v = (f16)s3[(co*36 + ci)*25 + p];
      }
    }
    w3m[idx] = v;
  }
  for (int idx = tid0; idx < 28672; idx += stride){
    int i = idx & 7, l = (idx >> 3) & 63, rest = idx >> 9;
    int mt = rest & 3, s = rest >> 2;
    int co = mt*16 + (l & 15);
    int k = s*32 + (l >> 4)*8 + i;
    f16 v = (f16)0.0f;
    if (k < 432){
      int pos = k / 48, ci = k - pos*48;
      v = (f16)s4[(co*48 + ci)*9 + pos];
    }
    w4m[idx] = v;
  }
  for (int t = tid0; t < 71680; t += stride){
    int l = t & 63, rest = t >> 6;
    int nt = rest % 7, s = rest / 7;
    int j = nt*16 + (l & 15);
    int kb = s*32 + (l >> 4)*8;
    union { f16 h[8]; f16x8 v; } pk;
    #pragma unroll
    for (int i=0;i<8;++i){
      int k = kb + i;
      int row = (k & 63)*80 + (k >> 6);
      pk.h[i] = (j < 100) ? (f16)sf[(size_t)row*100 + j] : (f16)0.0f;
    }
    *(f16x8*)(wfc + (size_t)t*8) = pk.v;
  }
}

// ---------------------------------------------------------------- conv1+conv2 fused (both MFMA, 8-row tiles)
// rgb (B,15000) f32 [w75][h200] -> a2 NHWC (Bc,47,16,36). grid=Bc*6, block=256.
// xb [w75][hh42] stride 46 (bank stride 14 mod 32: 16 distinct banks per 16-lane gather group).
__global__ __launch_bounds__(256) void conv12_k(const float* __restrict__ rgb, const f16* __restrict__ w1m,
                                                const float* __restrict__ b1, const f16* __restrict__ w2c,
                                                const float* __restrict__ b2, f16* __restrict__ a2, int ib){
  __shared__ __align__(16) f16 xb[75*46 + 8];      // 6916 B
  __shared__ __align__(16) f16 xt[2*19*18*24];     // 32832 B
  const int tid = threadIdx.x, bx = blockIdx.x;
  const int i = bx / 6, t = bx - i*6;
  const int h0 = t*32, oh0 = t*8;
  const float* img = rgb + (size_t)(ib + i)*15000;
  // phase 0: binarize staging (75 w x 21 row-pairs, hh 0..41)
  for (int idx = tid; idx < 1575; idx += 256){
    int w = idx / 21, t2 = idx - w*21;
    int hh = 2*t2, h = h0 + hh;
    union { f16 hv[2]; uint u; } pk;
    if (h < 200){
      float2 v = *(const float2*)(img + w*200 + h);
      pk.hv[0] = (v.x > 0.f) ? (f16)1.0f : (f16)0.0f;
      pk.hv[1] = (v.y > 0.f) ? (f16)1.0f : (f16)0.0f;
    } else {
      pk.u = 0u;
    }
    *(uint*)(xb + w*46 + hh) = pk.u;
  }
  __syncthreads();
  const int wv = tid >> 6, lane = tid & 63;
  const int jgrp = lane >> 4, npx = lane & 15;
  // ---- phase 1: conv1 MFMA into xt
  {
    f16x8 a1f0 = *(const f16x8*)(w1m + (size_t)lane*8);
    f16x8 a1f1 = *(const f16x8*)(w1m + (size_t)(64 + lane)*8);
    int koff[8];
    #pragma unroll
    for (int ii=0; ii<8; ++ii){
      int k = jgrp*8 + ii;
      if (k >= 25) k = 0;
      int kw = k / 5, kh = k - kw*5;
      koff[ii] = kw*46 + kh;
    }
    f32x4 bv0, bv1;
    #pragma unroll
    for (int reg=0; reg<4; ++reg){
      int c0 = jgrp*4 + reg;
      int c1 = 16 + jgrp*4 + reg;
      bv0[reg] = b1[c0];
      bv1[reg] = (c1 < 24) ? b1[c1] : 0.f;
    }
    for (int q=0; q<11; ++q){
      int nt = wv + 4*q;
      if (nt > 42) break;
      int pxt = nt*16 + npx;
      int px = (pxt > 683) ? 683 : pxt;
      int rr = px/36, ow = px - rr*36;
      const f16* gp = xb + 2*(ow*46 + rr);
      union { f16 h[8]; f16x8 v; } bq;
      #pragma unroll
      for (int ii=0; ii<8; ++ii) bq.h[ii] = gp[koff[ii]];
      f32x4 c0 = __builtin_amdgcn_mfma_f32_16x16x32_f16(a1f0, bq.v, bv0, 0, 0, 0);
      f32x4 c1 = __builtin_amdgcn_mfma_f32_16x16x32_f16(a1f1, bq.v, bv1, 0, 0, 0);
      if (pxt <= 683){
        f16* dst = xt + (((ow & 1)*19 + rr)*18 + (ow >> 1))*24;
        union { f16 h[4]; uint2 q2; } pk;
        #pragma unroll
        for (int reg=0; reg<4; ++reg){ float r = c0[reg]; if (r<0.f) r=0.f; pk.h[reg]=(f16)r; }
        *(uint2*)(dst + jgrp*4) = pk.q2;
        if (jgrp < 2){
          #pragma unroll
          for (int reg=0; reg<4; ++reg){ float r = c1[reg]; if (r<0.f) r=0.f; pk.h[reg]=(f16)r; }
          *(uint2*)(dst + 16 + jgrp*4) = pk.q2;
        }
      }
    }
  }
  __syncthreads();
  // ---- phase 2: conv2 MFMA, K-packed (19 steps of 32 over k = tap*24 + ci)
  int baddr[19];
  #pragma unroll
  for (int s=0; s<19; ++s){
    int m = s*4 + jgrp;
    int tap = m / 3, r3 = m - tap*3;
    if (m >= 75){ tap = 24; r3 = 0; }
    int kh = tap / 5, kw = tap - kh*5;
    int par = kw & 1, kws = kw >> 1;
    baddr[s] = ((par*19 + kh)*18 + npx + kws)*24 + r3*8;
  }
  f32x4 acc2[3][2];
  #pragma unroll
  for (int mt=0; mt<3; ++mt){
    f32x4 bv;
    #pragma unroll
    for (int reg=0; reg<4; ++reg){
      int co = mt*16 + jgrp*4 + reg;
      bv[reg] = (co < 36) ? b2[co] : 0.0f;
    }
    acc2[mt][0] = bv; acc2[mt][1] = bv;
  }
  const f16* agl = w2c + (size_t)lane*8;
  const int rowo = 4*wv*432;
  #pragma unroll
  for (int s=0; s<19; ++s){
    f16x8 af[3];
    #pragma unroll
    for (int mt=0; mt<3; ++mt)
      af[mt] = *(const f16x8*)(agl + (size_t)(s*3 + mt)*512);
    const f16* bb0 = xt + baddr[s] + rowo;
    f16x8 bf[2];
    bf[0] = *(const f16x8*)(bb0);
    bf[1] = *(const f16x8*)(bb0 + 2*432);
    #pragma unroll
    for (int mt=0; mt<3; ++mt)
      #pragma unroll
      for (int u=0; u<2; ++u)
        acc2[mt][u] = __builtin_amdgcn_mfma_f32_16x16x32_f16(af[mt], bf[u], acc2[mt][u], 0, 0, 0);
  }
  #pragma unroll
  for (int u=0; u<2; ++u){
    const int oh = oh0 + 2*wv + u;
    if (oh >= 47) continue;
    #pragma unroll
    for (int mt=0; mt<3; ++mt){
      const int co0s = mt*16 + jgrp*4;
      if (co0s >= 36) continue;
      union { f16 h[4]; uint2 q; } pk;
      #pragma unroll
      for (int reg=0; reg<4; ++reg){
        float r = acc2[mt][u][reg]; if (r < 0.f) r = 0.f;
        pk.h[reg] = (f16)r;
      }
      *(uint2*)(a2 + (((size_t)i*47 + oh)*16 + npx)*36 + co0s) = pk.q;
    }
  }
}

// ---------------------------------------------------------------- conv3+conv4 fused (per half-image)
__global__ __launch_bounds__(256) void conv34_k(const f16* __restrict__ a2, const f16* __restrict__ w3m,
                                                const float* __restrict__ b3, const f16* __restrict__ w4m,
                                                const float* __restrict__ b4, f16* __restrict__ a4){
  __shared__ __align__(16) f16 xt[27*680];     // 36720 B
  __shared__ __align__(16) f16 a3t[12*6*56];   // 8064 B
  const int tid = threadIdx.x, bx = blockIdx.x;
  const int i = bx >> 1, t = bx & 1;
  const int r0 = t*20, obase = t*10;
  {
    const uint2* s2 = (const uint2*)((const uint*)a2 + (size_t)i*13536);
    uint2* d = (uint2*)xt;
    for (int idx = tid; idx < 3888; idx += 256){
      int d2 = idx % 9, rc = idx / 9;
      int c = rc & 15, r = rc >> 4;
      int dwi = d2*2, jg = dwi >> 2, part = dwi & 3;
      d[(r*340 + jg*68 + c*4 + part) >> 1] = s2[((size_t)(r0 + r)*16 + c)*9 + d2];
    }
  }
  __syncthreads();
  const int wv = tid >> 6, lane = tid & 63;
  const int npx = lane & 15, jg = lane >> 4;
  {
    int baseq[2], ohl[2], owl[2];
    #pragma unroll
    for (int q=0;q<2;++q){
      int px = (wv*2+q)*16 + npx; if (px > 71) px = 71;
      ohl[q] = px/6; owl[q] = px - ohl[q]*6;
      baseq[q] = 2*ohl[q]*680 + jg*136 + 2*owl[q]*8;
    }
    f32x4 acc[3][2];
    #pragma unroll
    for (int mt=0;mt<3;++mt){
      f32x4 bv;
      #pragma unroll
      for (int reg=0;reg<4;++reg) bv[reg] = b3[mt*16 + jg*4 + reg];
      acc[mt][0]=bv; acc[mt][1]=bv;
    }
    const f16* agl = w3m + (size_t)lane*8;
    #pragma unroll 1
    for (int kh=0; kh<5; ++kh){
      #pragma unroll
      for (int kw=0; kw<5; ++kw){
        const int s = kh*5 + kw;
        f16x8 af[3];
        #pragma unroll
        for (int mt=0;mt<3;++mt)
          af[mt] = *(const f16x8*)(agl + (size_t)(s*3 + mt)*512);
        f16x8 bf[2];
        #pragma unroll
        for (int q=0;q<2;++q)
          bf[q] = *(const f16x8*)(xt + baseq[q] + kh*680 + kw*8);
        #pragma unroll
        for (int mt=0;mt<3;++mt)
          #pragma unroll
          for (int q=0;q<2;++q)
            acc[mt][q] = __builtin_amdgcn_mfma_f32_16x16x32_f16(af[mt], bf[q], acc[mt][q], 0, 0, 0);
      }
    }
    #pragma unroll
    for (int e=0;e<4;++e){
      const int s = 25 + e;
      f16x8 af[3];
      #pragma unroll
      for (int mt=0;mt<3;++mt)
        af[mt] = *(const f16x8*)(agl + (size_t)(s*3 + mt)*512);
      int p1 = e*8 + jg*2; int p2 = p1 + 1;
      if (p1 > 24) p1 = 24;
      if (p2 > 24) p2 = 24;
      const int kh1 = p1/5, kw1 = p1 - kh1*5;
      const int kh2 = p2/5, kw2 = p2 - kh2*5;
      #pragma unroll
      for (int q=0;q<2;++q){
        f16x4 lo = *(const f16x4*)(xt + (2*ohl[q]+kh1)*680 + 544 + (2*owl[q]+kw1)*8);
        f16x4 hi = *(const f16x4*)(xt + (2*ohl[q]+kh2)*680 + 544 + (2*owl[q]+kw2)*8);
        f16x8 bq = __builtin_shufflevector(lo, hi, 0,1,2,3,4,5,6,7);
        #pragma unroll
        for (int mt=0;mt<3;++mt)
          acc[mt][q] = __builtin_amdgcn_mfma_f32_16x16x32_f16(af[mt], bq, acc[mt][q], 0, 0, 0);
      }
    }
    #pragma unroll
    for (int q=0;q<2;++q){
      int px = (wv*2+q)*16 + npx;
      if (px >= 72) continue;
      #pragma unroll
      for (int mt=0;mt<3;++mt){
        union { f16 h[4]; uint2 q2; } pk;
        #pragma unroll
        for (int reg=0;reg<4;++reg){
          float r = acc[mt][q][reg]; if (r < 0.f) r = 0.f;
          pk.h[reg] = (f16)r;
        }
        *(uint2*)(a3t + px*56 + mt*16 + jg*4) = pk.q2;
      }
    }
  }
  __syncthreads();
  {
    f32x4 acc4[3];
    {
      f32x4 bv;
      #pragma unroll
      for (int reg=0;reg<4;++reg) bv[reg] = b4[wv*16 + jg*4 + reg];
      acc4[0]=bv; acc4[1]=bv; acc4[2]=bv;
    }
    int ohn[3], own[3];
    #pragma unroll
    for (int nt=0;nt<3;++nt){
      int px = nt*16 + npx; if (px > 39) px = 39;
      ohn[nt] = px >> 2; own[nt] = px & 3;
    }
    const f16* agl = w4m + (size_t)lane*8;
    #pragma unroll 1
    for (int s=0; s<14; ++s){
      f16x8 af = *(const f16x8*)(agl + (size_t)(s*4 + wv)*512);
      int k8 = s*32 + jg*8;
      int pos, ci0;
      if (k8 >= 432){ pos = 8; ci0 = 40; }
      else { pos = k8 / 48; ci0 = k8 - pos*48; }
      const int kh = pos/3, kw = pos - kh*3;
      #pragma unroll
      for (int nt=0;nt<3;++nt){
        const int r = ohn[nt] + kh, c = own[nt] + kw;
        f16x8 bq = *(const f16x8*)(a3t + (r*6 + c)*56 + ci0);
        acc4[nt] = __builtin_amdgcn_mfma_f32_16x16x32_f16(af, bq, acc4[nt], 0, 0, 0);
      }
    }
    #pragma unroll
    for (int nt=0;nt<3;++nt){
      int px = nt*16 + npx;
      if (px >= 40) continue;
      union { f16 h[4]; uint2 q2; } pk;
      #pragma unroll
      for (int reg=0;reg<4;++reg){
        float r = acc4[nt][reg]; if (r < 0.f) r = 0.f;
        pk.h[reg] = (f16)r;
      }
      *(uint2*)(a4 + ((size_t)i*80 + obase*4 + px)*64 + wv*16 + jg*4) = pk.q2;
    }
  }
}

// ---------------------------------------------------------------- fc1 (MFMA) + fc2..fc4 + AEBS fused
// 8 images per block -> grid Bc/8 (2x the TLP of the 16-img version). M rows 8..15 are clamped dummies.
__global__ __launch_bounds__(256) void fc1tail_k(const f16* __restrict__ a4, const f16* __restrict__ w1m,
    const float* __restrict__ fc1b, const float* __restrict__ dist, const float* __restrict__ speed,
    const float* __restrict__ fW2, const float* __restrict__ fb2,
    const float* __restrict__ fW3, const float* __restrict__ fb3,
    const float* __restrict__ fW4, const float* __restrict__ fb4,
    const float* __restrict__ aW1, const float* __restrict__ ab1,
    const float* __restrict__ aW2, const float* __restrict__ ab2,
    const float* __restrict__ aW3, const float* __restrict__ ab3,
    float* __restrict__ out, int ib, int n){
  __shared__ float red[4][64][28];
  __shared__ float x1s[8][100];
  __shared__ float h2s[8][50];
  __shared__ float h3s[8][10];
  __shared__ float stg[8];
  __shared__ float hb1[8][12];
  __shared__ float hb2[8][24];
  const int tid = threadIdx.x;
  const int wv = tid >> 6, lane = tid & 63;
  const int img0 = blockIdx.x*8;
  f32x4 acc[7];
  #pragma unroll
  for (int nt=0;nt<7;++nt) acc[nt] = (f32x4){0.f,0.f,0.f,0.f};
  int ia = img0 + (lane & 15);
  if (ia > n-1) ia = n-1;
  const f16* ap = a4 + (size_t)ia*5120 + (lane >> 4)*8;
  const f16* bp = w1m + (size_t)lane*8;
  #pragma unroll 1
  for (int s = wv*40; s < wv*40 + 40; ++s){
    f16x8 av = *(const f16x8*)(ap + s*32);
    #pragma unroll
    for (int nt=0;nt<7;++nt){
      f16x8 bv = *(const f16x8*)(bp + (size_t)(s*7 + nt)*512);
      acc[nt] = __builtin_amdgcn_mfma_f32_16x16x32_f16(av, bv, acc[nt], 0, 0, 0);
    }
  }
  #pragma unroll
  for (int nt=0;nt<7;++nt)
    #pragma unroll
    for (int reg=0;reg<4;++reg)
      red[wv][lane][nt*4+reg] = acc[nt][reg];
  __syncthreads();
  for (int idx = tid; idx < 896; idx += 256){
    int imgl = idx / 112, j = idx - imgl*112;
    if (j >= 100) continue;
    int l = ((imgl >> 2) << 4) | (j & 15);
    int c = (j >> 4)*4 + (imgl & 3);
    float s = red[0][l][c] + red[1][l][c] + red[2][l][c] + red[3][l][c] + fc1b[j];
    x1s[imgl][j] = s > 0.f ? s : 0.f;
  }
  __syncthreads();
  const int g = tid >> 5, l32 = tid & 31;
  const int img = ib + img0 + g;
  for (int j = l32; j < 50; j += 32){
    float s = fb2[j];
    #pragma unroll 4
    for (int k = 0; k < 100; ++k) s = fmaf(x1s[g][k], fW2[k*50+j], s);
    h2s[g][j] = s > 0.f ? s : 0.f;
  }
  __syncthreads();
  if (l32 < 10){
    float s = fb3[l32];
    #pragma unroll
    for (int k = 0; k < 50; ++k) s = fmaf(h2s[g][k], fW3[k*10+l32], s);
    h3s[g][l32] = s > 0.f ? s : 0.f;
  }
  __syncthreads();
  if (l32 == 0){
    float s = fb4[0];
    #pragma unroll
    for (int k = 0; k < 10; ++k) s = fmaf(h3s[g][k], fW4[k], s);
    stg[g] = s;
  }
  __syncthreads();
  if (l32 < 12){
    float s0 = stg[g], dd = dist[img], sp = speed[img];
    float s = ab1[l32] + s0*aW1[l32] + dd*aW1[12+l32] + sp*aW1[24+l32];
    hb1[g][l32] = s > 0.f ? s : 0.f;
  }
  __syncthreads();
  if (l32 < 24){
    float s = ab2[l32];
    #pragma unroll
    for (int k=0;k<12;++k) s = fmaf(hb1[g][k], aW2[k*24+l32], s);
    hb2[g][l32] = s > 0.f ? s : 0.f;
  }
  __syncthreads();
  if (l32 < 4){
    float s = ab3[l32];
    #pragma unroll
    for (int k=0;k<24;++k) s = fmaf(hb2[g][k], aW3[k*4+l32], s);
    out[(size_t)img*4 + l32] = s;
  }
}

// ================================================================ host
extern "C" void kernel_launch(void* const* d_in, const int* in_sizes, int n_in,
                              void* d_out, int out_size, void* d_ws, size_t ws_size,
                              hipStream_t stream){
  const float* rgb   = (const float*)d_in[0];
  const float* dist  = (const float*)d_in[1];
  const float* speed = (const float*)d_in[2];
  const float* cw1 = (const float*)d_in[3];
  const float* cb1 = (const float*)d_in[4];
  const float* cw2 = (const float*)d_in[5];
  const float* cb2 = (const float*)d_in[6];
  const float* cw3 = (const float*)d_in[7];
  const float* cb3 = (const float*)d_in[8];
  const float* cw4 = (const float*)d_in[9];
  const float* cb4 = (const float*)d_in[10];
  const float* fW1 = (const float*)d_in[11];
  const float* fb1 = (const float*)d_in[12];
  const float* fW2 = (const float*)d_in[13];
  const float* fb2 = (const float*)d_in[14];
  const float* fW3 = (const float*)d_in[15];
  const float* fb3 = (const float*)d_in[16];
  const float* fW4 = (const float*)d_in[17];
  const float* fb4 = (const float*)d_in[18];
  const float* aW1 = (const float*)d_in[19];
  const float* ab1 = (const float*)d_in[20];
  const float* aW2 = (const float*)d_in[21];
  const float* ab2 = (const float*)d_in[22];
  const float* aW3 = (const float*)d_in[23];
  const float* ab3 = (const float*)d_in[24];
  float* out = (float*)d_out;
  const int B = in_sizes[0] / 15000;

  auto ALN = [](size_t x){ return (x + 255) & ~(size_t)255; };
  const size_t fixed = ALN(2048) + ALN(58368) + ALN(89088) + ALN(57344) + ALN(1146880);

  int nc = 1;
  while (nc < 32){
    size_t Bc = (size_t)(B / nc);
    size_t need = fixed + ALN(Bc*54144) + ALN(Bc*10240);
    if (need <= ws_size) break;
    nc *= 2;
  }
  const int Bc = B / nc;

  char* ws = (char*)d_ws;
  size_t o = 0;
  auto alloc = [&](size_t bytes)->char*{ char* p = ws + o; o += ALN(bytes); return p; };
  f16* w1c = (f16*)alloc(2048);
  f16* w2c = (f16*)alloc(58368);
  f16* w3m = (f16*)alloc(89088);
  f16* w4m = (f16*)alloc(57344);
  f16* w1m = (f16*)alloc(1146880);
  f16* a2  = (f16*)alloc((size_t)Bc*54144);
  f16* a4  = (f16*)alloc((size_t)Bc*10240);

  repack_all_k<<<dim3(280), dim3(256), 0, stream>>>(w1c, w2c, w3m, w4m, w1m,
                                                    cw1, cw2, cw3, cw4, fW1);

  for (int c = 0; c < nc; ++c){
    const int ib = c*Bc;
    conv12_k<<<dim3(Bc*6),  dim3(256), 0, stream>>>(rgb, w1c, cb1, w2c, cb2, a2, ib);
    conv34_k<<<dim3(Bc*2),  dim3(256), 0, stream>>>(a2, w3m, cb3, w4m, cb4, a4);
    fc1tail_k<<<dim3(Bc/8), dim3(256), 0, stream>>>(a4, w1m, fb1, dist, speed,
        fW2, fb2, fW3, fb3, fW4, fb4, aW1, ab1, aW2, ab2, aW3, ab3, out, ib, Bc);
  }
}

// Round 13
// 171.075 us; speedup vs baseline: 1.2334x; 1.0798x over previous
//
#include <hip/hip_runtime.h>

typedef _Float16 f16;
typedef _Float16 f16x4 __attribute__((ext_vector_type(4)));
typedef _Float16 f16x8 __attribute__((ext_vector_type(8)));
typedef float f32x4 __attribute__((ext_vector_type(4)));

// ---------------------------------------------------------------- merged weight repack (all MFMA fragments)
__global__ __launch_bounds__(256) void repack_all_k(
    f16* __restrict__ w1c, f16* __restrict__ w2c, f16* __restrict__ w3m,
    f16* __restrict__ w4m, f16* __restrict__ wfc,
    const float* __restrict__ s1, const float* __restrict__ s2, const float* __restrict__ s3,
    const float* __restrict__ s4, const float* __restrict__ sf){
  const int tid0 = blockIdx.x*256 + threadIdx.x, stride = gridDim.x*256;
  for (int idx = tid0; idx < 1024; idx += stride){
    int i = idx & 7, l = (idx >> 3) & 63, mt = idx >> 9;
    int co = mt*16 + (l & 15);
    int k = (l >> 4)*8 + i;
    f16 v = (f16)0.0f;
    if (co < 24 && k < 25){
      int kw = k / 5, kh = k - kw*5;
      v = (f16)s1[co*25 + kh*5 + kw];
    }
    w1c[idx] = v;
  }
  for (int idx = tid0; idx < 29184; idx += stride){
    int i = idx & 7, l = (idx >> 3) & 63, rest = idx >> 9;
    int mt = rest % 3, s = rest / 3;
    int co = mt*16 + (l & 15);
    int k = s*32 + (l >> 4)*8 + i;
    f16 v = (f16)0.0f;
    if (co < 36 && k < 600){
      int tap = k / 24, ci = k - tap*24;
      v = (f16)s2[(co*24 + ci)*25 + tap];
    }
    w2c[idx] = v;
  }
  for (int idx = tid0; idx < 44544; idx += stride){
    int i = idx & 7, l = (idx >> 3) & 63, rest = idx >> 9;
    int mt = rest % 3, s = rest / 3;
    int co = mt*16 + (l & 15);
    f16 v = (f16)0.0f;
    if (s < 25){
      int ci = (l >> 4)*8 + i;
      v = (f16)s3[(co*36 + ci)*25 + s];
    } else {
      int ke = (s - 25)*32 + (l >> 4)*8 + i;
      if (ke < 100){
        int p = ke >> 2, ci = 32 + (ke & 3);
        v = (f16)s3[(co*36 + ci)*25 + p];
      }
    }
    w3m[idx] = v;
  }
  for (int idx = tid0; idx < 28672; idx += stride){
    int i = idx & 7, l = (idx >> 3) & 63, rest = idx >> 9;
    int mt = rest & 3, s = rest >> 2;
    int co = mt*16 + (l & 15);
    int k = s*32 + (l >> 4)*8 + i;
    f16 v = (f16)0.0f;
    if (k < 432){
      int pos = k / 48, ci = k - pos*48;
      v = (f16)s4[(co*48 + ci)*9 + pos];
    }
    w4m[idx] = v;
  }
  for (int t = tid0; t < 71680; t += stride){
    int l = t & 63, rest = t >> 6;
    int nt = rest % 7, s = rest / 7;
    int j = nt*16 + (l & 15);
    int kb = s*32 + (l >> 4)*8;
    union { f16 h[8]; f16x8 v; } pk;
    #pragma unroll
    for (int i=0;i<8;++i){
      int k = kb + i;
      int row = (k & 63)*80 + (k >> 6);
      pk.h[i] = (j < 100) ? (f16)sf[(size_t)row*100 + j] : (f16)0.0f;
    }
    *(f16x8*)(wfc + (size_t)t*8) = pk.v;
  }
}

// ---------------------------------------------------------------- conv1+conv2 fused (both MFMA, pipelined)
// rgb (B,15000) f32 [w75][h200] -> a2 NHWC (Bc,47,16,36). grid=Bc*6, block=256.
// xb [w75][hh44] stride 46 (gather lane-stride 46 dw -> 16 distinct banks).
__global__ __launch_bounds__(256) void conv12_k(const float* __restrict__ rgb, const f16* __restrict__ w1m,
                                                const float* __restrict__ b1, const f16* __restrict__ w2c,
                                                const float* __restrict__ b2, f16* __restrict__ a2, int ib){
  __shared__ __align__(16) f16 xb[75*46 + 8];      // 6916 B
  __shared__ __align__(16) f16 xt[2*19*18*24];     // 32832 B
  const int tid = threadIdx.x, bx = blockIdx.x;
  const int i = bx / 6, t = bx - i*6;
  const int h0 = t*32, oh0 = t*8;
  const float* img = rgb + (size_t)(ib + i)*15000;
  // phase 0: float4 binarize staging (75 w x 11 h4-groups, hh 0..43)
  for (int idx = tid; idx < 825; idx += 256){
    int w = idx / 11, h4 = idx - w*11;
    int hh = h4*4, h = h0 + hh;
    union { f16 hv[4]; uint u[2]; } pk;
    if (h < 200){
      float4 v = *(const float4*)(img + w*200 + h);
      pk.hv[0] = (v.x > 0.f) ? (f16)1.0f : (f16)0.0f;
      pk.hv[1] = (v.y > 0.f) ? (f16)1.0f : (f16)0.0f;
      pk.hv[2] = (v.z > 0.f) ? (f16)1.0f : (f16)0.0f;
      pk.hv[3] = (v.w > 0.f) ? (f16)1.0f : (f16)0.0f;
    } else {
      pk.u[0] = 0u; pk.u[1] = 0u;
    }
    *(uint*)(xb + w*46 + hh)     = pk.u[0];   // byte 92w+8h4   : 4B aligned
    *(uint*)(xb + w*46 + hh + 2) = pk.u[1];   // +4B           : 4B aligned
  }
  __syncthreads();
  const int wv = tid >> 6, lane = tid & 63;
  const int jgrp = lane >> 4, npx = lane & 15;
  // ---- phase 1: conv1 MFMA into xt (depth-1 gather prefetch)
  {
    f16x8 a1f0 = *(const f16x8*)(w1m + (size_t)lane*8);
    f16x8 a1f1 = *(const f16x8*)(w1m + (size_t)(64 + lane)*8);
    int koff[8];
    #pragma unroll
    for (int ii=0; ii<8; ++ii){
      int k = jgrp*8 + ii;
      if (k >= 25) k = 0;
      int kw = k / 5, kh = k - kw*5;
      koff[ii] = kw*46 + kh;
    }
    f32x4 bv0, bv1;
    #pragma unroll
    for (int reg=0; reg<4; ++reg){
      int c0 = jgrp*4 + reg;
      int c1 = 16 + jgrp*4 + reg;
      bv0[reg] = b1[c0];
      bv1[reg] = (c1 < 24) ? b1[c1] : 0.f;
    }
    const int qn = (wv == 3) ? 10 : 11;   // nt = wv + 4q <= 42
    union { f16 h[8]; f16x8 v; } bqc, bqn;
    int pxt_c, rr_c, ow_c;
    {
      int pxt = wv*16 + npx;
      int px = (pxt > 683) ? 683 : pxt;
      int rr = px/36, ow = px - rr*36;
      const f16* gp = xb + 2*(ow*46 + rr);
      #pragma unroll
      for (int ii=0; ii<8; ++ii) bqc.h[ii] = gp[koff[ii]];
      pxt_c = pxt; rr_c = rr; ow_c = ow;
    }
    for (int q=0; q<qn; ++q){
      int pxt_n = 0, rr_n = 0, ow_n = 0;
      if (q+1 < qn){
        int nt = wv + 4*(q+1);
        pxt_n = nt*16 + npx;
        int px = (pxt_n > 683) ? 683 : pxt_n;
        rr_n = px/36; ow_n = px - rr_n*36;
        const f16* gp = xb + 2*(ow_n*46 + rr_n);
        #pragma unroll
        for (int ii=0; ii<8; ++ii) bqn.h[ii] = gp[koff[ii]];
      }
      f32x4 c0 = __builtin_amdgcn_mfma_f32_16x16x32_f16(a1f0, bqc.v, bv0, 0, 0, 0);
      f32x4 c1 = __builtin_amdgcn_mfma_f32_16x16x32_f16(a1f1, bqc.v, bv1, 0, 0, 0);
      if (pxt_c <= 683){
        f16* dst = xt + (((ow_c & 1)*19 + rr_c)*18 + (ow_c >> 1))*24;
        union { f16 h[4]; uint2 q2; } pk;
        #pragma unroll
        for (int reg=0; reg<4; ++reg){ float r = c0[reg]; if (r<0.f) r=0.f; pk.h[reg]=(f16)r; }
        *(uint2*)(dst + jgrp*4) = pk.q2;
        if (jgrp < 2){
          #pragma unroll
          for (int reg=0; reg<4; ++reg){ float r = c1[reg]; if (r<0.f) r=0.f; pk.h[reg]=(f16)r; }
          *(uint2*)(dst + 16 + jgrp*4) = pk.q2;
        }
      }
      if (q+1 < qn){ bqc = bqn; pxt_c = pxt_n; rr_c = rr_n; ow_c = ow_n; }
    }
  }
  __syncthreads();
  // ---- phase 2: conv2 MFMA, K-packed 19 steps, depth-1 prefetch of A/B fragments
  int baddr[19];
  #pragma unroll
  for (int s=0; s<19; ++s){
    int m = s*4 + jgrp;
    int tap = m / 3, r3 = m - tap*3;
    if (m >= 75){ tap = 24; r3 = 0; }
    int kh = tap / 5, kw = tap - kh*5;
    int par = kw & 1, kws = kw >> 1;
    baddr[s] = ((par*19 + kh)*18 + npx + kws)*24 + r3*8;
  }
  f32x4 acc2[3][2];
  #pragma unroll
  for (int mt=0; mt<3; ++mt){
    f32x4 bv;
    #pragma unroll
    for (int reg=0; reg<4; ++reg){
      int co = mt*16 + jgrp*4 + reg;
      bv[reg] = (co < 36) ? b2[co] : 0.0f;
    }
    acc2[mt][0] = bv; acc2[mt][1] = bv;
  }
  const f16* agl = w2c + (size_t)lane*8;
  const int rowo = 4*wv*432;
  f16x8 af0, af1, af2, bf0, bf1;
  {
    af0 = *(const f16x8*)(agl + 0*512);
    af1 = *(const f16x8*)(agl + 1*512);
    af2 = *(const f16x8*)(agl + 2*512);
    const f16* bb0 = xt + baddr[0] + rowo;
    bf0 = *(const f16x8*)(bb0);
    bf1 = *(const f16x8*)(bb0 + 2*432);
  }
  #pragma unroll
  for (int s=0; s<19; ++s){
    f16x8 naf0, naf1, naf2, nbf0, nbf1;
    if (s < 18){
      naf0 = *(const f16x8*)(agl + (size_t)((s+1)*3 + 0)*512);
      naf1 = *(const f16x8*)(agl + (size_t)((s+1)*3 + 1)*512);
      naf2 = *(const f16x8*)(agl + (size_t)((s+1)*3 + 2)*512);
      const f16* bb0 = xt + baddr[s+1] + rowo;
      nbf0 = *(const f16x8*)(bb0);
      nbf1 = *(const f16x8*)(bb0 + 2*432);
    }
    acc2[0][0] = __builtin_amdgcn_mfma_f32_16x16x32_f16(af0, bf0, acc2[0][0], 0, 0, 0);
    acc2[0][1] = __builtin_amdgcn_mfma_f32_16x16x32_f16(af0, bf1, acc2[0][1], 0, 0, 0);
    acc2[1][0] = __builtin_amdgcn_mfma_f32_16x16x32_f16(af1, bf0, acc2[1][0], 0, 0, 0);
    acc2[1][1] = __builtin_amdgcn_mfma_f32_16x16x32_f16(af1, bf1, acc2[1][1], 0, 0, 0);
    acc2[2][0] = __builtin_amdgcn_mfma_f32_16x16x32_f16(af2, bf0, acc2[2][0], 0, 0, 0);
    acc2[2][1] = __builtin_amdgcn_mfma_f32_16x16x32_f16(af2, bf1, acc2[2][1], 0, 0, 0);
    if (s < 18){
      af0 = naf0; af1 = naf1; af2 = naf2; bf0 = nbf0; bf1 = nbf1;
    }
  }
  #pragma unroll
  for (int u=0; u<2; ++u){
    const int oh = oh0 + 2*wv + u;
    if (oh >= 47) continue;
    #pragma unroll
    for (int mt=0; mt<3; ++mt){
      const int co0s = mt*16 + jgrp*4;
      if (co0s >= 36) continue;
      union { f16 h[4]; uint2 q; } pk;
      #pragma unroll
      for (int reg=0; reg<4; ++reg){
        float r = acc2[mt][u][reg]; if (r < 0.f) r = 0.f;
        pk.h[reg] = (f16)r;
      }
      *(uint2*)(a2 + (((size_t)i*47 + oh)*16 + npx)*36 + co0s) = pk.q;
    }
  }
}

// ---------------------------------------------------------------- conv3+conv4 fused (per half-image)
__global__ __launch_bounds__(256) void conv34_k(const f16* __restrict__ a2, const f16* __restrict__ w3m,
                                                const float* __restrict__ b3, const f16* __restrict__ w4m,
                                                const float* __restrict__ b4, f16* __restrict__ a4){
  __shared__ __align__(16) f16 xt[27*680];     // 36720 B
  __shared__ __align__(16) f16 a3t[12*6*56];   // 8064 B
  const int tid = threadIdx.x, bx = blockIdx.x;
  const int i = bx >> 1, t = bx & 1;
  const int r0 = t*20, obase = t*10;
  {
    const uint2* s2 = (const uint2*)((const uint*)a2 + (size_t)i*13536);
    uint2* d = (uint2*)xt;
    for (int idx = tid; idx < 3888; idx += 256){
      int d2 = idx % 9, rc = idx / 9;
      int c = rc & 15, r = rc >> 4;
      int dwi = d2*2, jg = dwi >> 2, part = dwi & 3;
      d[(r*340 + jg*68 + c*4 + part) >> 1] = s2[((size_t)(r0 + r)*16 + c)*9 + d2];
    }
  }
  __syncthreads();
  const int wv = tid >> 6, lane = tid & 63;
  const int npx = lane & 15, jg = lane >> 4;
  {
    int baseq[2], ohl[2], owl[2];
    #pragma unroll
    for (int q=0;q<2;++q){
      int px = (wv*2+q)*16 + npx; if (px > 71) px = 71;
      ohl[q] = px/6; owl[q] = px - ohl[q]*6;
      baseq[q] = 2*ohl[q]*680 + jg*136 + 2*owl[q]*8;
    }
    f32x4 acc[3][2];
    #pragma unroll
    for (int mt=0;mt<3;++mt){
      f32x4 bv;
      #pragma unroll
      for (int reg=0;reg<4;++reg) bv[reg] = b3[mt*16 + jg*4 + reg];
      acc[mt][0]=bv; acc[mt][1]=bv;
    }
    const f16* agl = w3m + (size_t)lane*8;
    #pragma unroll 1
    for (int kh=0; kh<5; ++kh){
      #pragma unroll
      for (int kw=0; kw<5; ++kw){
        const int s = kh*5 + kw;
        f16x8 af[3];
        #pragma unroll
        for (int mt=0;mt<3;++mt)
          af[mt] = *(const f16x8*)(agl + (size_t)(s*3 + mt)*512);
        f16x8 bf[2];
        #pragma unroll
        for (int q=0;q<2;++q)
          bf[q] = *(const f16x8*)(xt + baseq[q] + kh*680 + kw*8);
        #pragma unroll
        for (int mt=0;mt<3;++mt)
          #pragma unroll
          for (int q=0;q<2;++q)
            acc[mt][q] = __builtin_amdgcn_mfma_f32_16x16x32_f16(af[mt], bf[q], acc[mt][q], 0, 0, 0);
      }
    }
    #pragma unroll
    for (int e=0;e<4;++e){
      const int s = 25 + e;
      f16x8 af[3];
      #pragma unroll
      for (int mt=0;mt<3;++mt)
        af[mt] = *(const f16x8*)(agl + (size_t)(s*3 + mt)*512);
      int p1 = e*8 + jg*2; int p2 = p1 + 1;
      if (p1 > 24) p1 = 24;
      if (p2 > 24) p2 = 24;
      const int kh1 = p1/5, kw1 = p1 - kh1*5;
      const int kh2 = p2/5, kw2 = p2 - kh2*5;
      #pragma unroll
      for (int q=0;q<2;++q){
        f16x4 lo = *(const f16x4*)(xt + (2*ohl[q]+kh1)*680 + 544 + (2*owl[q]+kw1)*8);
        f16x4 hi = *(const f16x4*)(xt + (2*ohl[q]+kh2)*680 + 544 + (2*owl[q]+kw2)*8);
        f16x8 bq = __builtin_shufflevector(lo, hi, 0,1,2,3,4,5,6,7);
        #pragma unroll
        for (int mt=0;mt<3;++mt)
          acc[mt][q] = __builtin_amdgcn_mfma_f32_16x16x32_f16(af[mt], bq, acc[mt][q], 0, 0, 0);
      }
    }
    #pragma unroll
    for (int q=0;q<2;++q){
      int px = (wv*2+q)*16 + npx;
      if (px >= 72) continue;
      #pragma unroll
      for (int mt=0;mt<3;++mt){
        union { f16 h[4]; uint2 q2; } pk;
        #pragma unroll
        for (int reg=0;reg<4;++reg){
          float r = acc[mt][q][reg]; if (r < 0.f) r = 0.f;
          pk.h[reg] = (f16)r;
        }
        *(uint2*)(a3t + px*56 + mt*16 + jg*4) = pk.q2;
      }
    }
  }
  __syncthreads();
  {
    f32x4 acc4[3];
    {
      f32x4 bv;
      #pragma unroll
      for (int reg=0;reg<4;++reg) bv[reg] = b4[wv*16 + jg*4 + reg];
      acc4[0]=bv; acc4[1]=bv; acc4[2]=bv;
    }
    int ohn[3], own[3];
    #pragma unroll
    for (int nt=0;nt<3;++nt){
      int px = nt*16 + npx; if (px > 39) px = 39;
      ohn[nt] = px >> 2; own[nt] = px & 3;
    }
    const f16* agl = w4m + (size_t)lane*8;
    #pragma unroll 1
    for (int s=0; s<14; ++s){
      f16x8 af = *(const f16x8*)(agl + (size_t)(s*4 + wv)*512);
      int k8 = s*32 + jg*8;
      int pos, ci0;
      if (k8 >= 432){ pos = 8; ci0 = 40; }
      else { pos = k8 / 48; ci0 = k8 - pos*48; }
      const int kh = pos/3, kw = pos - kh*3;
      #pragma unroll
      for (int nt=0;nt<3;++nt){
        const int r = ohn[nt] + kh, c = own[nt] + kw;
        f16x8 bq = *(const f16x8*)(a3t + (r*6 + c)*56 + ci0);
        acc4[nt] = __builtin_amdgcn_mfma_f32_16x16x32_f16(af, bq, acc4[nt], 0, 0, 0);
      }
    }
    #pragma unroll
    for (int nt=0;nt<3;++nt){
      int px = nt*16 + npx;
      if (px >= 40) continue;
      union { f16 h[4]; uint2 q2; } pk;
      #pragma unroll
      for (int reg=0;reg<4;++reg){
        float r = acc4[nt][reg]; if (r < 0.f) r = 0.f;
        pk.h[reg] = (f16)r;
      }
      *(uint2*)(a4 + ((size_t)i*80 + obase*4 + px)*64 + wv*16 + jg*4) = pk.q2;
    }
  }
}

// ---------------------------------------------------------------- fc1 (MFMA) + fc2..fc4 + AEBS fused
__global__ __launch_bounds__(256) void fc1tail_k(const f16* __restrict__ a4, const f16* __restrict__ w1m,
    const float* __restrict__ fc1b, const float* __restrict__ dist, const float* __restrict__ speed,
    const float* __restrict__ fW2, const float* __restrict__ fb2,
    const float* __restrict__ fW3, const float* __restrict__ fb3,
    const float* __restrict__ fW4, const float* __restrict__ fb4,
    const float* __restrict__ aW1, const float* __restrict__ ab1,
    const float* __restrict__ aW2, const float* __restrict__ ab2,
    const float* __restrict__ aW3, const float* __restrict__ ab3,
    float* __restrict__ out, int ib, int n){
  __shared__ float red[4][64][28];
  __shared__ float x1s[8][100];
  __shared__ float h2s[8][50];
  __shared__ float h3s[8][10];
  __shared__ float stg[8];
  __shared__ float hb1[8][12];
  __shared__ float hb2[8][24];
  const int tid = threadIdx.x;
  const int wv = tid >> 6, lane = tid & 63;
  const int img0 = blockIdx.x*8;
  f32x4 acc[7];
  #pragma unroll
  for (int nt=0;nt<7;++nt) acc[nt] = (f32x4){0.f,0.f,0.f,0.f};
  int ia = img0 + (lane & 15);
  if (ia > n-1) ia = n-1;
  const f16* ap = a4 + (size_t)ia*5120 + (lane >> 4)*8;
  const f16* bp = w1m + (size_t)lane*8;
  #pragma unroll 1
  for (int s = wv*40; s < wv*40 + 40; ++s){
    f16x8 av = *(const f16x8*)(ap + s*32);
    #pragma unroll
    for (int nt=0;nt<7;++nt){
      f16x8 bv = *(const f16x8*)(bp + (size_t)(s*7 + nt)*512);
      acc[nt] = __builtin_amdgcn_mfma_f32_16x16x32_f16(av, bv, acc[nt], 0, 0, 0);
    }
  }
  #pragma unroll
  for (int nt=0;nt<7;++nt)
    #pragma unroll
    for (int reg=0;reg<4;++reg)
      red[wv][lane][nt*4+reg] = acc[nt][reg];
  __syncthreads();
  for (int idx = tid; idx < 896; idx += 256){
    int imgl = idx / 112, j = idx - imgl*112;
    if (j >= 100) continue;
    int l = ((imgl >> 2) << 4) | (j & 15);
    int c = (j >> 4)*4 + (imgl & 3);
    float s = red[0][l][c] + red[1][l][c] + red[2][l][c] + red[3][l][c] + fc1b[j];
    x1s[imgl][j] = s > 0.f ? s : 0.f;
  }
  __syncthreads();
  const int g = tid >> 5, l32 = tid & 31;
  const int img = ib + img0 + g;
  for (int j = l32; j < 50; j += 32){
    float s = fb2[j];
    #pragma unroll 4
    for (int k = 0; k < 100; ++k) s = fmaf(x1s[g][k], fW2[k*50+j], s);
    h2s[g][j] = s > 0.f ? s : 0.f;
  }
  __syncthreads();
  if (l32 < 10){
    float s = fb3[l32];
    #pragma unroll
    for (int k = 0; k < 50; ++k) s = fmaf(h2s[g][k], fW3[k*10+l32], s);
    h3s[g][l32] = s > 0.f ? s : 0.f;
  }
  __syncthreads();
  if (l32 == 0){
    float s = fb4[0];
    #pragma unroll
    for (int k = 0; k < 10; ++k) s = fmaf(h3s[g][k], fW4[k], s);
    stg[g] = s;
  }
  __syncthreads();
  if (l32 < 12){
    float s0 = stg[g], dd = dist[img], sp = speed[img];
    float s = ab1[l32] + s0*aW1[l32] + dd*aW1[12+l32] + sp*aW1[24+l32];
    hb1[g][l32] = s > 0.f ? s : 0.f;
  }
  __syncthreads();
  if (l32 < 24){
    float s = ab2[l32];
    #pragma unroll
    for (int k=0;k<12;++k) s = fmaf(hb1[g][k], aW2[k*24+l32], s);
    hb2[g][l32] = s > 0.f ? s : 0.f;
  }
  __syncthreads();
  if (l32 < 4){
    float s = ab3[l32];
    #pragma unroll
    for (int k=0;k<24;++k) s = fmaf(hb2[g][k], aW3[k*4+l32], s);
    out[(size_t)img*4 + l32] = s;
  }
}

// ================================================================ host
extern "C" void kernel_launch(void* const* d_in, const int* in_sizes, int n_in,
                              void* d_out, int out_size, void* d_ws, size_t ws_size,
                              hipStream_t stream){
  const float* rgb   = (const float*)d_in[0];
  const float* dist  = (const float*)d_in[1];
  const float* speed = (const float*)d_in[2];
  const float* cw1 = (const float*)d_in[3];
  const float* cb1 = (const float*)d_in[4];
  const float* cw2 = (const float*)d_in[5];
  const float* cb2 = (const float*)d_in[6];
  const float* cw3 = (const float*)d_in[7];
  const float* cb3 = (const float*)d_in[8];
  const float* cw4 = (const float*)d_in[9];
  const float* cb4 = (const float*)d_in[10];
  const float* fW1 = (const float*)d_in[11];
  const float* fb1 = (const float*)d_in[12];
  const float* fW2 = (const float*)d_in[13];
  const float* fb2 = (const float*)d_in[14];
  const float* fW3 = (const float*)d_in[15];
  const float* fb3 = (const float*)d_in[16];
  const float* fW4 = (const float*)d_in[17];
  const float* fb4 = (const float*)d_in[18];
  const float* aW1 = (const float*)d_in[19];
  const float* ab1 = (const float*)d_in[20];
  const float* aW2 = (const float*)d_in[21];
  const float* ab2 = (const float*)d_in[22];
  const float* aW3 = (const float*)d_in[23];
  const float* ab3 = (const float*)d_in[24];
  float* out = (float*)d_out;
  const int B = in_sizes[0] / 15000;

  auto ALN = [](size_t x){ return (x + 255) & ~(size_t)255; };
  const size_t fixed = ALN(2048) + ALN(58368) + ALN(89088) + ALN(57344) + ALN(1146880);

  int nc = 1;
  while (nc < 32){
    size_t Bc = (size_t)(B / nc);
    size_t need = fixed + ALN(Bc*54144) + ALN(Bc*10240);
    if (need <= ws_size) break;
    nc *= 2;
  }
  const int Bc = B / nc;

  char* ws = (char*)d_ws;
  size_t o = 0;
  auto alloc = [&](size_t bytes)->char*{ char* p = ws + o; o += ALN(bytes); return p; };
  f16* w1c = (f16*)alloc(2048);
  f16* w2c = (f16*)alloc(58368);
  f16* w3m = (f16*)alloc(89088);
  f16* w4m = (f16*)alloc(57344);
  f16* w1m = (f16*)alloc(1146880);
  f16* a2  = (f16*)alloc((size_t)Bc*54144);
  f16* a4  = (f16*)alloc((size_t)Bc*10240);

  repack_all_k<<<dim3(280), dim3(256), 0, stream>>>(w1c, w2c, w3m, w4m, w1m,
                                                    cw1, cw2, cw3, cw4, fW1);

  for (int c = 0; c < nc; ++c){
    const int ib = c*Bc;
    conv12_k<<<dim3(Bc*6),  dim3(256), 0, stream>>>(rgb, w1c, cb1, w2c, cb2, a2, ib);
    conv34_k<<<dim3(Bc*2),  dim3(256), 0, stream>>>(a2, w3m, cb3, w4m, cb4, a4);
    fc1tail_k<<<dim3(Bc/8), dim3(256), 0, stream>>>(a4, w1m, fb1, dist, speed,
        fW2, fb2, fW3, fb3, fW4, fb4, aW1, ab1, aW2, ab2, aW3, ab3, out, ib, Bc);
  }
}

// Round 14
// 170.573 us; speedup vs baseline: 1.2370x; 1.0029x over previous
//
#include <hip/hip_runtime.h>

typedef _Float16 f16;
typedef _Float16 f16x4 __attribute__((ext_vector_type(4)));
typedef _Float16 f16x8 __attribute__((ext_vector_type(8)));
typedef float f32x4 __attribute__((ext_vector_type(4)));

// ---------------------------------------------------------------- merged weight repack (all MFMA fragments)
// w1c: [mt2][lane64][8], PERMUTED taps (must match conv12 phase-1 gather):
//   jgrp0: ii0-3=(kw0,kh0-3) ii4-7=(kw1,kh0-3); jgrp1: kw2,kw3 same;
//   jgrp2: ii0-3=(kw4,kh0-3), ii4=(kw0,kh4), ii5=(kw1,kh4), ii6-7=0;
//   jgrp3: ii0=(kw4,kh4), ii4=(kw2,kh4), ii5=(kw3,kh4), rest 0.
__global__ __launch_bounds__(256) void repack_all_k(
    f16* __restrict__ w1c, f16* __restrict__ w2c, f16* __restrict__ w3m,
    f16* __restrict__ w4m, f16* __restrict__ wfc,
    const float* __restrict__ s1, const float* __restrict__ s2, const float* __restrict__ s3,
    const float* __restrict__ s4, const float* __restrict__ sf){
  const int tid0 = blockIdx.x*256 + threadIdx.x, stride = gridDim.x*256;
  for (int idx = tid0; idx < 1024; idx += stride){
    int i = idx & 7, l = (idx >> 3) & 63, mt = idx >> 9;
    int co = mt*16 + (l & 15);
    int jg = l >> 4;
    int kw = -1, kh = 0;
    if (jg < 2){ kw = jg*2 + (i >> 2); kh = i & 3; }
    else if (jg == 2){
      if (i < 4){ kw = 4; kh = i; }
      else if (i == 4){ kw = 0; kh = 4; }
      else if (i == 5){ kw = 1; kh = 4; }
    } else {
      if (i == 0){ kw = 4; kh = 4; }
      else if (i == 4){ kw = 2; kh = 4; }
      else if (i == 5){ kw = 3; kh = 4; }
    }
    f16 v = (f16)0.0f;
    if (co < 24 && kw >= 0) v = (f16)s1[co*25 + kh*5 + kw];
    w1c[idx] = v;
  }
  for (int idx = tid0; idx < 29184; idx += stride){
    int i = idx & 7, l = (idx >> 3) & 63, rest = idx >> 9;
    int mt = rest % 3, s = rest / 3;
    int co = mt*16 + (l & 15);
    int k = s*32 + (l >> 4)*8 + i;
    f16 v = (f16)0.0f;
    if (co < 36 && k < 600){
      int tap = k / 24, ci = k - tap*24;
      v = (f16)s2[(co*24 + ci)*25 + tap];
    }
    w2c[idx] = v;
  }
  for (int idx = tid0; idx < 44544; idx += stride){
    int i = idx & 7, l = (idx >> 3) & 63, rest = idx >> 9;
    int mt = rest % 3, s = rest / 3;
    int co = mt*16 + (l & 15);
    f16 v = (f16)0.0f;
    if (s < 25){
      int ci = (l >> 4)*8 + i;
      v = (f16)s3[(co*36 + ci)*25 + s];
    } else {
      int ke = (s - 25)*32 + (l >> 4)*8 + i;
      if (ke < 100){
        int p = ke >> 2, ci = 32 + (ke & 3);
        v = (f16)s3[(co*36 + ci)*25 + p];
      }
    }
    w3m[idx] = v;
  }
  for (int idx = tid0; idx < 28672; idx += stride){
    int i = idx & 7, l = (idx >> 3) & 63, rest = idx >> 9;
    int mt = rest & 3, s = rest >> 2;
    int co = mt*16 + (l & 15);
    int k = s*32 + (l >> 4)*8 + i;
    f16 v = (f16)0.0f;
    if (k < 432){
      int pos = k / 48, ci = k - pos*48;
      v = (f16)s4[(co*48 + ci)*9 + pos];
    }
    w4m[idx] = v;
  }
  for (int t = tid0; t < 71680; t += stride){
    int l = t & 63, rest = t >> 6;
    int nt = rest % 7, s = rest / 7;
    int j = nt*16 + (l & 15);
    int kb = s*32 + (l >> 4)*8;
    union { f16 h[8]; f16x8 v; } pk;
    #pragma unroll
    for (int i=0;i<8;++i){
      int k = kb + i;
      int row = (k & 63)*80 + (k >> 6);
      pk.h[i] = (j < 100) ? (f16)sf[(size_t)row*100 + j] : (f16)0.0f;
    }
    *(f16x8*)(wfc + (size_t)t*8) = pk.v;
  }
}

// ---------------------------------------------------------------- conv1+conv2 fused (both MFMA, pipelined)
// rgb (B,15000) f32 [w75][h200] -> a2 NHWC (Bc,47,16,36). grid=Bc*6, block=256.
// xb [w75][hh44] stride 46. Phase-1 B-gather: 4 x ds_read_b32 + 2 x u16 (K-permuted, matches w1c).
__global__ __launch_bounds__(256) void conv12_k(const float* __restrict__ rgb, const f16* __restrict__ w1m,
                                                const float* __restrict__ b1, const f16* __restrict__ w2c,
                                                const float* __restrict__ b2, f16* __restrict__ a2, int ib){
  __shared__ __align__(16) f16 xb[75*46 + 8];      // 6916 B
  __shared__ __align__(16) f16 xt[2*19*18*24];     // 32832 B
  const int tid = threadIdx.x, bx = blockIdx.x;
  const int i = bx / 6, t = bx - i*6;
  const int h0 = t*32, oh0 = t*8;
  const float* img = rgb + (size_t)(ib + i)*15000;
  // phase 0: float4 binarize staging (75 w x 11 h4-groups, hh 0..43)
  for (int idx = tid; idx < 825; idx += 256){
    int w = idx / 11, h4 = idx - w*11;
    int hh = h4*4, h = h0 + hh;
    union { f16 hv[4]; uint u[2]; } pk;
    if (h < 200){
      float4 v = *(const float4*)(img + w*200 + h);
      pk.hv[0] = (v.x > 0.f) ? (f16)1.0f : (f16)0.0f;
      pk.hv[1] = (v.y > 0.f) ? (f16)1.0f : (f16)0.0f;
      pk.hv[2] = (v.z > 0.f) ? (f16)1.0f : (f16)0.0f;
      pk.hv[3] = (v.w > 0.f) ? (f16)1.0f : (f16)0.0f;
    } else {
      pk.u[0] = 0u; pk.u[1] = 0u;
    }
    *(uint*)(xb + w*46 + hh)     = pk.u[0];
    *(uint*)(xb + w*46 + hh + 2) = pk.u[1];
  }
  __syncthreads();
  const int wv = tid >> 6, lane = tid & 63;
  const int jgrp = lane >> 4, npx = lane & 15;
  // ---- phase 1: conv1 MFMA into xt (6-read gather, depth-1 prefetch)
  {
    f16x8 a1f0 = *(const f16x8*)(w1m + (size_t)lane*8);
    f16x8 a1f1 = *(const f16x8*)(w1m + (size_t)(64 + lane)*8);
    // per-lane gather offset table (f16 units); all even except E/F which are u16 reads
    const int tA = (jgrp < 2) ? jgrp*92 : ((jgrp == 2) ? 184 : 188);
    const int tC = (jgrp == 1) ? 138 : 46;
    const int tE = (jgrp == 2) ? 4  : ((jgrp == 3) ? 96  : 0);
    const int tF = (jgrp == 2) ? 50 : ((jgrp == 3) ? 142 : 0);
    f32x4 bv0, bv1;
    #pragma unroll
    for (int reg=0; reg<4; ++reg){
      int c0 = jgrp*4 + reg;
      int c1 = 16 + jgrp*4 + reg;
      bv0[reg] = b1[c0];
      bv1[reg] = (c1 < 24) ? b1[c1] : 0.f;
    }
    const int qn = (wv == 3) ? 10 : 11;   // nt = wv + 4q <= 42
    union { uint d[4]; f16x8 v; } bqc, bqn;
    int pxt_c, rr_c, ow_c;
    {
      int pxt = wv*16 + npx;
      int px = (pxt > 683) ? 683 : pxt;
      int rr = px/36, ow = px - rr*36;
      const int base = 2*(ow*46 + rr);
      uint ra = *(const uint*)(xb + base + tA);
      uint rb = *(const uint*)(xb + base + tA + 2);
      uint rc = *(const uint*)(xb + base + tC);
      uint rd = *(const uint*)(xb + base + tC + 2);
      uint re = *(const unsigned short*)(xb + base + tE);
      uint rf = *(const unsigned short*)(xb + base + tF);
      bqc.d[0] = ra; bqc.d[1] = rb;
      bqc.d[2] = (jgrp < 2) ? rc : (re | (rf << 16));
      bqc.d[3] = rd;
      pxt_c = pxt; rr_c = rr; ow_c = ow;
    }
    for (int q=0; q<qn; ++q){
      int pxt_n = 0, rr_n = 0, ow_n = 0;
      if (q+1 < qn){
        int nt = wv + 4*(q+1);
        pxt_n = nt*16 + npx;
        int px = (pxt_n > 683) ? 683 : pxt_n;
        rr_n = px/36; ow_n = px - rr_n*36;
        const int base = 2*(ow_n*46 + rr_n);
        uint ra = *(const uint*)(xb + base + tA);
        uint rb = *(const uint*)(xb + base + tA + 2);
        uint rc = *(const uint*)(xb + base + tC);
        uint rd = *(const uint*)(xb + base + tC + 2);
        uint re = *(const unsigned short*)(xb + base + tE);
        uint rf = *(const unsigned short*)(xb + base + tF);
        bqn.d[0] = ra; bqn.d[1] = rb;
        bqn.d[2] = (jgrp < 2) ? rc : (re | (rf << 16));
        bqn.d[3] = rd;
      }
      f32x4 c0 = __builtin_amdgcn_mfma_f32_16x16x32_f16(a1f0, bqc.v, bv0, 0, 0, 0);
      f32x4 c1 = __builtin_amdgcn_mfma_f32_16x16x32_f16(a1f1, bqc.v, bv1, 0, 0, 0);
      if (pxt_c <= 683){
        f16* dst = xt + (((ow_c & 1)*19 + rr_c)*18 + (ow_c >> 1))*24;
        union { f16 h[4]; uint2 q2; } pk;
        #pragma unroll
        for (int reg=0; reg<4; ++reg){ float r = c0[reg]; if (r<0.f) r=0.f; pk.h[reg]=(f16)r; }
        *(uint2*)(dst + jgrp*4) = pk.q2;
        if (jgrp < 2){
          #pragma unroll
          for (int reg=0; reg<4; ++reg){ float r = c1[reg]; if (r<0.f) r=0.f; pk.h[reg]=(f16)r; }
          *(uint2*)(dst + 16 + jgrp*4) = pk.q2;
        }
      }
      if (q+1 < qn){ bqc.v = bqn.v; pxt_c = pxt_n; rr_c = rr_n; ow_c = ow_n; }
    }
  }
  __syncthreads();
  // ---- phase 2: conv2 MFMA, K-packed 19 steps, depth-1 prefetch of A/B fragments
  int baddr[19];
  #pragma unroll
  for (int s=0; s<19; ++s){
    int m = s*4 + jgrp;
    int tap = m / 3, r3 = m - tap*3;
    if (m >= 75){ tap = 24; r3 = 0; }
    int kh = tap / 5, kw = tap - kh*5;
    int par = kw & 1, kws = kw >> 1;
    baddr[s] = ((par*19 + kh)*18 + npx + kws)*24 + r3*8;
  }
  f32x4 acc2[3][2];
  #pragma unroll
  for (int mt=0; mt<3; ++mt){
    f32x4 bv;
    #pragma unroll
    for (int reg=0; reg<4; ++reg){
      int co = mt*16 + jgrp*4 + reg;
      bv[reg] = (co < 36) ? b2[co] : 0.0f;
    }
    acc2[mt][0] = bv; acc2[mt][1] = bv;
  }
  const f16* agl = w2c + (size_t)lane*8;
  const int rowo = 4*wv*432;
  f16x8 af0, af1, af2, bf0, bf1;
  {
    af0 = *(const f16x8*)(agl + 0*512);
    af1 = *(const f16x8*)(agl + 1*512);
    af2 = *(const f16x8*)(agl + 2*512);
    const f16* bb0 = xt + baddr[0] + rowo;
    bf0 = *(const f16x8*)(bb0);
    bf1 = *(const f16x8*)(bb0 + 2*432);
  }
  #pragma unroll
  for (int s=0; s<19; ++s){
    f16x8 naf0, naf1, naf2, nbf0, nbf1;
    if (s < 18){
      naf0 = *(const f16x8*)(agl + (size_t)((s+1)*3 + 0)*512);
      naf1 = *(const f16x8*)(agl + (size_t)((s+1)*3 + 1)*512);
      naf2 = *(const f16x8*)(agl + (size_t)((s+1)*3 + 2)*512);
      const f16* bb0 = xt + baddr[s+1] + rowo;
      nbf0 = *(const f16x8*)(bb0);
      nbf1 = *(const f16x8*)(bb0 + 2*432);
    }
    acc2[0][0] = __builtin_amdgcn_mfma_f32_16x16x32_f16(af0, bf0, acc2[0][0], 0, 0, 0);
    acc2[0][1] = __builtin_amdgcn_mfma_f32_16x16x32_f16(af0, bf1, acc2[0][1], 0, 0, 0);
    acc2[1][0] = __builtin_amdgcn_mfma_f32_16x16x32_f16(af1, bf0, acc2[1][0], 0, 0, 0);
    acc2[1][1] = __builtin_amdgcn_mfma_f32_16x16x32_f16(af1, bf1, acc2[1][1], 0, 0, 0);
    acc2[2][0] = __builtin_amdgcn_mfma_f32_16x16x32_f16(af2, bf0, acc2[2][0], 0, 0, 0);
    acc2[2][1] = __builtin_amdgcn_mfma_f32_16x16x32_f16(af2, bf1, acc2[2][1], 0, 0, 0);
    if (s < 18){
      af0 = naf0; af1 = naf1; af2 = naf2; bf0 = nbf0; bf1 = nbf1;
    }
  }
  #pragma unroll
  for (int u=0; u<2; ++u){
    const int oh = oh0 + 2*wv + u;
    if (oh >= 47) continue;
    #pragma unroll
    for (int mt=0; mt<3; ++mt){
      const int co0s = mt*16 + jgrp*4;
      if (co0s >= 36) continue;
      union { f16 h[4]; uint2 q; } pk;
      #pragma unroll
      for (int reg=0; reg<4; ++reg){
        float r = acc2[mt][u][reg]; if (r < 0.f) r = 0.f;
        pk.h[reg] = (f16)r;
      }
      *(uint2*)(a2 + (((size_t)i*47 + oh)*16 + npx)*36 + co0s) = pk.q;
    }
  }
}

// ---------------------------------------------------------------- conv3+conv4 fused (per half-image)
__global__ __launch_bounds__(256) void conv34_k(const f16* __restrict__ a2, const f16* __restrict__ w3m,
                                                const float* __restrict__ b3, const f16* __restrict__ w4m,
                                                const float* __restrict__ b4, f16* __restrict__ a4){
  __shared__ __align__(16) f16 xt[27*680];     // 36720 B
  __shared__ __align__(16) f16 a3t[12*6*56];   // 8064 B
  const int tid = threadIdx.x, bx = blockIdx.x;
  const int i = bx >> 1, t = bx & 1;
  const int r0 = t*20, obase = t*10;
  {
    const uint2* s2 = (const uint2*)((const uint*)a2 + (size_t)i*13536);
    uint2* d = (uint2*)xt;
    for (int idx = tid; idx < 3888; idx += 256){
      int d2 = idx % 9, rc = idx / 9;
      int c = rc & 15, r = rc >> 4;
      int dwi = d2*2, jg = dwi >> 2, part = dwi & 3;
      d[(r*340 + jg*68 + c*4 + part) >> 1] = s2[((size_t)(r0 + r)*16 + c)*9 + d2];
    }
  }
  __syncthreads();
  const int wv = tid >> 6, lane = tid & 63;
  const int npx = lane & 15, jg = lane >> 4;
  {
    int baseq[2], ohl[2], owl[2];
    #pragma unroll
    for (int q=0;q<2;++q){
      int px = (wv*2+q)*16 + npx; if (px > 71) px = 71;
      ohl[q] = px/6; owl[q] = px - ohl[q]*6;
      baseq[q] = 2*ohl[q]*680 + jg*136 + 2*owl[q]*8;
    }
    f32x4 acc[3][2];
    #pragma unroll
    for (int mt=0;mt<3;++mt){
      f32x4 bv;
      #pragma unroll
      for (int reg=0;reg<4;++reg) bv[reg] = b3[mt*16 + jg*4 + reg];
      acc[mt][0]=bv; acc[mt][1]=bv;
    }
    const f16* agl = w3m + (size_t)lane*8;
    #pragma unroll 1
    for (int kh=0; kh<5; ++kh){
      #pragma unroll
      for (int kw=0; kw<5; ++kw){
        const int s = kh*5 + kw;
        f16x8 af[3];
        #pragma unroll
        for (int mt=0;mt<3;++mt)
          af[mt] = *(const f16x8*)(agl + (size_t)(s*3 + mt)*512);
        f16x8 bf[2];
        #pragma unroll
        for (int q=0;q<2;++q)
          bf[q] = *(const f16x8*)(xt + baseq[q] + kh*680 + kw*8);
        #pragma unroll
        for (int mt=0;mt<3;++mt)
          #pragma unroll
          for (int q=0;q<2;++q)
            acc[mt][q] = __builtin_amdgcn_mfma_f32_16x16x32_f16(af[mt], bf[q], acc[mt][q], 0, 0, 0);
      }
    }
    #pragma unroll
    for (int e=0;e<4;++e){
      const int s = 25 + e;
      f16x8 af[3];
      #pragma unroll
      for (int mt=0;mt<3;++mt)
        af[mt] = *(const f16x8*)(agl + (size_t)(s*3 + mt)*512);
      int p1 = e*8 + jg*2; int p2 = p1 + 1;
      if (p1 > 24) p1 = 24;
      if (p2 > 24) p2 = 24;
      const int kh1 = p1/5, kw1 = p1 - kh1*5;
      const int kh2 = p2/5, kw2 = p2 - kh2*5;
      #pragma unroll
      for (int q=0;q<2;++q){
        f16x4 lo = *(const f16x4*)(xt + (2*ohl[q]+kh1)*680 + 544 + (2*owl[q]+kw1)*8);
        f16x4 hi = *(const f16x4*)(xt + (2*ohl[q]+kh2)*680 + 544 + (2*owl[q]+kw2)*8);
        f16x8 bq = __builtin_shufflevector(lo, hi, 0,1,2,3,4,5,6,7);
        #pragma unroll
        for (int mt=0;mt<3;++mt)
          acc[mt][q] = __builtin_amdgcn_mfma_f32_16x16x32_f16(af[mt], bq, acc[mt][q], 0, 0, 0);
      }
    }
    #pragma unroll
    for (int q=0;q<2;++q){
      int px = (wv*2+q)*16 + npx;
      if (px >= 72) continue;
      #pragma unroll
      for (int mt=0;mt<3;++mt){
        union { f16 h[4]; uint2 q2; } pk;
        #pragma unroll
        for (int reg=0;reg<4;++reg){
          float r = acc[mt][q][reg]; if (r < 0.f) r = 0.f;
          pk.h[reg] = (f16)r;
        }
        *(uint2*)(a3t + px*56 + mt*16 + jg*4) = pk.q2;
      }
    }
  }
  __syncthreads();
  {
    f32x4 acc4[3];
    {
      f32x4 bv;
      #pragma unroll
      for (int reg=0;reg<4;++reg) bv[reg] = b4[wv*16 + jg*4 + reg];
      acc4[0]=bv; acc4[1]=bv; acc4[2]=bv;
    }
    int ohn[3], own[3];
    #pragma unroll
    for (int nt=0;nt<3;++nt){
      int px = nt*16 + npx; if (px > 39) px = 39;
      ohn[nt] = px >> 2; own[nt] = px & 3;
    }
    const f16* agl = w4m + (size_t)lane*8;
    #pragma unroll 1
    for (int s=0; s<14; ++s){
      f16x8 af = *(const f16x8*)(agl + (size_t)(s*4 + wv)*512);
      int k8 = s*32 + jg*8;
      int pos, ci0;
      if (k8 >= 432){ pos = 8; ci0 = 40; }
      else { pos = k8 / 48; ci0 = k8 - pos*48; }
      const int kh = pos/3, kw = pos - kh*3;
      #pragma unroll
      for (int nt=0;nt<3;++nt){
        const int r = ohn[nt] + kh, c = own[nt] + kw;
        f16x8 bq = *(const f16x8*)(a3t + (r*6 + c)*56 + ci0);
        acc4[nt] = __builtin_amdgcn_mfma_f32_16x16x32_f16(af, bq, acc4[nt], 0, 0, 0);
      }
    }
    #pragma unroll
    for (int nt=0;nt<3;++nt){
      int px = nt*16 + npx;
      if (px >= 40) continue;
      union { f16 h[4]; uint2 q2; } pk;
      #pragma unroll
      for (int reg=0;reg<4;++reg){
        float r = acc4[nt][reg]; if (r < 0.f) r = 0.f;
        pk.h[reg] = (f16)r;
      }
      *(uint2*)(a4 + ((size_t)i*80 + obase*4 + px)*64 + wv*16 + jg*4) = pk.q2;
    }
  }
}

// ---------------------------------------------------------------- fc1 (MFMA) + fc2..fc4 + AEBS fused
__global__ __launch_bounds__(256) void fc1tail_k(const f16* __restrict__ a4, const f16* __restrict__ w1m,
    const float* __restrict__ fc1b, const float* __restrict__ dist, const float* __restrict__ speed,
    const float* __restrict__ fW2, const float* __restrict__ fb2,
    const float* __restrict__ fW3, const float* __restrict__ fb3,
    const float* __restrict__ fW4, const float* __restrict__ fb4,
    const float* __restrict__ aW1, const float* __restrict__ ab1,
    const float* __restrict__ aW2, const float* __restrict__ ab2,
    const float* __restrict__ aW3, const float* __restrict__ ab3,
    float* __restrict__ out, int ib, int n){
  __shared__ float red[4][64][28];
  __shared__ float x1s[8][100];
  __shared__ float h2s[8][50];
  __shared__ float h3s[8][10];
  __shared__ float stg[8];
  __shared__ float hb1[8][12];
  __shared__ float hb2[8][24];
  const int tid = threadIdx.x;
  const int wv = tid >> 6, lane = tid & 63;
  const int img0 = blockIdx.x*8;
  f32x4 acc[7];
  #pragma unroll
  for (int nt=0;nt<7;++nt) acc[nt] = (f32x4){0.f,0.f,0.f,0.f};
  int ia = img0 + (lane & 15);
  if (ia > n-1) ia = n-1;
  const f16* ap = a4 + (size_t)ia*5120 + (lane >> 4)*8;
  const f16* bp = w1m + (size_t)lane*8;
  #pragma unroll 1
  for (int s = wv*40; s < wv*40 + 40; ++s){
    f16x8 av = *(const f16x8*)(ap + s*32);
    #pragma unroll
    for (int nt=0;nt<7;++nt){
      f16x8 bv = *(const f16x8*)(bp + (size_t)(s*7 + nt)*512);
      acc[nt] = __builtin_amdgcn_mfma_f32_16x16x32_f16(av, bv, acc[nt], 0, 0, 0);
    }
  }
  #pragma unroll
  for (int nt=0;nt<7;++nt)
    #pragma unroll
    for (int reg=0;reg<4;++reg)
      red[wv][lane][nt*4+reg] = acc[nt][reg];
  __syncthreads();
  for (int idx = tid; idx < 896; idx += 256){
    int imgl = idx / 112, j = idx - imgl*112;
    if (j >= 100) continue;
    int l = ((imgl >> 2) << 4) | (j & 15);
    int c = (j >> 4)*4 + (imgl & 3);
    float s = red[0][l][c] + red[1][l][c] + red[2][l][c] + red[3][l][c] + fc1b[j];
    x1s[imgl][j] = s > 0.f ? s : 0.f;
  }
  __syncthreads();
  const int g = tid >> 5, l32 = tid & 31;
  const int img = ib + img0 + g;
  for (int j = l32; j < 50; j += 32){
    float s = fb2[j];
    #pragma unroll 4
    for (int k = 0; k < 100; ++k) s = fmaf(x1s[g][k], fW2[k*50+j], s);
    h2s[g][j] = s > 0.f ? s : 0.f;
  }
  __syncthreads();
  if (l32 < 10){
    float s = fb3[l32];
    #pragma unroll
    for (int k = 0; k < 50; ++k) s = fmaf(h2s[g][k], fW3[k*10+l32], s);
    h3s[g][l32] = s > 0.f ? s : 0.f;
  }
  __syncthreads();
  if (l32 == 0){
    float s = fb4[0];
    #pragma unroll
    for (int k = 0; k < 10; ++k) s = fmaf(h3s[g][k], fW4[k], s);
    stg[g] = s;
  }
  __syncthreads();
  if (l32 < 12){
    float s0 = stg[g], dd = dist[img], sp = speed[img];
    float s = ab1[l32] + s0*aW1[l32] + dd*aW1[12+l32] + sp*aW1[24+l32];
    hb1[g][l32] = s > 0.f ? s : 0.f;
  }
  __syncthreads();
  if (l32 < 24){
    float s = ab2[l32];
    #pragma unroll
    for (int k=0;k<12;++k) s = fmaf(hb1[g][k], aW2[k*24+l32], s);
    hb2[g][l32] = s > 0.f ? s : 0.f;
  }
  __syncthreads();
  if (l32 < 4){
    float s = ab3[l32];
    #pragma unroll
    for (int k=0;k<24;++k) s = fmaf(hb2[g][k], aW3[k*4+l32], s);
    out[(size_t)img*4 + l32] = s;
  }
}

// ================================================================ host
extern "C" void kernel_launch(void* const* d_in, const int* in_sizes, int n_in,
                              void* d_out, int out_size, void* d_ws, size_t ws_size,
                              hipStream_t stream){
  const float* rgb   = (const float*)d_in[0];
  const float* dist  = (const float*)d_in[1];
  const float* speed = (const float*)d_in[2];
  const float* cw1 = (const float*)d_in[3];
  const float* cb1 = (const float*)d_in[4];
  const float* cw2 = (const float*)d_in[5];
  const float* cb2 = (const float*)d_in[6];
  const float* cw3 = (const float*)d_in[7];
  const float* cb3 = (const float*)d_in[8];
  const float* cw4 = (const float*)d_in[9];
  const float* cb4 = (const float*)d_in[10];
  const float* fW1 = (const float*)d_in[11];
  const float* fb1 = (const float*)d_in[12];
  const float* fW2 = (const float*)d_in[13];
  const float* fb2 = (const float*)d_in[14];
  const float* fW3 = (const float*)d_in[15];
  const float* fb3 = (const float*)d_in[16];
  const float* fW4 = (const float*)d_in[17];
  const float* fb4 = (const float*)d_in[18];
  const float* aW1 = (const float*)d_in[19];
  const float* ab1 = (const float*)d_in[20];
  const float* aW2 = (const float*)d_in[21];
  const float* ab2 = (const float*)d_in[22];
  const float* aW3 = (const float*)d_in[23];
  const float* ab3 = (const float*)d_in[24];
  float* out = (float*)d_out;
  const int B = in_sizes[0] / 15000;

  auto ALN = [](size_t x){ return (x + 255) & ~(size_t)255; };
  const size_t fixed = ALN(2048) + ALN(58368) + ALN(89088) + ALN(57344) + ALN(1146880);

  int nc = 1;
  while (nc < 32){
    size_t Bc = (size_t)(B / nc);
    size_t need = fixed + ALN(Bc*54144) + ALN(Bc*10240);
    if (need <= ws_size) break;
    nc *= 2;
  }
  const int Bc = B / nc;

  char* ws = (char*)d_ws;
  size_t o = 0;
  auto alloc = [&](size_t bytes)->char*{ char* p = ws + o; o += ALN(bytes); return p; };
  f16* w1c = (f16*)alloc(2048);
  f16* w2c = (f16*)alloc(58368);
  f16* w3m = (f16*)alloc(89088);
  f16* w4m = (f16*)alloc(57344);
  f16* w1m = (f16*)alloc(1146880);
  f16* a2  = (f16*)alloc((size_t)Bc*54144);
  f16* a4  = (f16*)alloc((size_t)Bc*10240);

  repack_all_k<<<dim3(280), dim3(256), 0, stream>>>(w1c, w2c, w3m, w4m, w1m,
                                                    cw1, cw2, cw3, cw4, fW1);

  for (int c = 0; c < nc; ++c){
    const int ib = c*Bc;
    conv12_k<<<dim3(Bc*6),  dim3(256), 0, stream>>>(rgb, w1c, cb1, w2c, cb2, a2, ib);
    conv34_k<<<dim3(Bc*2),  dim3(256), 0, stream>>>(a2, w3m, cb3, w4m, cb4, a4);
    fc1tail_k<<<dim3(Bc/8), dim3(256), 0, stream>>>(a4, w1m, fb1, dist, speed,
        fW2, fb2, fW3, fb3, fW4, fb4, aW1, ab1, aW2, ab2, aW3, ab3, out, ib, Bc);
  }
}

// Round 15
// 165.207 us; speedup vs baseline: 1.2772x; 1.0325x over previous
//
#include <hip/hip_runtime.h>

typedef _Float16 f16;
typedef _Float16 f16x4 __attribute__((ext_vector_type(4)));
typedef _Float16 f16x8 __attribute__((ext_vector_type(8)));
typedef float f32x4 __attribute__((ext_vector_type(4)));

// ---------------------------------------------------------------- merged weight repack (all MFMA fragments)
__global__ __launch_bounds__(256) void repack_all_k(
    f16* __restrict__ w1c, f16* __restrict__ w2c, f16* __restrict__ w3m,
    f16* __restrict__ w4m, f16* __restrict__ wfc,
    const float* __restrict__ s1, const float* __restrict__ s2, const float* __restrict__ s3,
    const float* __restrict__ s4, const float* __restrict__ sf){
  const int tid0 = blockIdx.x*256 + threadIdx.x, stride = gridDim.x*256;
  for (int idx = tid0; idx < 1024; idx += stride){
    int i = idx & 7, l = (idx >> 3) & 63, mt = idx >> 9;
    int co = mt*16 + (l & 15);
    int jg = l >> 4;
    int kw = -1, kh = 0;
    if (jg < 2){ kw = jg*2 + (i >> 2); kh = i & 3; }
    else if (jg == 2){
      if (i < 4){ kw = 4; kh = i; }
      else if (i == 4){ kw = 0; kh = 4; }
      else if (i == 5){ kw = 1; kh = 4; }
    } else {
      if (i == 0){ kw = 4; kh = 4; }
      else if (i == 4){ kw = 2; kh = 4; }
      else if (i == 5){ kw = 3; kh = 4; }
    }
    f16 v = (f16)0.0f;
    if (co < 24 && kw >= 0) v = (f16)s1[co*25 + kh*5 + kw];
    w1c[idx] = v;
  }
  for (int idx = tid0; idx < 29184; idx += stride){
    int i = idx & 7, l = (idx >> 3) & 63, rest = idx >> 9;
    int mt = rest % 3, s = rest / 3;
    int co = mt*16 + (l & 15);
    int k = s*32 + (l >> 4)*8 + i;
    f16 v = (f16)0.0f;
    if (co < 36 && k < 600){
      int tap = k / 24, ci = k - tap*24;
      v = (f16)s2[(co*24 + ci)*25 + tap];
    }
    w2c[idx] = v;
  }
  for (int idx = tid0; idx < 44544; idx += stride){
    int i = idx & 7, l = (idx >> 3) & 63, rest = idx >> 9;
    int mt = rest % 3, s = rest / 3;
    int co = mt*16 + (l & 15);
    f16 v = (f16)0.0f;
    if (s < 25){
      int ci = (l >> 4)*8 + i;
      v = (f16)s3[(co*36 + ci)*25 + s];
    } else {
      int ke = (s - 25)*32 + (l >> 4)*8 + i;
      if (ke < 100){
        int p = ke >> 2, ci = 32 + (ke & 3);
        v = (f16)s3[(co*36 + ci)*25 + p];
      }
    }
    w3m[idx] = v;
  }
  for (int idx = tid0; idx < 28672; idx += stride){
    int i = idx & 7, l = (idx >> 3) & 63, rest = idx >> 9;
    int mt = rest & 3, s = rest >> 2;
    int co = mt*16 + (l & 15);
    int k = s*32 + (l >> 4)*8 + i;
    f16 v = (f16)0.0f;
    if (k < 432){
      int pos = k / 48, ci = k - pos*48;
      v = (f16)s4[(co*48 + ci)*9 + pos];
    }
    w4m[idx] = v;
  }
  for (int t = tid0; t < 71680; t += stride){
    int l = t & 63, rest = t >> 6;
    int nt = rest % 7, s = rest / 7;
    int j = nt*16 + (l & 15);
    int kb = s*32 + (l >> 4)*8;
    union { f16 h[8]; f16x8 v; } pk;
    #pragma unroll
    for (int i=0;i<8;++i){
      int k = kb + i;
      int row = (k & 63)*80 + (k >> 6);
      pk.h[i] = (j < 100) ? (f16)sf[(size_t)row*100 + j] : (f16)0.0f;
    }
    *(f16x8*)(wfc + (size_t)t*8) = pk.v;
  }
}

// ---------------------------------------------------------------- conv1+conv2 fused (both MFMA, pipelined)
__global__ __launch_bounds__(256) void conv12_k(const float* __restrict__ rgb, const f16* __restrict__ w1m,
                                                const float* __restrict__ b1, const f16* __restrict__ w2c,
                                                const float* __restrict__ b2, f16* __restrict__ a2, int ib){
  __shared__ __align__(16) f16 xb[75*46 + 8];      // 6916 B
  __shared__ __align__(16) f16 xt[2*19*18*24];     // 32832 B
  const int tid = threadIdx.x, bx = blockIdx.x;
  const int i = bx / 6, t = bx - i*6;
  const int h0 = t*32, oh0 = t*8;
  const float* img = rgb + (size_t)(ib + i)*15000;
  for (int idx = tid; idx < 825; idx += 256){
    int w = idx / 11, h4 = idx - w*11;
    int hh = h4*4, h = h0 + hh;
    union { f16 hv[4]; uint u[2]; } pk;
    if (h < 200){
      float4 v = *(const float4*)(img + w*200 + h);
      pk.hv[0] = (v.x > 0.f) ? (f16)1.0f : (f16)0.0f;
      pk.hv[1] = (v.y > 0.f) ? (f16)1.0f : (f16)0.0f;
      pk.hv[2] = (v.z > 0.f) ? (f16)1.0f : (f16)0.0f;
      pk.hv[3] = (v.w > 0.f) ? (f16)1.0f : (f16)0.0f;
    } else {
      pk.u[0] = 0u; pk.u[1] = 0u;
    }
    *(uint*)(xb + w*46 + hh)     = pk.u[0];
    *(uint*)(xb + w*46 + hh + 2) = pk.u[1];
  }
  __syncthreads();
  const int wv = tid >> 6, lane = tid & 63;
  const int jgrp = lane >> 4, npx = lane & 15;
  // ---- phase 1: conv1 MFMA into xt (6-read gather, depth-1 prefetch)
  {
    f16x8 a1f0 = *(const f16x8*)(w1m + (size_t)lane*8);
    f16x8 a1f1 = *(const f16x8*)(w1m + (size_t)(64 + lane)*8);
    const int tA = (jgrp < 2) ? jgrp*92 : ((jgrp == 2) ? 184 : 188);
    const int tC = (jgrp == 1) ? 138 : 46;
    const int tE = (jgrp == 2) ? 4  : ((jgrp == 3) ? 96  : 0);
    const int tF = (jgrp == 2) ? 50 : ((jgrp == 3) ? 142 : 0);
    f32x4 bv0, bv1;
    #pragma unroll
    for (int reg=0; reg<4; ++reg){
      int c0 = jgrp*4 + reg;
      int c1 = 16 + jgrp*4 + reg;
      bv0[reg] = b1[c0];
      bv1[reg] = (c1 < 24) ? b1[c1] : 0.f;
    }
    const int qn = (wv == 3) ? 10 : 11;
    union { uint d[4]; f16x8 v; } bqc, bqn;
    int pxt_c, rr_c, ow_c;
    {
      int pxt = wv*16 + npx;
      int px = (pxt > 683) ? 683 : pxt;
      int rr = px/36, ow = px - rr*36;
      const int base = 2*(ow*46 + rr);
      uint ra = *(const uint*)(xb + base + tA);
      uint rb = *(const uint*)(xb + base + tA + 2);
      uint rc = *(const uint*)(xb + base + tC);
      uint rd = *(const uint*)(xb + base + tC + 2);
      uint re = *(const unsigned short*)(xb + base + tE);
      uint rf = *(const unsigned short*)(xb + base + tF);
      bqc.d[0] = ra; bqc.d[1] = rb;
      bqc.d[2] = (jgrp < 2) ? rc : (re | (rf << 16));
      bqc.d[3] = rd;
      pxt_c = pxt; rr_c = rr; ow_c = ow;
    }
    for (int q=0; q<qn; ++q){
      int pxt_n = 0, rr_n = 0, ow_n = 0;
      if (q+1 < qn){
        int nt = wv + 4*(q+1);
        pxt_n = nt*16 + npx;
        int px = (pxt_n > 683) ? 683 : pxt_n;
        rr_n = px/36; ow_n = px - rr_n*36;
        const int base = 2*(ow_n*46 + rr_n);
        uint ra = *(const uint*)(xb + base + tA);
        uint rb = *(const uint*)(xb + base + tA + 2);
        uint rc = *(const uint*)(xb + base + tC);
        uint rd = *(const uint*)(xb + base + tC + 2);
        uint re = *(const unsigned short*)(xb + base + tE);
        uint rf = *(const unsigned short*)(xb + base + tF);
        bqn.d[0] = ra; bqn.d[1] = rb;
        bqn.d[2] = (jgrp < 2) ? rc : (re | (rf << 16));
        bqn.d[3] = rd;
      }
      f32x4 c0 = __builtin_amdgcn_mfma_f32_16x16x32_f16(a1f0, bqc.v, bv0, 0, 0, 0);
      f32x4 c1 = __builtin_amdgcn_mfma_f32_16x16x32_f16(a1f1, bqc.v, bv1, 0, 0, 0);
      if (pxt_c <= 683){
        f16* dst = xt + (((ow_c & 1)*19 + rr_c)*18 + (ow_c >> 1))*24;
        union { f16 h[4]; uint2 q2; } pk;
        #pragma unroll
        for (int reg=0; reg<4; ++reg){ float r = c0[reg]; if (r<0.f) r=0.f; pk.h[reg]=(f16)r; }
        *(uint2*)(dst + jgrp*4) = pk.q2;
        if (jgrp < 2){
          #pragma unroll
          for (int reg=0; reg<4; ++reg){ float r = c1[reg]; if (r<0.f) r=0.f; pk.h[reg]=(f16)r; }
          *(uint2*)(dst + 16 + jgrp*4) = pk.q2;
        }
      }
      if (q+1 < qn){ bqc.v = bqn.v; pxt_c = pxt_n; rr_c = rr_n; ow_c = ow_n; }
    }
  }
  __syncthreads();
  // ---- phase 2: conv2 MFMA, K-packed 19 steps, depth-1 prefetch
  int baddr[19];
  #pragma unroll
  for (int s=0; s<19; ++s){
    int m = s*4 + jgrp;
    int tap = m / 3, r3 = m - tap*3;
    if (m >= 75){ tap = 24; r3 = 0; }
    int kh = tap / 5, kw = tap - kh*5;
    int par = kw & 1, kws = kw >> 1;
    baddr[s] = ((par*19 + kh)*18 + npx + kws)*24 + r3*8;
  }
  f32x4 acc2[3][2];
  #pragma unroll
  for (int mt=0; mt<3; ++mt){
    f32x4 bv;
    #pragma unroll
    for (int reg=0; reg<4; ++reg){
      int co = mt*16 + jgrp*4 + reg;
      bv[reg] = (co < 36) ? b2[co] : 0.0f;
    }
    acc2[mt][0] = bv; acc2[mt][1] = bv;
  }
  const f16* agl = w2c + (size_t)lane*8;
  const int rowo = 4*wv*432;
  f16x8 af0, af1, af2, bf0, bf1;
  {
    af0 = *(const f16x8*)(agl + 0*512);
    af1 = *(const f16x8*)(agl + 1*512);
    af2 = *(const f16x8*)(agl + 2*512);
    const f16* bb0 = xt + baddr[0] + rowo;
    bf0 = *(const f16x8*)(bb0);
    bf1 = *(const f16x8*)(bb0 + 2*432);
  }
  #pragma unroll
  for (int s=0; s<19; ++s){
    f16x8 naf0, naf1, naf2, nbf0, nbf1;
    if (s < 18){
      naf0 = *(const f16x8*)(agl + (size_t)((s+1)*3 + 0)*512);
      naf1 = *(const f16x8*)(agl + (size_t)((s+1)*3 + 1)*512);
      naf2 = *(const f16x8*)(agl + (size_t)((s+1)*3 + 2)*512);
      const f16* bb0 = xt + baddr[s+1] + rowo;
      nbf0 = *(const f16x8*)(bb0);
      nbf1 = *(const f16x8*)(bb0 + 2*432);
    }
    acc2[0][0] = __builtin_amdgcn_mfma_f32_16x16x32_f16(af0, bf0, acc2[0][0], 0, 0, 0);
    acc2[0][1] = __builtin_amdgcn_mfma_f32_16x16x32_f16(af0, bf1, acc2[0][1], 0, 0, 0);
    acc2[1][0] = __builtin_amdgcn_mfma_f32_16x16x32_f16(af1, bf0, acc2[1][0], 0, 0, 0);
    acc2[1][1] = __builtin_amdgcn_mfma_f32_16x16x32_f16(af1, bf1, acc2[1][1], 0, 0, 0);
    acc2[2][0] = __builtin_amdgcn_mfma_f32_16x16x32_f16(af2, bf0, acc2[2][0], 0, 0, 0);
    acc2[2][1] = __builtin_amdgcn_mfma_f32_16x16x32_f16(af2, bf1, acc2[2][1], 0, 0, 0);
    if (s < 18){
      af0 = naf0; af1 = naf1; af2 = naf2; bf0 = nbf0; bf1 = nbf1;
    }
  }
  #pragma unroll
  for (int u=0; u<2; ++u){
    const int oh = oh0 + 2*wv + u;
    if (oh >= 47) continue;
    #pragma unroll
    for (int mt=0; mt<3; ++mt){
      const int co0s = mt*16 + jgrp*4;
      if (co0s >= 36) continue;
      union { f16 h[4]; uint2 q; } pk;
      #pragma unroll
      for (int reg=0; reg<4; ++reg){
        float r = acc2[mt][u][reg]; if (r < 0.f) r = 0.f;
        pk.h[reg] = (f16)r;
      }
      *(uint2*)(a2 + (((size_t)i*47 + oh)*16 + npx)*36 + co0s) = pk.q;
    }
  }
}

// ---------------------------------------------------------------- conv3+conv4 fused (per half-image, pipelined)
__global__ __launch_bounds__(256) void conv34_k(const f16* __restrict__ a2, const f16* __restrict__ w3m,
                                                const float* __restrict__ b3, const f16* __restrict__ w4m,
                                                const float* __restrict__ b4, f16* __restrict__ a4){
  __shared__ __align__(16) f16 xt[27*680];     // 36720 B
  __shared__ __align__(16) f16 a3t[12*6*56];   // 8064 B
  const int tid = threadIdx.x, bx = blockIdx.x;
  const int i = bx >> 1, t = bx & 1;
  const int r0 = t*20, obase = t*10;
  {
    const uint2* s2 = (const uint2*)((const uint*)a2 + (size_t)i*13536);
    uint2* d = (uint2*)xt;
    for (int idx = tid; idx < 3888; idx += 256){
      int d2 = idx % 9, rc = idx / 9;
      int c = rc & 15, r = rc >> 4;
      int dwi = d2*2, jg = dwi >> 2, part = dwi & 3;
      d[(r*340 + jg*68 + c*4 + part) >> 1] = s2[((size_t)(r0 + r)*16 + c)*9 + d2];
    }
  }
  __syncthreads();
  const int wv = tid >> 6, lane = tid & 63;
  const int npx = lane & 15, jg = lane >> 4;
  // ---- conv3 stage (depth-1 prefetch over 25 main taps)
  {
    int baseq[2], ohl[2], owl[2];
    #pragma unroll
    for (int q=0;q<2;++q){
      int px = (wv*2+q)*16 + npx; if (px > 71) px = 71;
      ohl[q] = px/6; owl[q] = px - ohl[q]*6;
      baseq[q] = 2*ohl[q]*680 + jg*136 + 2*owl[q]*8;
    }
    f32x4 acc[3][2];
    #pragma unroll
    for (int mt=0;mt<3;++mt){
      f32x4 bv;
      #pragma unroll
      for (int reg=0;reg<4;++reg) bv[reg] = b3[mt*16 + jg*4 + reg];
      acc[mt][0]=bv; acc[mt][1]=bv;
    }
    const f16* agl = w3m + (size_t)lane*8;
    f16x8 caf0 = *(const f16x8*)(agl);
    f16x8 caf1 = *(const f16x8*)(agl + 512);
    f16x8 caf2 = *(const f16x8*)(agl + 1024);
    f16x8 cbf0 = *(const f16x8*)(xt + baseq[0]);
    f16x8 cbf1 = *(const f16x8*)(xt + baseq[1]);
    #pragma unroll
    for (int s=0; s<25; ++s){
      f16x8 naf0, naf1, naf2, nbf0, nbf1;
      if (s < 24){
        const int sn = s + 1;
        naf0 = *(const f16x8*)(agl + (size_t)(sn*3 + 0)*512);
        naf1 = *(const f16x8*)(agl + (size_t)(sn*3 + 1)*512);
        naf2 = *(const f16x8*)(agl + (size_t)(sn*3 + 2)*512);
        const int off = (sn/5)*680 + (sn%5)*8;
        nbf0 = *(const f16x8*)(xt + baseq[0] + off);
        nbf1 = *(const f16x8*)(xt + baseq[1] + off);
      }
      acc[0][0] = __builtin_amdgcn_mfma_f32_16x16x32_f16(caf0, cbf0, acc[0][0], 0, 0, 0);
      acc[0][1] = __builtin_amdgcn_mfma_f32_16x16x32_f16(caf0, cbf1, acc[0][1], 0, 0, 0);
      acc[1][0] = __builtin_amdgcn_mfma_f32_16x16x32_f16(caf1, cbf0, acc[1][0], 0, 0, 0);
      acc[1][1] = __builtin_amdgcn_mfma_f32_16x16x32_f16(caf1, cbf1, acc[1][1], 0, 0, 0);
      acc[2][0] = __builtin_amdgcn_mfma_f32_16x16x32_f16(caf2, cbf0, acc[2][0], 0, 0, 0);
      acc[2][1] = __builtin_amdgcn_mfma_f32_16x16x32_f16(caf2, cbf1, acc[2][1], 0, 0, 0);
      if (s < 24){ caf0=naf0; caf1=naf1; caf2=naf2; cbf0=nbf0; cbf1=nbf1; }
    }
    // extra 4 K-steps: leftovers ci32..35
    #pragma unroll
    for (int e=0;e<4;++e){
      const int s = 25 + e;
      f16x8 af[3];
      #pragma unroll
      for (int mt=0;mt<3;++mt)
        af[mt] = *(const f16x8*)(agl + (size_t)(s*3 + mt)*512);
      int p1 = e*8 + jg*2; int p2 = p1 + 1;
      if (p1 > 24) p1 = 24;
      if (p2 > 24) p2 = 24;
      const int kh1 = p1/5, kw1 = p1 - kh1*5;
      const int kh2 = p2/5, kw2 = p2 - kh2*5;
      #pragma unroll
      for (int q=0;q<2;++q){
        f16x4 lo = *(const f16x4*)(xt + (2*ohl[q]+kh1)*680 + 544 + (2*owl[q]+kw1)*8);
        f16x4 hi = *(const f16x4*)(xt + (2*ohl[q]+kh2)*680 + 544 + (2*owl[q]+kw2)*8);
        f16x8 bq = __builtin_shufflevector(lo, hi, 0,1,2,3,4,5,6,7);
        #pragma unroll
        for (int mt=0;mt<3;++mt)
          acc[mt][q] = __builtin_amdgcn_mfma_f32_16x16x32_f16(af[mt], bq, acc[mt][q], 0, 0, 0);
      }
    }
    #pragma unroll
    for (int q=0;q<2;++q){
      int px = (wv*2+q)*16 + npx;
      if (px >= 72) continue;
      #pragma unroll
      for (int mt=0;mt<3;++mt){
        union { f16 h[4]; uint2 q2; } pk;
        #pragma unroll
        for (int reg=0;reg<4;++reg){
          float r = acc[mt][q][reg]; if (r < 0.f) r = 0.f;
          pk.h[reg] = (f16)r;
        }
        *(uint2*)(a3t + px*56 + mt*16 + jg*4) = pk.q2;
      }
    }
  }
  __syncthreads();
  // ---- conv4 stage (depth-1 prefetch over 14 K-steps)
  {
    f32x4 acc4[3];
    {
      f32x4 bv;
      #pragma unroll
      for (int reg=0;reg<4;++reg) bv[reg] = b4[wv*16 + jg*4 + reg];
      acc4[0]=bv; acc4[1]=bv; acc4[2]=bv;
    }
    int ohn[3], own[3];
    #pragma unroll
    for (int nt=0;nt<3;++nt){
      int px = nt*16 + npx; if (px > 39) px = 39;
      ohn[nt] = px >> 2; own[nt] = px & 3;
    }
    const f16* agl = w4m + (size_t)lane*8;
    f16x8 caf, cb0, cb1, cb2;
    {
      caf = *(const f16x8*)(agl + (size_t)wv*512);
      const int ci0 = jg*8;     // s=0: k8 = jg*8 < 48 -> pos 0, kh=kw=0
      cb0 = *(const f16x8*)(a3t + (ohn[0]*6 + own[0])*56 + ci0);
      cb1 = *(const f16x8*)(a3t + (ohn[1]*6 + own[1])*56 + ci0);
      cb2 = *(const f16x8*)(a3t + (ohn[2]*6 + own[2])*56 + ci0);
    }
    #pragma unroll
    for (int s=0; s<14; ++s){
      f16x8 naf, nb0, nb1, nb2;
      if (s < 13){
        const int sn = s + 1;
        naf = *(const f16x8*)(agl + (size_t)(sn*4 + wv)*512);
        int k8 = sn*32 + jg*8;
        int pos, ci0;
        if (k8 >= 432){ pos = 8; ci0 = 40; }
        else { pos = k8 / 48; ci0 = k8 - pos*48; }
        const int kh = pos/3, kw = pos - kh*3;
        nb0 = *(const f16x8*)(a3t + ((ohn[0]+kh)*6 + own[0]+kw)*56 + ci0);
        nb1 = *(const f16x8*)(a3t + ((ohn[1]+kh)*6 + own[1]+kw)*56 + ci0);
        nb2 = *(const f16x8*)(a3t + ((ohn[2]+kh)*6 + own[2]+kw)*56 + ci0);
      }
      acc4[0] = __builtin_amdgcn_mfma_f32_16x16x32_f16(caf, cb0, acc4[0], 0, 0, 0);
      acc4[1] = __builtin_amdgcn_mfma_f32_16x16x32_f16(caf, cb1, acc4[1], 0, 0, 0);
      acc4[2] = __builtin_amdgcn_mfma_f32_16x16x32_f16(caf, cb2, acc4[2], 0, 0, 0);
      if (s < 13){ caf = naf; cb0 = nb0; cb1 = nb1; cb2 = nb2; }
    }
    #pragma unroll
    for (int nt=0;nt<3;++nt){
      int px = nt*16 + npx;
      if (px >= 40) continue;
      union { f16 h[4]; uint2 q2; } pk;
      #pragma unroll
      for (int reg=0;reg<4;++reg){
        float r = acc4[nt][reg]; if (r < 0.f) r = 0.f;
        pk.h[reg] = (f16)r;
      }
      *(uint2*)(a4 + ((size_t)i*80 + obase*4 + px)*64 + wv*16 + jg*4) = pk.q2;
    }
  }
}

// ---------------------------------------------------------------- fc1 (MFMA, pipelined) + fc2..fc4 + AEBS fused
__global__ __launch_bounds__(256) void fc1tail_k(const f16* __restrict__ a4, const f16* __restrict__ w1m,
    const float* __restrict__ fc1b, const float* __restrict__ dist, const float* __restrict__ speed,
    const float* __restrict__ fW2, const float* __restrict__ fb2,
    const float* __restrict__ fW3, const float* __restrict__ fb3,
    const float* __restrict__ fW4, const float* __restrict__ fb4,
    const float* __restrict__ aW1, const float* __restrict__ ab1,
    const float* __restrict__ aW2, const float* __restrict__ ab2,
    const float* __restrict__ aW3, const float* __restrict__ ab3,
    float* __restrict__ out, int ib, int n){
  __shared__ float red[4][64][28];
  __shared__ float x1s[8][100];
  __shared__ float h2s[8][50];
  __shared__ float h3s[8][10];
  __shared__ float stg[8];
  __shared__ float hb1[8][12];
  __shared__ float hb2[8][24];
  const int tid = threadIdx.x;
  const int wv = tid >> 6, lane = tid & 63;
  const int img0 = blockIdx.x*8;
  f32x4 acc[7];
  #pragma unroll
  for (int nt=0;nt<7;++nt) acc[nt] = (f32x4){0.f,0.f,0.f,0.f};
  int ia = img0 + (lane & 15);
  if (ia > n-1) ia = n-1;
  const f16* ap = a4 + (size_t)ia*5120 + (lane >> 4)*8;
  const f16* bp = w1m + (size_t)lane*8;
  const int s0 = wv*40;
  f16x8 cav = *(const f16x8*)(ap + s0*32);
  f16x8 cbv0 = *(const f16x8*)(bp + (size_t)(s0*7 + 0)*512);
  f16x8 cbv1 = *(const f16x8*)(bp + (size_t)(s0*7 + 1)*512);
  f16x8 cbv2 = *(const f16x8*)(bp + (size_t)(s0*7 + 2)*512);
  f16x8 cbv3 = *(const f16x8*)(bp + (size_t)(s0*7 + 3)*512);
  f16x8 cbv4 = *(const f16x8*)(bp + (size_t)(s0*7 + 4)*512);
  f16x8 cbv5 = *(const f16x8*)(bp + (size_t)(s0*7 + 5)*512);
  f16x8 cbv6 = *(const f16x8*)(bp + (size_t)(s0*7 + 6)*512);
  #pragma unroll 1
  for (int s = s0; s < s0 + 40; ++s){
    f16x8 nav, nbv0, nbv1, nbv2, nbv3, nbv4, nbv5, nbv6;
    const bool more = (s + 1 < s0 + 40);
    if (more){
      nav  = *(const f16x8*)(ap + (s+1)*32);
      nbv0 = *(const f16x8*)(bp + (size_t)((s+1)*7 + 0)*512);
      nbv1 = *(const f16x8*)(bp + (size_t)((s+1)*7 + 1)*512);
      nbv2 = *(const f16x8*)(bp + (size_t)((s+1)*7 + 2)*512);
      nbv3 = *(const f16x8*)(bp + (size_t)((s+1)*7 + 3)*512);
      nbv4 = *(const f16x8*)(bp + (size_t)((s+1)*7 + 4)*512);
      nbv5 = *(const f16x8*)(bp + (size_t)((s+1)*7 + 5)*512);
      nbv6 = *(const f16x8*)(bp + (size_t)((s+1)*7 + 6)*512);
    }
    acc[0] = __builtin_amdgcn_mfma_f32_16x16x32_f16(cav, cbv0, acc[0], 0, 0, 0);
    acc[1] = __builtin_amdgcn_mfma_f32_16x16x32_f16(cav, cbv1, acc[1], 0, 0, 0);
    acc[2] = __builtin_amdgcn_mfma_f32_16x16x32_f16(cav, cbv2, acc[2], 0, 0, 0);
    acc[3] = __builtin_amdgcn_mfma_f32_16x16x32_f16(cav, cbv3, acc[3], 0, 0, 0);
    acc[4] = __builtin_amdgcn_mfma_f32_16x16x32_f16(cav, cbv4, acc[4], 0, 0, 0);
    acc[5] = __builtin_amdgcn_mfma_f32_16x16x32_f16(cav, cbv5, acc[5], 0, 0, 0);
    acc[6] = __builtin_amdgcn_mfma_f32_16x16x32_f16(cav, cbv6, acc[6], 0, 0, 0);
    if (more){
      cav = nav;
      cbv0 = nbv0; cbv1 = nbv1; cbv2 = nbv2; cbv3 = nbv3;
      cbv4 = nbv4; cbv5 = nbv5; cbv6 = nbv6;
    }
  }
  {
    f32x4* accp = acc;
    #pragma unroll
    for (int nt=0;nt<7;++nt)
      #pragma unroll
      for (int reg=0;reg<4;++reg)
        red[wv][lane][nt*4+reg] = accp[nt][reg];
  }
  __syncthreads();
  for (int idx = tid; idx < 896; idx += 256){
    int imgl = idx / 112, j = idx - imgl*112;
    if (j >= 100) continue;
    int l = ((imgl >> 2) << 4) | (j & 15);
    int c = (j >> 4)*4 + (imgl & 3);
    float s = red[0][l][c] + red[1][l][c] + red[2][l][c] + red[3][l][c] + fc1b[j];
    x1s[imgl][j] = s > 0.f ? s : 0.f;
  }
  __syncthreads();
  const int g = tid >> 5, l32 = tid & 31;
  const int img = ib + img0 + g;
  for (int j = l32; j < 50; j += 32){
    float s = fb2[j];
    #pragma unroll 4
    for (int k = 0; k < 100; ++k) s = fmaf(x1s[g][k], fW2[k*50+j], s);
    h2s[g][j] = s > 0.f ? s : 0.f;
  }
  __syncthreads();
  if (l32 < 10){
    float s = fb3[l32];
    #pragma unroll
    for (int k = 0; k < 50; ++k) s = fmaf(h2s[g][k], fW3[k*10+l32], s);
    h3s[g][l32] = s > 0.f ? s : 0.f;
  }
  __syncthreads();
  if (l32 == 0){
    float s = fb4[0];
    #pragma unroll
    for (int k = 0; k < 10; ++k) s = fmaf(h3s[g][k], fW4[k], s);
    stg[g] = s;
  }
  __syncthreads();
  if (l32 < 12){
    float s0v = stg[g], dd = dist[img], sp = speed[img];
    float s = ab1[l32] + s0v*aW1[l32] + dd*aW1[12+l32] + sp*aW1[24+l32];
    hb1[g][l32] = s > 0.f ? s : 0.f;
  }
  __syncthreads();
  if (l32 < 24){
    float s = ab2[l32];
    #pragma unroll
    for (int k=0;k<12;++k) s = fmaf(hb1[g][k], aW2[k*24+l32], s);
    hb2[g][l32] = s > 0.f ? s : 0.f;
  }
  __syncthreads();
  if (l32 < 4){
    float s = ab3[l32];
    #pragma unroll
    for (int k=0;k<24;++k) s = fmaf(hb2[g][k], aW3[k*4+l32], s);
    out[(size_t)img*4 + l32] = s;
  }
}

// ================================================================ host
extern "C" void kernel_launch(void* const* d_in, const int* in_sizes, int n_in,
                              void* d_out, int out_size, void* d_ws, size_t ws_size,
                              hipStream_t stream){
  const float* rgb   = (const float*)d_in[0];
  const float* dist  = (const float*)d_in[1];
  const float* speed = (const float*)d_in[2];
  const float* cw1 = (const float*)d_in[3];
  const float* cb1 = (const float*)d_in[4];
  const float* cw2 = (const float*)d_in[5];
  const float* cb2 = (const float*)d_in[6];
  const float* cw3 = (const float*)d_in[7];
  const float* cb3 = (const float*)d_in[8];
  const float* cw4 = (const float*)d_in[9];
  const float* cb4 = (const float*)d_in[10];
  const float* fW1 = (const float*)d_in[11];
  const float* fb1 = (const float*)d_in[12];
  const float* fW2 = (const float*)d_in[13];
  const float* fb2 = (const float*)d_in[14];
  const float* fW3 = (const float*)d_in[15];
  const float* fb3 = (const float*)d_in[16];
  const float* fW4 = (const float*)d_in[17];
  const float* fb4 = (const float*)d_in[18];
  const float* aW1 = (const float*)d_in[19];
  const float* ab1 = (const float*)d_in[20];
  const float* aW2 = (const float*)d_in[21];
  const float* ab2 = (const float*)d_in[22];
  const float* aW3 = (const float*)d_in[23];
  const float* ab3 = (const float*)d_in[24];
  float* out = (float*)d_out;
  const int B = in_sizes[0] / 15000;

  auto ALN = [](size_t x){ return (x + 255) & ~(size_t)255; };
  const size_t fixed = ALN(2048) + ALN(58368) + ALN(89088) + ALN(57344) + ALN(1146880);

  int nc = 1;
  while (nc < 32){
    size_t Bc = (size_t)(B / nc);
    size_t need = fixed + ALN(Bc*54144) + ALN(Bc*10240);
    if (need <= ws_size) break;
    nc *= 2;
  }
  const int Bc = B / nc;

  char* ws = (char*)d_ws;
  size_t o = 0;
  auto alloc = [&](size_t bytes)->char*{ char* p = ws + o; o += ALN(bytes); return p; };
  f16* w1c = (f16*)alloc(2048);
  f16* w2c = (f16*)alloc(58368);
  f16* w3m = (f16*)alloc(89088);
  f16* w4m = (f16*)alloc(57344);
  f16* w1m = (f16*)alloc(1146880);
  f16* a2  = (f16*)alloc((size_t)Bc*54144);
  f16* a4  = (f16*)alloc((size_t)Bc*10240);

  repack_all_k<<<dim3(280), dim3(256), 0, stream>>>(w1c, w2c, w3m, w4m, w1m,
                                                    cw1, cw2, cw3, cw4, fW1);

  for (int c = 0; c < nc; ++c){
    const int ib = c*Bc;
    conv12_k<<<dim3(Bc*6),  dim3(256), 0, stream>>>(rgb, w1c, cb1, w2c, cb2, a2, ib);
    conv34_k<<<dim3(Bc*2),  dim3(256), 0, stream>>>(a2, w3m, cb3, w4m, cb4, a4);
    fc1tail_k<<<dim3(Bc/8), dim3(256), 0, stream>>>(a4, w1m, fb1, dist, speed,
        fW2, fb2, fW3, fb3, fW4, fb4, aW1, ab1, aW2, ab2, aW3, ab3, out, ib, Bc);
  }
}

// Round 16
// 159.354 us; speedup vs baseline: 1.3241x; 1.0367x over previous
//
#include <hip/hip_runtime.h>

typedef _Float16 f16;
typedef _Float16 f16x4 __attribute__((ext_vector_type(4)));
typedef _Float16 f16x8 __attribute__((ext_vector_type(8)));
typedef float f32x4 __attribute__((ext_vector_type(4)));

// ---------------------------------------------------------------- merged weight repack (all MFMA fragments)
__global__ __launch_bounds__(256) void repack_all_k(
    f16* __restrict__ w1c, f16* __restrict__ w2c, f16* __restrict__ w3m,
    f16* __restrict__ w4m, f16* __restrict__ wfc,
    const float* __restrict__ s1, const float* __restrict__ s2, const float* __restrict__ s3,
    const float* __restrict__ s4, const float* __restrict__ sf){
  const int tid0 = blockIdx.x*256 + threadIdx.x, stride = gridDim.x*256;
  for (int idx = tid0; idx < 1024; idx += stride){
    int i = idx & 7, l = (idx >> 3) & 63, mt = idx >> 9;
    int co = mt*16 + (l & 15);
    int jg = l >> 4;
    int kw = -1, kh = 0;
    if (jg < 2){ kw = jg*2 + (i >> 2); kh = i & 3; }
    else if (jg == 2){
      if (i < 4){ kw = 4; kh = i; }
      else if (i == 4){ kw = 0; kh = 4; }
      else if (i == 5){ kw = 1; kh = 4; }
    } else {
      if (i == 0){ kw = 4; kh = 4; }
      else if (i == 4){ kw = 2; kh = 4; }
      else if (i == 5){ kw = 3; kh = 4; }
    }
    f16 v = (f16)0.0f;
    if (co < 24 && kw >= 0) v = (f16)s1[co*25 + kh*5 + kw];
    w1c[idx] = v;
  }
  for (int idx = tid0; idx < 29184; idx += stride){
    int i = idx & 7, l = (idx >> 3) & 63, rest = idx >> 9;
    int mt = rest % 3, s = rest / 3;
    int co = mt*16 + (l & 15);
    int k = s*32 + (l >> 4)*8 + i;
    f16 v = (f16)0.0f;
    if (co < 36 && k < 600){
      int tap = k / 24, ci = k - tap*24;
      v = (f16)s2[(co*24 + ci)*25 + tap];
    }
    w2c[idx] = v;
  }
  for (int idx = tid0; idx < 44544; idx += stride){
    int i = idx & 7, l = (idx >> 3) & 63, rest = idx >> 9;
    int mt = rest % 3, s = rest / 3;
    int co = mt*16 + (l & 15);
    f16 v = (f16)0.0f;
    if (s < 25){
      int ci = (l >> 4)*8 + i;
      v = (f16)s3[(co*36 + ci)*25 + s];
    } else {
      int ke = (s - 25)*32 + (l >> 4)*8 + i;
      if (ke < 100){
        int p = ke >> 2, ci = 32 + (ke & 3);
        v = (f16)s3[(co*36 + ci)*25 + p];
      }
    }
    w3m[idx] = v;
  }
  for (int idx = tid0; idx < 28672; idx += stride){
    int i = idx & 7, l = (idx >> 3) & 63, rest = idx >> 9;
    int mt = rest & 3, s = rest >> 2;
    int co = mt*16 + (l & 15);
    int k = s*32 + (l >> 4)*8 + i;
    f16 v = (f16)0.0f;
    if (k < 432){
      int pos = k / 48, ci = k - pos*48;
      v = (f16)s4[(co*48 + ci)*9 + pos];
    }
    w4m[idx] = v;
  }
  for (int t = tid0; t < 71680; t += stride){
    int l = t & 63, rest = t >> 6;
    int nt = rest % 7, s = rest / 7;
    int j = nt*16 + (l & 15);
    int kb = s*32 + (l >> 4)*8;
    union { f16 h[8]; f16x8 v; } pk;
    #pragma unroll
    for (int i=0;i<8;++i){
      int k = kb + i;
      int row = (k & 63)*80 + (k >> 6);
      pk.h[i] = (j < 100) ? (f16)sf[(size_t)row*100 + j] : (f16)0.0f;
    }
    *(f16x8*)(wfc + (size_t)t*8) = pk.v;
  }
}

// ---------------------------------------------------------------- conv1+conv2 fused (both MFMA, pipelined, XCD-swizzled)
__global__ __launch_bounds__(256) void conv12_k(const float* __restrict__ rgb, const f16* __restrict__ w1m,
                                                const float* __restrict__ b1, const f16* __restrict__ w2c,
                                                const float* __restrict__ b2, f16* __restrict__ a2, int ib){
  __shared__ __align__(16) f16 xb[75*46 + 8];      // 6916 B
  __shared__ __align__(16) f16 xt[2*19*18*24];     // 32832 B
  const int tid = threadIdx.x;
  const int bxr = blockIdx.x;
  const int bx = ((gridDim.x & 7) == 0) ? ((bxr & 7)*(gridDim.x >> 3) + (bxr >> 3)) : bxr;
  const int i = bx / 6, t = bx - i*6;
  const int h0 = t*32, oh0 = t*8;
  const float* img = rgb + (size_t)(ib + i)*15000;
  for (int idx = tid; idx < 825; idx += 256){
    int w = idx / 11, h4 = idx - w*11;
    int hh = h4*4, h = h0 + hh;
    union { f16 hv[4]; uint u[2]; } pk;
    if (h < 200){
      float4 v = *(const float4*)(img + w*200 + h);
      pk.hv[0] = (v.x > 0.f) ? (f16)1.0f : (f16)0.0f;
      pk.hv[1] = (v.y > 0.f) ? (f16)1.0f : (f16)0.0f;
      pk.hv[2] = (v.z > 0.f) ? (f16)1.0f : (f16)0.0f;
      pk.hv[3] = (v.w > 0.f) ? (f16)1.0f : (f16)0.0f;
    } else {
      pk.u[0] = 0u; pk.u[1] = 0u;
    }
    *(uint*)(xb + w*46 + hh)     = pk.u[0];
    *(uint*)(xb + w*46 + hh + 2) = pk.u[1];
  }
  __syncthreads();
  const int wv = tid >> 6, lane = tid & 63;
  const int jgrp = lane >> 4, npx = lane & 15;
  // ---- phase 1: conv1 MFMA into xt (6-read gather, depth-1 prefetch)
  {
    f16x8 a1f0 = *(const f16x8*)(w1m + (size_t)lane*8);
    f16x8 a1f1 = *(const f16x8*)(w1m + (size_t)(64 + lane)*8);
    const int tA = (jgrp < 2) ? jgrp*92 : ((jgrp == 2) ? 184 : 188);
    const int tC = (jgrp == 1) ? 138 : 46;
    const int tE = (jgrp == 2) ? 4  : ((jgrp == 3) ? 96  : 0);
    const int tF = (jgrp == 2) ? 50 : ((jgrp == 3) ? 142 : 0);
    f32x4 bv0, bv1;
    #pragma unroll
    for (int reg=0; reg<4; ++reg){
      int c0 = jgrp*4 + reg;
      int c1 = 16 + jgrp*4 + reg;
      bv0[reg] = b1[c0];
      bv1[reg] = (c1 < 24) ? b1[c1] : 0.f;
    }
    const int qn = (wv == 3) ? 10 : 11;
    union { uint d[4]; f16x8 v; } bqc, bqn;
    int pxt_c, rr_c, ow_c;
    {
      int pxt = wv*16 + npx;
      int px = (pxt > 683) ? 683 : pxt;
      int rr = px/36, ow = px - rr*36;
      const int base = 2*(ow*46 + rr);
      uint ra = *(const uint*)(xb + base + tA);
      uint rb = *(const uint*)(xb + base + tA + 2);
      uint rc = *(const uint*)(xb + base + tC);
      uint rd = *(const uint*)(xb + base + tC + 2);
      uint re = *(const unsigned short*)(xb + base + tE);
      uint rf = *(const unsigned short*)(xb + base + tF);
      bqc.d[0] = ra; bqc.d[1] = rb;
      bqc.d[2] = (jgrp < 2) ? rc : (re | (rf << 16));
      bqc.d[3] = rd;
      pxt_c = pxt; rr_c = rr; ow_c = ow;
    }
    for (int q=0; q<qn; ++q){
      int pxt_n = 0, rr_n = 0, ow_n = 0;
      if (q+1 < qn){
        int nt = wv + 4*(q+1);
        pxt_n = nt*16 + npx;
        int px = (pxt_n > 683) ? 683 : pxt_n;
        rr_n = px/36; ow_n = px - rr_n*36;
        const int base = 2*(ow_n*46 + rr_n);
        uint ra = *(const uint*)(xb + base + tA);
        uint rb = *(const uint*)(xb + base + tA + 2);
        uint rc = *(const uint*)(xb + base + tC);
        uint rd = *(const uint*)(xb + base + tC + 2);
        uint re = *(const unsigned short*)(xb + base + tE);
        uint rf = *(const unsigned short*)(xb + base + tF);
        bqn.d[0] = ra; bqn.d[1] = rb;
        bqn.d[2] = (jgrp < 2) ? rc : (re | (rf << 16));
        bqn.d[3] = rd;
      }
      f32x4 c0 = __builtin_amdgcn_mfma_f32_16x16x32_f16(a1f0, bqc.v, bv0, 0, 0, 0);
      f32x4 c1 = __builtin_amdgcn_mfma_f32_16x16x32_f16(a1f1, bqc.v, bv1, 0, 0, 0);
      if (pxt_c <= 683){
        f16* dst = xt + (((ow_c & 1)*19 + rr_c)*18 + (ow_c >> 1))*24;
        union { f16 h[4]; uint2 q2; } pk;
        #pragma unroll
        for (int reg=0; reg<4; ++reg){ float r = c0[reg]; if (r<0.f) r=0.f; pk.h[reg]=(f16)r; }
        *(uint2*)(dst + jgrp*4) = pk.q2;
        if (jgrp < 2){
          #pragma unroll
          for (int reg=0; reg<4; ++reg){ float r = c1[reg]; if (r<0.f) r=0.f; pk.h[reg]=(f16)r; }
          *(uint2*)(dst + 16 + jgrp*4) = pk.q2;
        }
      }
      if (q+1 < qn){ bqc.v = bqn.v; pxt_c = pxt_n; rr_c = rr_n; ow_c = ow_n; }
    }
  }
  __syncthreads();
  // ---- phase 2: conv2 MFMA, K-packed 19 steps, depth-1 prefetch
  int baddr[19];
  #pragma unroll
  for (int s=0; s<19; ++s){
    int m = s*4 + jgrp;
    int tap = m / 3, r3 = m - tap*3;
    if (m >= 75){ tap = 24; r3 = 0; }
    int kh = tap / 5, kw = tap - kh*5;
    int par = kw & 1, kws = kw >> 1;
    baddr[s] = ((par*19 + kh)*18 + npx + kws)*24 + r3*8;
  }
  f32x4 acc2[3][2];
  #pragma unroll
  for (int mt=0; mt<3; ++mt){
    f32x4 bv;
    #pragma unroll
    for (int reg=0; reg<4; ++reg){
      int co = mt*16 + jgrp*4 + reg;
      bv[reg] = (co < 36) ? b2[co] : 0.0f;
    }
    acc2[mt][0] = bv; acc2[mt][1] = bv;
  }
  const f16* agl = w2c + (size_t)lane*8;
  const int rowo = 4*wv*432;
  f16x8 af0, af1, af2, bf0, bf1;
  {
    af0 = *(const f16x8*)(agl + 0*512);
    af1 = *(const f16x8*)(agl + 1*512);
    af2 = *(const f16x8*)(agl + 2*512);
    const f16* bb0 = xt + baddr[0] + rowo;
    bf0 = *(const f16x8*)(bb0);
    bf1 = *(const f16x8*)(bb0 + 2*432);
  }
  #pragma unroll
  for (int s=0; s<19; ++s){
    f16x8 naf0, naf1, naf2, nbf0, nbf1;
    if (s < 18){
      naf0 = *(const f16x8*)(agl + (size_t)((s+1)*3 + 0)*512);
      naf1 = *(const f16x8*)(agl + (size_t)((s+1)*3 + 1)*512);
      naf2 = *(const f16x8*)(agl + (size_t)((s+1)*3 + 2)*512);
      const f16* bb0 = xt + baddr[s+1] + rowo;
      nbf0 = *(const f16x8*)(bb0);
      nbf1 = *(const f16x8*)(bb0 + 2*432);
    }
    acc2[0][0] = __builtin_amdgcn_mfma_f32_16x16x32_f16(af0, bf0, acc2[0][0], 0, 0, 0);
    acc2[0][1] = __builtin_amdgcn_mfma_f32_16x16x32_f16(af0, bf1, acc2[0][1], 0, 0, 0);
    acc2[1][0] = __builtin_amdgcn_mfma_f32_16x16x32_f16(af1, bf0, acc2[1][0], 0, 0, 0);
    acc2[1][1] = __builtin_amdgcn_mfma_f32_16x16x32_f16(af1, bf1, acc2[1][1], 0, 0, 0);
    acc2[2][0] = __builtin_amdgcn_mfma_f32_16x16x32_f16(af2, bf0, acc2[2][0], 0, 0, 0);
    acc2[2][1] = __builtin_amdgcn_mfma_f32_16x16x32_f16(af2, bf1, acc2[2][1], 0, 0, 0);
    if (s < 18){
      af0 = naf0; af1 = naf1; af2 = naf2; bf0 = nbf0; bf1 = nbf1;
    }
  }
  #pragma unroll
  for (int u=0; u<2; ++u){
    const int oh = oh0 + 2*wv + u;
    if (oh >= 47) continue;
    #pragma unroll
    for (int mt=0; mt<3; ++mt){
      const int co0s = mt*16 + jgrp*4;
      if (co0s >= 36) continue;
      union { f16 h[4]; uint2 q; } pk;
      #pragma unroll
      for (int reg=0; reg<4; ++reg){
        float r = acc2[mt][u][reg]; if (r < 0.f) r = 0.f;
        pk.h[reg] = (f16)r;
      }
      *(uint2*)(a2 + (((size_t)i*47 + oh)*16 + npx)*36 + co0s) = pk.q;
    }
  }
}

// ---------------------------------------------------------------- conv3+conv4 fused (per half-image, pipelined, XCD-swizzled)
__global__ __launch_bounds__(256) void conv34_k(const f16* __restrict__ a2, const f16* __restrict__ w3m,
                                                const float* __restrict__ b3, const f16* __restrict__ w4m,
                                                const float* __restrict__ b4, f16* __restrict__ a4){
  __shared__ __align__(16) f16 xt[27*680];     // 36720 B
  __shared__ __align__(16) f16 a3t[12*6*56];   // 8064 B
  const int tid = threadIdx.x;
  const int bxr = blockIdx.x;
  const int bx = ((gridDim.x & 7) == 0) ? ((bxr & 7)*(gridDim.x >> 3) + (bxr >> 3)) : bxr;
  const int i = bx >> 1, t = bx & 1;
  const int r0 = t*20, obase = t*10;
  {
    const uint2* s2 = (const uint2*)((const uint*)a2 + (size_t)i*13536);
    uint2* d = (uint2*)xt;
    for (int idx = tid; idx < 3888; idx += 256){
      int d2 = idx % 9, rc = idx / 9;
      int c = rc & 15, r = rc >> 4;
      int dwi = d2*2, jg = dwi >> 2, part = dwi & 3;
      d[(r*340 + jg*68 + c*4 + part) >> 1] = s2[((size_t)(r0 + r)*16 + c)*9 + d2];
    }
  }
  __syncthreads();
  const int wv = tid >> 6, lane = tid & 63;
  const int npx = lane & 15, jg = lane >> 4;
  // ---- conv3 stage (depth-1 prefetch over 25 main taps)
  {
    int baseq[2], ohl[2], owl[2];
    #pragma unroll
    for (int q=0;q<2;++q){
      int px = (wv*2+q)*16 + npx; if (px > 71) px = 71;
      ohl[q] = px/6; owl[q] = px - ohl[q]*6;
      baseq[q] = 2*ohl[q]*680 + jg*136 + 2*owl[q]*8;
    }
    f32x4 acc[3][2];
    #pragma unroll
    for (int mt=0;mt<3;++mt){
      f32x4 bv;
      #pragma unroll
      for (int reg=0;reg<4;++reg) bv[reg] = b3[mt*16 + jg*4 + reg];
      acc[mt][0]=bv; acc[mt][1]=bv;
    }
    const f16* agl = w3m + (size_t)lane*8;
    f16x8 caf0 = *(const f16x8*)(agl);
    f16x8 caf1 = *(const f16x8*)(agl + 512);
    f16x8 caf2 = *(const f16x8*)(agl + 1024);
    f16x8 cbf0 = *(const f16x8*)(xt + baseq[0]);
    f16x8 cbf1 = *(const f16x8*)(xt + baseq[1]);
    #pragma unroll
    for (int s=0; s<25; ++s){
      f16x8 naf0, naf1, naf2, nbf0, nbf1;
      if (s < 24){
        const int sn = s + 1;
        naf0 = *(const f16x8*)(agl + (size_t)(sn*3 + 0)*512);
        naf1 = *(const f16x8*)(agl + (size_t)(sn*3 + 1)*512);
        naf2 = *(const f16x8*)(agl + (size_t)(sn*3 + 2)*512);
        const int off = (sn/5)*680 + (sn%5)*8;
        nbf0 = *(const f16x8*)(xt + baseq[0] + off);
        nbf1 = *(const f16x8*)(xt + baseq[1] + off);
      }
      acc[0][0] = __builtin_amdgcn_mfma_f32_16x16x32_f16(caf0, cbf0, acc[0][0], 0, 0, 0);
      acc[0][1] = __builtin_amdgcn_mfma_f32_16x16x32_f16(caf0, cbf1, acc[0][1], 0, 0, 0);
      acc[1][0] = __builtin_amdgcn_mfma_f32_16x16x32_f16(caf1, cbf0, acc[1][0], 0, 0, 0);
      acc[1][1] = __builtin_amdgcn_mfma_f32_16x16x32_f16(caf1, cbf1, acc[1][1], 0, 0, 0);
      acc[2][0] = __builtin_amdgcn_mfma_f32_16x16x32_f16(caf2, cbf0, acc[2][0], 0, 0, 0);
      acc[2][1] = __builtin_amdgcn_mfma_f32_16x16x32_f16(caf2, cbf1, acc[2][1], 0, 0, 0);
      if (s < 24){ caf0=naf0; caf1=naf1; caf2=naf2; cbf0=nbf0; cbf1=nbf1; }
    }
    #pragma unroll
    for (int e=0;e<4;++e){
      const int s = 25 + e;
      f16x8 af[3];
      #pragma unroll
      for (int mt=0;mt<3;++mt)
        af[mt] = *(const f16x8*)(agl + (size_t)(s*3 + mt)*512);
      int p1 = e*8 + jg*2; int p2 = p1 + 1;
      if (p1 > 24) p1 = 24;
      if (p2 > 24) p2 = 24;
      const int kh1 = p1/5, kw1 = p1 - kh1*5;
      const int kh2 = p2/5, kw2 = p2 - kh2*5;
      #pragma unroll
      for (int q=0;q<2;++q){
        f16x4 lo = *(const f16x4*)(xt + (2*ohl[q]+kh1)*680 + 544 + (2*owl[q]+kw1)*8);
        f16x4 hi = *(const f16x4*)(xt + (2*ohl[q]+kh2)*680 + 544 + (2*owl[q]+kw2)*8);
        f16x8 bq = __builtin_shufflevector(lo, hi, 0,1,2,3,4,5,6,7);
        #pragma unroll
        for (int mt=0;mt<3;++mt)
          acc[mt][q] = __builtin_amdgcn_mfma_f32_16x16x32_f16(af[mt], bq, acc[mt][q], 0, 0, 0);
      }
    }
    #pragma unroll
    for (int q=0;q<2;++q){
      int px = (wv*2+q)*16 + npx;
      if (px >= 72) continue;
      #pragma unroll
      for (int mt=0;mt<3;++mt){
        union { f16 h[4]; uint2 q2; } pk;
        #pragma unroll
        for (int reg=0;reg<4;++reg){
          float r = acc[mt][q][reg]; if (r < 0.f) r = 0.f;
          pk.h[reg] = (f16)r;
        }
        *(uint2*)(a3t + px*56 + mt*16 + jg*4) = pk.q2;
      }
    }
  }
  __syncthreads();
  // ---- conv4 stage (depth-1 prefetch over 14 K-steps)
  {
    f32x4 acc4[3];
    {
      f32x4 bv;
      #pragma unroll
      for (int reg=0;reg<4;++reg) bv[reg] = b4[wv*16 + jg*4 + reg];
      acc4[0]=bv; acc4[1]=bv; acc4[2]=bv;
    }
    int ohn[3], own[3];
    #pragma unroll
    for (int nt=0;nt<3;++nt){
      int px = nt*16 + npx; if (px > 39) px = 39;
      ohn[nt] = px >> 2; own[nt] = px & 3;
    }
    const f16* agl = w4m + (size_t)lane*8;
    f16x8 caf, cb0, cb1, cb2;
    {
      caf = *(const f16x8*)(agl + (size_t)wv*512);
      const int ci0 = jg*8;
      cb0 = *(const f16x8*)(a3t + (ohn[0]*6 + own[0])*56 + ci0);
      cb1 = *(const f16x8*)(a3t + (ohn[1]*6 + own[1])*56 + ci0);
      cb2 = *(const f16x8*)(a3t + (ohn[2]*6 + own[2])*56 + ci0);
    }
    #pragma unroll
    for (int s=0; s<14; ++s){
      f16x8 naf, nb0, nb1, nb2;
      if (s < 13){
        const int sn = s + 1;
        naf = *(const f16x8*)(agl + (size_t)(sn*4 + wv)*512);
        int k8 = sn*32 + jg*8;
        int pos, ci0;
        if (k8 >= 432){ pos = 8; ci0 = 40; }
        else { pos = k8 / 48; ci0 = k8 - pos*48; }
        const int kh = pos/3, kw = pos - kh*3;
        nb0 = *(const f16x8*)(a3t + ((ohn[0]+kh)*6 + own[0]+kw)*56 + ci0);
        nb1 = *(const f16x8*)(a3t + ((ohn[1]+kh)*6 + own[1]+kw)*56 + ci0);
        nb2 = *(const f16x8*)(a3t + ((ohn[2]+kh)*6 + own[2]+kw)*56 + ci0);
      }
      acc4[0] = __builtin_amdgcn_mfma_f32_16x16x32_f16(caf, cb0, acc4[0], 0, 0, 0);
      acc4[1] = __builtin_amdgcn_mfma_f32_16x16x32_f16(caf, cb1, acc4[1], 0, 0, 0);
      acc4[2] = __builtin_amdgcn_mfma_f32_16x16x32_f16(caf, cb2, acc4[2], 0, 0, 0);
      if (s < 13){ caf = naf; cb0 = nb0; cb1 = nb1; cb2 = nb2; }
    }
    #pragma unroll
    for (int nt=0;nt<3;++nt){
      int px = nt*16 + npx;
      if (px >= 40) continue;
      union { f16 h[4]; uint2 q2; } pk;
      #pragma unroll
      for (int reg=0;reg<4;++reg){
        float r = acc4[nt][reg]; if (r < 0.f) r = 0.f;
        pk.h[reg] = (f16)r;
      }
      *(uint2*)(a4 + ((size_t)i*80 + obase*4 + px)*64 + wv*16 + jg*4) = pk.q2;
    }
  }
}

// ---------------------------------------------------------------- fc1 (MFMA, pipelined) + fc2..fc4 + AEBS fused
// 4 images/block (M rows replicate each image 4x); grid Bc/4, XCD-swizzled; tail = 64 lanes/img.
__global__ __launch_bounds__(256) void fc1tail_k(const f16* __restrict__ a4, const f16* __restrict__ w1m,
    const float* __restrict__ fc1b, const float* __restrict__ dist, const float* __restrict__ speed,
    const float* __restrict__ fW2, const float* __restrict__ fb2,
    const float* __restrict__ fW3, const float* __restrict__ fb3,
    const float* __restrict__ fW4, const float* __restrict__ fb4,
    const float* __restrict__ aW1, const float* __restrict__ ab1,
    const float* __restrict__ aW2, const float* __restrict__ ab2,
    const float* __restrict__ aW3, const float* __restrict__ ab3,
    float* __restrict__ out, int ib, int n){
  __shared__ float red[4][64][28];
  __shared__ float x1s[4][100];
  __shared__ float h2s[4][50];
  __shared__ float h3s[4][10];
  __shared__ float stg[4];
  __shared__ float hb1[4][12];
  __shared__ float hb2[4][24];
  const int tid = threadIdx.x;
  const int wv = tid >> 6, lane = tid & 63;
  const int bxr = blockIdx.x;
  const int bx = ((gridDim.x & 7) == 0) ? ((bxr & 7)*(gridDim.x >> 3) + (bxr >> 3)) : bxr;
  const int img0 = bx*4;
  f32x4 acc[7];
  #pragma unroll
  for (int nt=0;nt<7;++nt) acc[nt] = (f32x4){0.f,0.f,0.f,0.f};
  const f16* ap = a4 + (size_t)(img0 + ((lane & 15) & 3))*5120 + (lane >> 4)*8;
  const f16* bp = w1m + (size_t)lane*8;
  const int s0 = wv*40;
  f16x8 cav = *(const f16x8*)(ap + s0*32);
  f16x8 cbv0 = *(const f16x8*)(bp + (size_t)(s0*7 + 0)*512);
  f16x8 cbv1 = *(const f16x8*)(bp + (size_t)(s0*7 + 1)*512);
  f16x8 cbv2 = *(const f16x8*)(bp + (size_t)(s0*7 + 2)*512);
  f16x8 cbv3 = *(const f16x8*)(bp + (size_t)(s0*7 + 3)*512);
  f16x8 cbv4 = *(const f16x8*)(bp + (size_t)(s0*7 + 4)*512);
  f16x8 cbv5 = *(const f16x8*)(bp + (size_t)(s0*7 + 5)*512);
  f16x8 cbv6 = *(const f16x8*)(bp + (size_t)(s0*7 + 6)*512);
  #pragma unroll 1
  for (int s = s0; s < s0 + 40; ++s){
    f16x8 nav, nbv0, nbv1, nbv2, nbv3, nbv4, nbv5, nbv6;
    const bool more = (s + 1 < s0 + 40);
    if (more){
      nav  = *(const f16x8*)(ap + (s+1)*32);
      nbv0 = *(const f16x8*)(bp + (size_t)((s+1)*7 + 0)*512);
      nbv1 = *(const f16x8*)(bp + (size_t)((s+1)*7 + 1)*512);
      nbv2 = *(const f16x8*)(bp + (size_t)((s+1)*7 + 2)*512);
      nbv3 = *(const f16x8*)(bp + (size_t)((s+1)*7 + 3)*512);
      nbv4 = *(const f16x8*)(bp + (size_t)((s+1)*7 + 4)*512);
      nbv5 = *(const f16x8*)(bp + (size_t)((s+1)*7 + 5)*512);
      nbv6 = *(const f16x8*)(bp + (size_t)((s+1)*7 + 6)*512);
    }
    acc[0] = __builtin_amdgcn_mfma_f32_16x16x32_f16(cav, cbv0, acc[0], 0, 0, 0);
    acc[1] = __builtin_amdgcn_mfma_f32_16x16x32_f16(cav, cbv1, acc[1], 0, 0, 0);
    acc[2] = __builtin_amdgcn_mfma_f32_16x16x32_f16(cav, cbv2, acc[2], 0, 0, 0);
    acc[3] = __builtin_amdgcn_mfma_f32_16x16x32_f16(cav, cbv3, acc[3], 0, 0, 0);
    acc[4] = __builtin_amdgcn_mfma_f32_16x16x32_f16(cav, cbv4, acc[4], 0, 0, 0);
    acc[5] = __builtin_amdgcn_mfma_f32_16x16x32_f16(cav, cbv5, acc[5], 0, 0, 0);
    acc[6] = __builtin_amdgcn_mfma_f32_16x16x32_f16(cav, cbv6, acc[6], 0, 0, 0);
    if (more){
      cav = nav;
      cbv0 = nbv0; cbv1 = nbv1; cbv2 = nbv2; cbv3 = nbv3;
      cbv4 = nbv4; cbv5 = nbv5; cbv6 = nbv6;
    }
  }
  #pragma unroll
  for (int nt=0;nt<7;++nt)
    #pragma unroll
    for (int reg=0;reg<4;++reg)
      red[wv][lane][nt*4+reg] = acc[nt][reg];
  __syncthreads();
  // reduce 4 wave-partials + bias + ReLU ; image imgl lives in M-row = imgl (rows 4..15 are replicas)
  for (int idx = tid; idx < 448; idx += 256){
    int imgl = idx / 112, j = idx - imgl*112;
    if (j >= 100) continue;
    int l = j & 15;                      // M-row imgl -> lane = (imgl>>2)<<4 | (j&15) = j&15 for imgl<4
    int c = (j >> 4)*4 + imgl;           // reg = imgl&3 = imgl
    float s = red[0][l][c] + red[1][l][c] + red[2][l][c] + red[3][l][c] + fc1b[j];
    x1s[imgl][j] = s > 0.f ? s : 0.f;
  }
  __syncthreads();
  const int g = wv, l64 = lane;          // 4 imgs x 64 lanes
  const int img = ib + img0 + g;
  if (l64 < 50){
    float s = fb2[l64];
    #pragma unroll 4
    for (int k = 0; k < 100; ++k) s = fmaf(x1s[g][k], fW2[k*50+l64], s);
    h2s[g][l64] = s > 0.f ? s : 0.f;
  }
  __syncthreads();
  if (l64 < 10){
    float s = fb3[l64];
    #pragma unroll
    for (int k = 0; k < 50; ++k) s = fmaf(h2s[g][k], fW3[k*10+l64], s);
    h3s[g][l64] = s > 0.f ? s : 0.f;
  }
  __syncthreads();
  if (l64 == 0){
    float s = fb4[0];
    #pragma unroll
    for (int k = 0; k < 10; ++k) s = fmaf(h3s[g][k], fW4[k], s);
    stg[g] = s;
  }
  __syncthreads();
  if (l64 < 12){
    float s0v = stg[g], dd = dist[img], sp = speed[img];
    float s = ab1[l64] + s0v*aW1[l64] + dd*aW1[12+l64] + sp*aW1[24+l64];
    hb1[g][l64] = s > 0.f ? s : 0.f;
  }
  __syncthreads();
  if (l64 < 24){
    float s = ab2[l64];
    #pragma unroll
    for (int k=0;k<12;++k) s = fmaf(hb1[g][k], aW2[k*24+l64], s);
    hb2[g][l64] = s > 0.f ? s : 0.f;
  }
  __syncthreads();
  if (l64 < 4){
    float s = ab3[l64];
    #pragma unroll
    for (int k=0;k<24;++k) s = fmaf(hb2[g][k], aW3[k*4+l64], s);
    out[(size_t)img*4 + l64] = s;
  }
}

// ================================================================ host
extern "C" void kernel_launch(void* const* d_in, const int* in_sizes, int n_in,
                              void* d_out, int out_size, void* d_ws, size_t ws_size,
                              hipStream_t stream){
  const float* rgb   = (const float*)d_in[0];
  const float* dist  = (const float*)d_in[1];
  const float* speed = (const float*)d_in[2];
  const float* cw1 = (const float*)d_in[3];
  const float* cb1 = (const float*)d_in[4];
  const float* cw2 = (const float*)d_in[5];
  const float* cb2 = (const float*)d_in[6];
  const float* cw3 = (const float*)d_in[7];
  const float* cb3 = (const float*)d_in[8];
  const float* cw4 = (const float*)d_in[9];
  const float* cb4 = (const float*)d_in[10];
  const float* fW1 = (const float*)d_in[11];
  const float* fb1 = (const float*)d_in[12];
  const float* fW2 = (const float*)d_in[13];
  const float* fb2 = (const float*)d_in[14];
  const float* fW3 = (const float*)d_in[15];
  const float* fb3 = (const float*)d_in[16];
  const float* fW4 = (const float*)d_in[17];
  const float* fb4 = (const float*)d_in[18];
  const float* aW1 = (const float*)d_in[19];
  const float* ab1 = (const float*)d_in[20];
  const float* aW2 = (const float*)d_in[21];
  const float* ab2 = (const float*)d_in[22];
  const float* aW3 = (const float*)d_in[23];
  const float* ab3 = (const float*)d_in[24];
  float* out = (float*)d_out;
  const int B = in_sizes[0] / 15000;

  auto ALN = [](size_t x){ return (x + 255) & ~(size_t)255; };
  const size_t fixed = ALN(2048) + ALN(58368) + ALN(89088) + ALN(57344) + ALN(1146880);

  int nc = 1;
  while (nc < 32){
    size_t Bc = (size_t)(B / nc);
    size_t need = fixed + ALN(Bc*54144) + ALN(Bc*10240);
    if (need <= ws_size) break;
    nc *= 2;
  }
  const int Bc = B / nc;

  char* ws = (char*)d_ws;
  size_t o = 0;
  auto alloc = [&](size_t bytes)->char*{ char* p = ws + o; o += ALN(bytes); return p; };
  f16* w1c = (f16*)alloc(2048);
  f16* w2c = (f16*)alloc(58368);
  f16* w3m = (f16*)alloc(89088);
  f16* w4m = (f16*)alloc(57344);
  f16* w1m = (f16*)alloc(1146880);
  f16* a2  = (f16*)alloc((size_t)Bc*54144);
  f16* a4  = (f16*)alloc((size_t)Bc*10240);

  repack_all_k<<<dim3(280), dim3(256), 0, stream>>>(w1c, w2c, w3m, w4m, w1m,
                                                    cw1, cw2, cw3, cw4, fW1);

  for (int c = 0; c < nc; ++c){
    const int ib = c*Bc;
    conv12_k<<<dim3(Bc*6),  dim3(256), 0, stream>>>(rgb, w1c, cb1, w2c, cb2, a2, ib);
    conv34_k<<<dim3(Bc*2),  dim3(256), 0, stream>>>(a2, w3m, cb3, w4m, cb4, a4);
    fc1tail_k<<<dim3(Bc/4), dim3(256), 0, stream>>>(a4, w1m, fb1, dist, speed,
        fW2, fb2, fW3, fb3, fW4, fb4, aW1, ab1, aW2, ab2, aW3, ab3, out, ib, Bc);
  }
}

// Round 17
// 158.373 us; speedup vs baseline: 1.3323x; 1.0062x over previous
//
#include <hip/hip_runtime.h>

typedef _Float16 f16;
typedef _Float16 f16x4 __attribute__((ext_vector_type(4)));
typedef _Float16 f16x8 __attribute__((ext_vector_type(8)));
typedef float f32x4 __attribute__((ext_vector_type(4)));

// ---------------------------------------------------------------- merged weight repack (all MFMA fragments)
__global__ __launch_bounds__(256) void repack_all_k(
    f16* __restrict__ w1c, f16* __restrict__ w2c, f16* __restrict__ w3m,
    f16* __restrict__ w4m, f16* __restrict__ wfc,
    const float* __restrict__ s1, const float* __restrict__ s2, const float* __restrict__ s3,
    const float* __restrict__ s4, const float* __restrict__ sf){
  const int tid0 = blockIdx.x*256 + threadIdx.x, stride = gridDim.x*256;
  for (int idx = tid0; idx < 1024; idx += stride){
    int i = idx & 7, l = (idx >> 3) & 63, mt = idx >> 9;
    int co = mt*16 + (l & 15);
    int jg = l >> 4;
    int kw = -1, kh = 0;
    if (jg < 2){ kw = jg*2 + (i >> 2); kh = i & 3; }
    else if (jg == 2){
      if (i < 4){ kw = 4; kh = i; }
      else if (i == 4){ kw = 0; kh = 4; }
      else if (i == 5){ kw = 1; kh = 4; }
    } else {
      if (i == 0){ kw = 4; kh = 4; }
      else if (i == 4){ kw = 2; kh = 4; }
      else if (i == 5){ kw = 3; kh = 4; }
    }
    f16 v = (f16)0.0f;
    if (co < 24 && kw >= 0) v = (f16)s1[co*25 + kh*5 + kw];
    w1c[idx] = v;
  }
  for (int idx = tid0; idx < 29184; idx += stride){
    int i = idx & 7, l = (idx >> 3) & 63, rest = idx >> 9;
    int mt = rest % 3, s = rest / 3;
    int co = mt*16 + (l & 15);
    int k = s*32 + (l >> 4)*8 + i;
    f16 v = (f16)0.0f;
    if (co < 36 && k < 600){
      int tap = k / 24, ci = k - tap*24;
      v = (f16)s2[(co*24 + ci)*25 + tap];
    }
    w2c[idx] = v;
  }
  for (int idx = tid0; idx < 44544; idx += stride){
    int i = idx & 7, l = (idx >> 3) & 63, rest = idx >> 9;
    int mt = rest % 3, s = rest / 3;
    int co = mt*16 + (l & 15);
    f16 v = (f16)0.0f;
    if (s < 25){
      int ci = (l >> 4)*8 + i;
      v = (f16)s3[(co*36 + ci)*25 + s];
    } else {
      int ke = (s - 25)*32 + (l >> 4)*8 + i;
      if (ke < 100){
        int p = ke >> 2, ci = 32 + (ke & 3);
        v = (f16)s3[(co*36 + ci)*25 + p];
      }
    }
    w3m[idx] = v;
  }
  for (int idx = tid0; idx < 28672; idx += stride){
    int i = idx & 7, l = (idx >> 3) & 63, rest = idx >> 9;
    int mt = rest & 3, s = rest >> 2;
    int co = mt*16 + (l & 15);
    int k = s*32 + (l >> 4)*8 + i;
    f16 v = (f16)0.0f;
    if (k < 432){
      int pos = k / 48, ci = k - pos*48;
      v = (f16)s4[(co*48 + ci)*9 + pos];
    }
    w4m[idx] = v;
  }
  for (int t = tid0; t < 71680; t += stride){
    int l = t & 63, rest = t >> 6;
    int nt = rest % 7, s = rest / 7;
    int j = nt*16 + (l & 15);
    int kb = s*32 + (l >> 4)*8;
    union { f16 h[8]; f16x8 v; } pk;
    #pragma unroll
    for (int i=0;i<8;++i){
      int k = kb + i;
      int row = (k & 63)*80 + (k >> 6);
      pk.h[i] = (j < 100) ? (f16)sf[(size_t)row*100 + j] : (f16)0.0f;
    }
    *(f16x8*)(wfc + (size_t)t*8) = pk.v;
  }
}

// ---------------------------------------------------------------- conv1+conv2 fused (both MFMA, A-depth-3 pipelined, XCD-swizzled)
__global__ __launch_bounds__(256) void conv12_k(const float* __restrict__ rgb, const f16* __restrict__ w1m,
                                                const float* __restrict__ b1, const f16* __restrict__ w2c,
                                                const float* __restrict__ b2, f16* __restrict__ a2, int ib){
  __shared__ __align__(16) f16 xb[75*46 + 8];      // 6916 B
  __shared__ __align__(16) f16 xt[2*19*18*24];     // 32832 B
  const int tid = threadIdx.x;
  const int bxr = blockIdx.x;
  const int bx = ((gridDim.x & 7) == 0) ? ((bxr & 7)*(gridDim.x >> 3) + (bxr >> 3)) : bxr;
  const int i = bx / 6, t = bx - i*6;
  const int h0 = t*32, oh0 = t*8;
  const float* img = rgb + (size_t)(ib + i)*15000;
  for (int idx = tid; idx < 825; idx += 256){
    int w = idx / 11, h4 = idx - w*11;
    int hh = h4*4, h = h0 + hh;
    union { f16 hv[4]; uint u[2]; } pk;
    if (h < 200){
      float4 v = *(const float4*)(img + w*200 + h);
      pk.hv[0] = (v.x > 0.f) ? (f16)1.0f : (f16)0.0f;
      pk.hv[1] = (v.y > 0.f) ? (f16)1.0f : (f16)0.0f;
      pk.hv[2] = (v.z > 0.f) ? (f16)1.0f : (f16)0.0f;
      pk.hv[3] = (v.w > 0.f) ? (f16)1.0f : (f16)0.0f;
    } else {
      pk.u[0] = 0u; pk.u[1] = 0u;
    }
    *(uint*)(xb + w*46 + hh)     = pk.u[0];
    *(uint*)(xb + w*46 + hh + 2) = pk.u[1];
  }
  __syncthreads();
  const int wv = tid >> 6, lane = tid & 63;
  const int jgrp = lane >> 4, npx = lane & 15;
  // ---- phase 1: conv1 MFMA into xt (6-read gather, depth-1 prefetch)
  {
    f16x8 a1f0 = *(const f16x8*)(w1m + (size_t)lane*8);
    f16x8 a1f1 = *(const f16x8*)(w1m + (size_t)(64 + lane)*8);
    const int tA = (jgrp < 2) ? jgrp*92 : ((jgrp == 2) ? 184 : 188);
    const int tC = (jgrp == 1) ? 138 : 46;
    const int tE = (jgrp == 2) ? 4  : ((jgrp == 3) ? 96  : 0);
    const int tF = (jgrp == 2) ? 50 : ((jgrp == 3) ? 142 : 0);
    f32x4 bv0, bv1;
    #pragma unroll
    for (int reg=0; reg<4; ++reg){
      int c0 = jgrp*4 + reg;
      int c1 = 16 + jgrp*4 + reg;
      bv0[reg] = b1[c0];
      bv1[reg] = (c1 < 24) ? b1[c1] : 0.f;
    }
    const int qn = (wv == 3) ? 10 : 11;
    union { uint d[4]; f16x8 v; } bqc, bqn;
    int pxt_c, rr_c, ow_c;
    {
      int pxt = wv*16 + npx;
      int px = (pxt > 683) ? 683 : pxt;
      int rr = px/36, ow = px - rr*36;
      const int base = 2*(ow*46 + rr);
      uint ra = *(const uint*)(xb + base + tA);
      uint rb = *(const uint*)(xb + base + tA + 2);
      uint rc = *(const uint*)(xb + base + tC);
      uint rd = *(const uint*)(xb + base + tC + 2);
      uint re = *(const unsigned short*)(xb + base + tE);
      uint rf = *(const unsigned short*)(xb + base + tF);
      bqc.d[0] = ra; bqc.d[1] = rb;
      bqc.d[2] = (jgrp < 2) ? rc : (re | (rf << 16));
      bqc.d[3] = rd;
      pxt_c = pxt; rr_c = rr; ow_c = ow;
    }
    for (int q=0; q<qn; ++q){
      int pxt_n = 0, rr_n = 0, ow_n = 0;
      if (q+1 < qn){
        int nt = wv + 4*(q+1);
        pxt_n = nt*16 + npx;
        int px = (pxt_n > 683) ? 683 : pxt_n;
        rr_n = px/36; ow_n = px - rr_n*36;
        const int base = 2*(ow_n*46 + rr_n);
        uint ra = *(const uint*)(xb + base + tA);
        uint rb = *(const uint*)(xb + base + tA + 2);
        uint rc = *(const uint*)(xb + base + tC);
        uint rd = *(const uint*)(xb + base + tC + 2);
        uint re = *(const unsigned short*)(xb + base + tE);
        uint rf = *(const unsigned short*)(xb + base + tF);
        bqn.d[0] = ra; bqn.d[1] = rb;
        bqn.d[2] = (jgrp < 2) ? rc : (re | (rf << 16));
        bqn.d[3] = rd;
      }
      f32x4 c0 = __builtin_amdgcn_mfma_f32_16x16x32_f16(a1f0, bqc.v, bv0, 0, 0, 0);
      f32x4 c1 = __builtin_amdgcn_mfma_f32_16x16x32_f16(a1f1, bqc.v, bv1, 0, 0, 0);
      if (pxt_c <= 683){
        f16* dst = xt + (((ow_c & 1)*19 + rr_c)*18 + (ow_c >> 1))*24;
        union { f16 h[4]; uint2 q2; } pk;
        #pragma unroll
        for (int reg=0; reg<4; ++reg){ float r = c0[reg]; if (r<0.f) r=0.f; pk.h[reg]=(f16)r; }
        *(uint2*)(dst + jgrp*4) = pk.q2;
        if (jgrp < 2){
          #pragma unroll
          for (int reg=0; reg<4; ++reg){ float r = c1[reg]; if (r<0.f) r=0.f; pk.h[reg]=(f16)r; }
          *(uint2*)(dst + 16 + jgrp*4) = pk.q2;
        }
      }
      if (q+1 < qn){ bqc.v = bqn.v; pxt_c = pxt_n; rr_c = rr_n; ow_c = ow_n; }
    }
  }
  __syncthreads();
  // ---- phase 2: conv2 MFMA, K-packed 19 steps; A prefetch depth 3 (L2 stream), B depth 1 (LDS)
  int baddr[19];
  #pragma unroll
  for (int s=0; s<19; ++s){
    int m = s*4 + jgrp;
    int tap = m / 3, r3 = m - tap*3;
    if (m >= 75){ tap = 24; r3 = 0; }
    int kh = tap / 5, kw = tap - kh*5;
    int par = kw & 1, kws = kw >> 1;
    baddr[s] = ((par*19 + kh)*18 + npx + kws)*24 + r3*8;
  }
  f32x4 acc2[3][2];
  #pragma unroll
  for (int mt=0; mt<3; ++mt){
    f32x4 bv;
    #pragma unroll
    for (int reg=0; reg<4; ++reg){
      int co = mt*16 + jgrp*4 + reg;
      bv[reg] = (co < 36) ? b2[co] : 0.0f;
    }
    acc2[mt][0] = bv; acc2[mt][1] = bv;
  }
  const f16* agl = w2c + (size_t)lane*8;
  const int rowo = 4*wv*432;
  f16x8 afq[3][3];   // ring: slot p holds step s with s%3==p (indices constant-fold under full unroll)
  #pragma unroll
  for (int p=0; p<3; ++p)
    #pragma unroll
    for (int mt=0; mt<3; ++mt)
      afq[p][mt] = *(const f16x8*)(agl + (size_t)(p*3 + mt)*512);
  f16x8 bf0, bf1;
  {
    const f16* bb0 = xt + baddr[0] + rowo;
    bf0 = *(const f16x8*)(bb0);
    bf1 = *(const f16x8*)(bb0 + 2*432);
  }
  #pragma unroll
  for (int s=0; s<19; ++s){
    const int sl = s % 3;
    f16x8 naf0, naf1, naf2, nbf0, nbf1;
    const bool moreA = (s + 3 < 19);
    if (moreA){
      naf0 = *(const f16x8*)(agl + (size_t)((s+3)*3 + 0)*512);
      naf1 = *(const f16x8*)(agl + (size_t)((s+3)*3 + 1)*512);
      naf2 = *(const f16x8*)(agl + (size_t)((s+3)*3 + 2)*512);
    }
    if (s < 18){
      const f16* bb0 = xt + baddr[s+1] + rowo;
      nbf0 = *(const f16x8*)(bb0);
      nbf1 = *(const f16x8*)(bb0 + 2*432);
    }
    acc2[0][0] = __builtin_amdgcn_mfma_f32_16x16x32_f16(afq[sl][0], bf0, acc2[0][0], 0, 0, 0);
    acc2[0][1] = __builtin_amdgcn_mfma_f32_16x16x32_f16(afq[sl][0], bf1, acc2[0][1], 0, 0, 0);
    acc2[1][0] = __builtin_amdgcn_mfma_f32_16x16x32_f16(afq[sl][1], bf0, acc2[1][0], 0, 0, 0);
    acc2[1][1] = __builtin_amdgcn_mfma_f32_16x16x32_f16(afq[sl][1], bf1, acc2[1][1], 0, 0, 0);
    acc2[2][0] = __builtin_amdgcn_mfma_f32_16x16x32_f16(afq[sl][2], bf0, acc2[2][0], 0, 0, 0);
    acc2[2][1] = __builtin_amdgcn_mfma_f32_16x16x32_f16(afq[sl][2], bf1, acc2[2][1], 0, 0, 0);
    if (moreA){ afq[sl][0] = naf0; afq[sl][1] = naf1; afq[sl][2] = naf2; }
    if (s < 18){ bf0 = nbf0; bf1 = nbf1; }
  }
  #pragma unroll
  for (int u=0; u<2; ++u){
    const int oh = oh0 + 2*wv + u;
    if (oh >= 47) continue;
    #pragma unroll
    for (int mt=0; mt<3; ++mt){
      const int co0s = mt*16 + jgrp*4;
      if (co0s >= 36) continue;
      union { f16 h[4]; uint2 q; } pk;
      #pragma unroll
      for (int reg=0; reg<4; ++reg){
        float r = acc2[mt][u][reg]; if (r < 0.f) r = 0.f;
        pk.h[reg] = (f16)r;
      }
      *(uint2*)(a2 + (((size_t)i*47 + oh)*16 + npx)*36 + co0s) = pk.q;
    }
  }
}

// ---------------------------------------------------------------- conv3+conv4 fused (per half-image, A-depth-3, XCD-swizzled)
__global__ __launch_bounds__(256) void conv34_k(const f16* __restrict__ a2, const f16* __restrict__ w3m,
                                                const float* __restrict__ b3, const f16* __restrict__ w4m,
                                                const float* __restrict__ b4, f16* __restrict__ a4){
  __shared__ __align__(16) f16 xt[27*680];     // 36720 B
  __shared__ __align__(16) f16 a3t[12*6*56];   // 8064 B
  const int tid = threadIdx.x;
  const int bxr = blockIdx.x;
  const int bx = ((gridDim.x & 7) == 0) ? ((bxr & 7)*(gridDim.x >> 3) + (bxr >> 3)) : bxr;
  const int i = bx >> 1, t = bx & 1;
  const int r0 = t*20, obase = t*10;
  {
    const uint2* s2 = (const uint2*)((const uint*)a2 + (size_t)i*13536);
    uint2* d = (uint2*)xt;
    for (int idx = tid; idx < 3888; idx += 256){
      int d2 = idx % 9, rc = idx / 9;
      int c = rc & 15, r = rc >> 4;
      int dwi = d2*2, jg = dwi >> 2, part = dwi & 3;
      d[(r*340 + jg*68 + c*4 + part) >> 1] = s2[((size_t)(r0 + r)*16 + c)*9 + d2];
    }
  }
  __syncthreads();
  const int wv = tid >> 6, lane = tid & 63;
  const int npx = lane & 15, jg = lane >> 4;
  // ---- conv3 stage (A-depth-3 / B-depth-1 over 25 main taps)
  {
    int baseq[2], ohl[2], owl[2];
    #pragma unroll
    for (int q=0;q<2;++q){
      int px = (wv*2+q)*16 + npx; if (px > 71) px = 71;
      ohl[q] = px/6; owl[q] = px - ohl[q]*6;
      baseq[q] = 2*ohl[q]*680 + jg*136 + 2*owl[q]*8;
    }
    f32x4 acc[3][2];
    #pragma unroll
    for (int mt=0;mt<3;++mt){
      f32x4 bv;
      #pragma unroll
      for (int reg=0;reg<4;++reg) bv[reg] = b3[mt*16 + jg*4 + reg];
      acc[mt][0]=bv; acc[mt][1]=bv;
    }
    const f16* agl = w3m + (size_t)lane*8;
    f16x8 afq[3][3];
    #pragma unroll
    for (int p=0;p<3;++p)
      #pragma unroll
      for (int mt=0;mt<3;++mt)
        afq[p][mt] = *(const f16x8*)(agl + (size_t)(p*3 + mt)*512);
    f16x8 cbf0 = *(const f16x8*)(xt + baseq[0]);
    f16x8 cbf1 = *(const f16x8*)(xt + baseq[1]);
    #pragma unroll
    for (int s=0; s<25; ++s){
      const int sl = s % 3;
      f16x8 naf0, naf1, naf2, nbf0, nbf1;
      const bool moreA = (s + 3 < 25);
      if (moreA){
        naf0 = *(const f16x8*)(agl + (size_t)((s+3)*3 + 0)*512);
        naf1 = *(const f16x8*)(agl + (size_t)((s+3)*3 + 1)*512);
        naf2 = *(const f16x8*)(agl + (size_t)((s+3)*3 + 2)*512);
      }
      if (s < 24){
        const int sn = s + 1;
        const int off = (sn/5)*680 + (sn%5)*8;
        nbf0 = *(const f16x8*)(xt + baseq[0] + off);
        nbf1 = *(const f16x8*)(xt + baseq[1] + off);
      }
      acc[0][0] = __builtin_amdgcn_mfma_f32_16x16x32_f16(afq[sl][0], cbf0, acc[0][0], 0, 0, 0);
      acc[0][1] = __builtin_amdgcn_mfma_f32_16x16x32_f16(afq[sl][0], cbf1, acc[0][1], 0, 0, 0);
      acc[1][0] = __builtin_amdgcn_mfma_f32_16x16x32_f16(afq[sl][1], cbf0, acc[1][0], 0, 0, 0);
      acc[1][1] = __builtin_amdgcn_mfma_f32_16x16x32_f16(afq[sl][1], cbf1, acc[1][1], 0, 0, 0);
      acc[2][0] = __builtin_amdgcn_mfma_f32_16x16x32_f16(afq[sl][2], cbf0, acc[2][0], 0, 0, 0);
      acc[2][1] = __builtin_amdgcn_mfma_f32_16x16x32_f16(afq[sl][2], cbf1, acc[2][1], 0, 0, 0);
      if (moreA){ afq[sl][0]=naf0; afq[sl][1]=naf1; afq[sl][2]=naf2; }
      if (s < 24){ cbf0 = nbf0; cbf1 = nbf1; }
    }
    #pragma unroll
    for (int e=0;e<4;++e){
      const int s = 25 + e;
      f16x8 af[3];
      #pragma unroll
      for (int mt=0;mt<3;++mt)
        af[mt] = *(const f16x8*)(agl + (size_t)(s*3 + mt)*512);
      int p1 = e*8 + jg*2; int p2 = p1 + 1;
      if (p1 > 24) p1 = 24;
      if (p2 > 24) p2 = 24;
      const int kh1 = p1/5, kw1 = p1 - kh1*5;
      const int kh2 = p2/5, kw2 = p2 - kh2*5;
      #pragma unroll
      for (int q=0;q<2;++q){
        f16x4 lo = *(const f16x4*)(xt + (2*ohl[q]+kh1)*680 + 544 + (2*owl[q]+kw1)*8);
        f16x4 hi = *(const f16x4*)(xt + (2*ohl[q]+kh2)*680 + 544 + (2*owl[q]+kw2)*8);
        f16x8 bq = __builtin_shufflevector(lo, hi, 0,1,2,3,4,5,6,7);
        #pragma unroll
        for (int mt=0;mt<3;++mt)
          acc[mt][q] = __builtin_amdgcn_mfma_f32_16x16x32_f16(af[mt], bq, acc[mt][q], 0, 0, 0);
      }
    }
    #pragma unroll
    for (int q=0;q<2;++q){
      int px = (wv*2+q)*16 + npx;
      if (px >= 72) continue;
      #pragma unroll
      for (int mt=0;mt<3;++mt){
        union { f16 h[4]; uint2 q2; } pk;
        #pragma unroll
        for (int reg=0;reg<4;++reg){
          float r = acc[mt][q][reg]; if (r < 0.f) r = 0.f;
          pk.h[reg] = (f16)r;
        }
        *(uint2*)(a3t + px*56 + mt*16 + jg*4) = pk.q2;
      }
    }
  }
  __syncthreads();
  // ---- conv4 stage (A-depth-3 / B-depth-1 over 14 K-steps)
  {
    f32x4 acc4[3];
    {
      f32x4 bv;
      #pragma unroll
      for (int reg=0;reg<4;++reg) bv[reg] = b4[wv*16 + jg*4 + reg];
      acc4[0]=bv; acc4[1]=bv; acc4[2]=bv;
    }
    int ohn[3], own[3];
    #pragma unroll
    for (int nt=0;nt<3;++nt){
      int px = nt*16 + npx; if (px > 39) px = 39;
      ohn[nt] = px >> 2; own[nt] = px & 3;
    }
    const f16* agl = w4m + (size_t)lane*8;
    f16x8 afr[3];
    #pragma unroll
    for (int p=0;p<3;++p)
      afr[p] = *(const f16x8*)(agl + (size_t)(p*4 + wv)*512);
    f16x8 cb0, cb1, cb2;
    {
      const int ci0 = jg*8;
      cb0 = *(const f16x8*)(a3t + (ohn[0]*6 + own[0])*56 + ci0);
      cb1 = *(const f16x8*)(a3t + (ohn[1]*6 + own[1])*56 + ci0);
      cb2 = *(const f16x8*)(a3t + (ohn[2]*6 + own[2])*56 + ci0);
    }
    #pragma unroll
    for (int s=0; s<14; ++s){
      const int sl = s % 3;
      f16x8 naf, nb0, nb1, nb2;
      const bool moreA = (s + 3 < 14);
      if (moreA)
        naf = *(const f16x8*)(agl + (size_t)((s+3)*4 + wv)*512);
      if (s < 13){
        const int sn = s + 1;
        int k8 = sn*32 + jg*8;
        int pos, ci0;
        if (k8 >= 432){ pos = 8; ci0 = 40; }
        else { pos = k8 / 48; ci0 = k8 - pos*48; }
        const int kh = pos/3, kw = pos - kh*3;
        nb0 = *(const f16x8*)(a3t + ((ohn[0]+kh)*6 + own[0]+kw)*56 + ci0);
        nb1 = *(const f16x8*)(a3t + ((ohn[1]+kh)*6 + own[1]+kw)*56 + ci0);
        nb2 = *(const f16x8*)(a3t + ((ohn[2]+kh)*6 + own[2]+kw)*56 + ci0);
      }
      acc4[0] = __builtin_amdgcn_mfma_f32_16x16x32_f16(afr[sl], cb0, acc4[0], 0, 0, 0);
      acc4[1] = __builtin_amdgcn_mfma_f32_16x16x32_f16(afr[sl], cb1, acc4[1], 0, 0, 0);
      acc4[2] = __builtin_amdgcn_mfma_f32_16x16x32_f16(afr[sl], cb2, acc4[2], 0, 0, 0);
      if (moreA) afr[sl] = naf;
      if (s < 13){ cb0 = nb0; cb1 = nb1; cb2 = nb2; }
    }
    #pragma unroll
    for (int nt=0;nt<3;++nt){
      int px = nt*16 + npx;
      if (px >= 40) continue;
      union { f16 h[4]; uint2 q2; } pk;
      #pragma unroll
      for (int reg=0;reg<4;++reg){
        float r = acc4[nt][reg]; if (r < 0.f) r = 0.f;
        pk.h[reg] = (f16)r;
      }
      *(uint2*)(a4 + ((size_t)i*80 + obase*4 + px)*64 + wv*16 + jg*4) = pk.q2;
    }
  }
}

// ---------------------------------------------------------------- fc1 (MFMA, pipelined) + fc2..fc4 + AEBS fused
__global__ __launch_bounds__(256) void fc1tail_k(const f16* __restrict__ a4, const f16* __restrict__ w1m,
    const float* __restrict__ fc1b, const float* __restrict__ dist, const float* __restrict__ speed,
    const float* __restrict__ fW2, const float* __restrict__ fb2,
    const float* __restrict__ fW3, const float* __restrict__ fb3,
    const float* __restrict__ fW4, const float* __restrict__ fb4,
    const float* __restrict__ aW1, const float* __restrict__ ab1,
    const float* __restrict__ aW2, const float* __restrict__ ab2,
    const float* __restrict__ aW3, const float* __restrict__ ab3,
    float* __restrict__ out, int ib, int n){
  __shared__ float red[4][64][28];
  __shared__ float x1s[4][100];
  __shared__ float h2s[4][50];
  __shared__ float h3s[4][10];
  __shared__ float stg[4];
  __shared__ float hb1[4][12];
  __shared__ float hb2[4][24];
  const int tid = threadIdx.x;
  const int wv = tid >> 6, lane = tid & 63;
  const int bxr = blockIdx.x;
  const int bx = ((gridDim.x & 7) == 0) ? ((bxr & 7)*(gridDim.x >> 3) + (bxr >> 3)) : bxr;
  const int img0 = bx*4;
  f32x4 acc[7];
  #pragma unroll
  for (int nt=0;nt<7;++nt) acc[nt] = (f32x4){0.f,0.f,0.f,0.f};
  const f16* ap = a4 + (size_t)(img0 + ((lane & 15) & 3))*5120 + (lane >> 4)*8;
  const f16* bp = w1m + (size_t)lane*8;
  const int s0 = wv*40;
  f16x8 cav = *(const f16x8*)(ap + s0*32);
  f16x8 cbv0 = *(const f16x8*)(bp + (size_t)(s0*7 + 0)*512);
  f16x8 cbv1 = *(const f16x8*)(bp + (size_t)(s0*7 + 1)*512);
  f16x8 cbv2 = *(const f16x8*)(bp + (size_t)(s0*7 + 2)*512);
  f16x8 cbv3 = *(const f16x8*)(bp + (size_t)(s0*7 + 3)*512);
  f16x8 cbv4 = *(const f16x8*)(bp + (size_t)(s0*7 + 4)*512);
  f16x8 cbv5 = *(const f16x8*)(bp + (size_t)(s0*7 + 5)*512);
  f16x8 cbv6 = *(const f16x8*)(bp + (size_t)(s0*7 + 6)*512);
  #pragma unroll 1
  for (int s = s0; s < s0 + 40; ++s){
    f16x8 nav, nbv0, nbv1, nbv2, nbv3, nbv4, nbv5, nbv6;
    const bool more = (s + 1 < s0 + 40);
    if (more){
      nav  = *(const f16x8*)(ap + (s+1)*32);
      nbv0 = *(const f16x8*)(bp + (size_t)((s+1)*7 + 0)*512);
      nbv1 = *(const f16x8*)(bp + (size_t)((s+1)*7 + 1)*512);
      nbv2 = *(const f16x8*)(bp + (size_t)((s+1)*7 + 2)*512);
      nbv3 = *(const f16x8*)(bp + (size_t)((s+1)*7 + 3)*512);
      nbv4 = *(const f16x8*)(bp + (size_t)((s+1)*7 + 4)*512);
      nbv5 = *(const f16x8*)(bp + (size_t)((s+1)*7 + 5)*512);
      nbv6 = *(const f16x8*)(bp + (size_t)((s+1)*7 + 6)*512);
    }
    acc[0] = __builtin_amdgcn_mfma_f32_16x16x32_f16(cav, cbv0, acc[0], 0, 0, 0);
    acc[1] = __builtin_amdgcn_mfma_f32_16x16x32_f16(cav, cbv1, acc[1], 0, 0, 0);
    acc[2] = __builtin_amdgcn_mfma_f32_16x16x32_f16(cav, cbv2, acc[2], 0, 0, 0);
    acc[3] = __builtin_amdgcn_mfma_f32_16x16x32_f16(cav, cbv3, acc[3], 0, 0, 0);
    acc[4] = __builtin_amdgcn_mfma_f32_16x16x32_f16(cav, cbv4, acc[4], 0, 0, 0);
    acc[5] = __builtin_amdgcn_mfma_f32_16x16x32_f16(cav, cbv5, acc[5], 0, 0, 0);
    acc[6] = __builtin_amdgcn_mfma_f32_16x16x32_f16(cav, cbv6, acc[6], 0, 0, 0);
    if (more){
      cav = nav;
      cbv0 = nbv0; cbv1 = nbv1; cbv2 = nbv2; cbv3 = nbv3;
      cbv4 = nbv4; cbv5 = nbv5; cbv6 = nbv6;
    }
  }
  #pragma unroll
  for (int nt=0;nt<7;++nt)
    #pragma unroll
    for (int reg=0;reg<4;++reg)
      red[wv][lane][nt*4+reg] = acc[nt][reg];
  __syncthreads();
  for (int idx = tid; idx < 448; idx += 256){
    int imgl = idx / 112, j = idx - imgl*112;
    if (j >= 100) continue;
    int l = j & 15;
    int c = (j >> 4)*4 + imgl;
    float s = red[0][l][c] + red[1][l][c] + red[2][l][c] + red[3][l][c] + fc1b[j];
    x1s[imgl][j] = s > 0.f ? s : 0.f;
  }
  __syncthreads();
  const int g = wv, l64 = lane;
  const int img = ib + img0 + g;
  if (l64 < 50){
    float s = fb2[l64];
    #pragma unroll 4
    for (int k = 0; k < 100; ++k) s = fmaf(x1s[g][k], fW2[k*50+l64], s);
    h2s[g][l64] = s > 0.f ? s : 0.f;
  }
  __syncthreads();
  if (l64 < 10){
    float s = fb3[l64];
    #pragma unroll
    for (int k = 0; k < 50; ++k) s = fmaf(h2s[g][k], fW3[k*10+l64], s);
    h3s[g][l64] = s > 0.f ? s : 0.f;
  }
  __syncthreads();
  if (l64 == 0){
    float s = fb4[0];
    #pragma unroll
    for (int k = 0; k < 10; ++k) s = fmaf(h3s[g][k], fW4[k], s);
    stg[g] = s;
  }
  __syncthreads();
  if (l64 < 12){
    float s0v = stg[g], dd = dist[img], sp = speed[img];
    float s = ab1[l64] + s0v*aW1[l64] + dd*aW1[12+l64] + sp*aW1[24+l64];
    hb1[g][l64] = s > 0.f ? s : 0.f;
  }
  __syncthreads();
  if (l64 < 24){
    float s = ab2[l64];
    #pragma unroll
    for (int k=0;k<12;++k) s = fmaf(hb1[g][k], aW2[k*24+l64], s);
    hb2[g][l64] = s > 0.f ? s : 0.f;
  }
  __syncthreads();
  if (l64 < 4){
    float s = ab3[l64];
    #pragma unroll
    for (int k=0;k<24;++k) s = fmaf(hb2[g][k], aW3[k*4+l64], s);
    out[(size_t)img*4 + l64] = s;
  }
}

// ================================================================ host
extern "C" void kernel_launch(void* const* d_in, const int* in_sizes, int n_in,
                              void* d_out, int out_size, void* d_ws, size_t ws_size,
                              hipStream_t stream){
  const float* rgb   = (const float*)d_in[0];
  const float* dist  = (const float*)d_in[1];
  const float* speed = (const float*)d_in[2];
  const float* cw1 = (const float*)d_in[3];
  const float* cb1 = (const float*)d_in[4];
  const float* cw2 = (const float*)d_in[5];
  const float* cb2 = (const float*)d_in[6];
  const float* cw3 = (const float*)d_in[7];
  const float* cb3 = (const float*)d_in[8];
  const float* cw4 = (const float*)d_in[9];
  const float* cb4 = (const float*)d_in[10];
  const float* fW1 = (const float*)d_in[11];
  const float* fb1 = (const float*)d_in[12];
  const float* fW2 = (const float*)d_in[13];
  const float* fb2 = (const float*)d_in[14];
  const float* fW3 = (const float*)d_in[15];
  const float* fb3 = (const float*)d_in[16];
  const float* fW4 = (const float*)d_in[17];
  const float* fb4 = (const float*)d_in[18];
  const float* aW1 = (const float*)d_in[19];
  const float* ab1 = (const float*)d_in[20];
  const float* aW2 = (const float*)d_in[21];
  const float* ab2 = (const float*)d_in[22];
  const float* aW3 = (const float*)d_in[23];
  const float* ab3 = (const float*)d_in[24];
  float* out = (float*)d_out;
  const int B = in_sizes[0] / 15000;

  auto ALN = [](size_t x){ return (x + 255) & ~(size_t)255; };
  const size_t fixed = ALN(2048) + ALN(58368) + ALN(89088) + ALN(57344) + ALN(1146880);

  int nc = 1;
  while (nc < 32){
    size_t Bc = (size_t)(B / nc);
    size_t need = fixed + ALN(Bc*54144) + ALN(Bc*10240);
    if (need <= ws_size) break;
    nc *= 2;
  }
  const int Bc = B / nc;

  char* ws = (char*)d_ws;
  size_t o = 0;
  auto alloc = [&](size_t bytes)->char*{ char* p = ws + o; o += ALN(bytes); return p; };
  f16* w1c = (f16*)alloc(2048);
  f16* w2c = (f16*)alloc(58368);
  f16* w3m = (f16*)alloc(89088);
  f16* w4m = (f16*)alloc(57344);
  f16* w1m = (f16*)alloc(1146880);
  f16* a2  = (f16*)alloc((size_t)Bc*54144);
  f16* a4  = (f16*)alloc((size_t)Bc*10240);

  repack_all_k<<<dim3(280), dim3(256), 0, stream>>>(w1c, w2c, w3m, w4m, w1m,
                                                    cw1, cw2, cw3, cw4, fW1);

  for (int c = 0; c < nc; ++c){
    const int ib = c*Bc;
    conv12_k<<<dim3(Bc*6),  dim3(256), 0, stream>>>(rgb, w1c, cb1, w2c, cb2, a2, ib);
    conv34_k<<<dim3(Bc*2),  dim3(256), 0, stream>>>(a2, w3m, cb3, w4m, cb4, a4);
    fc1tail_k<<<dim3(Bc/4), dim3(256), 0, stream>>>(a4, w1m, fb1, dist, speed,
        fW2, fb2, fW3, fb3, fW4, fb4, aW1, ab1, aW2, ab2, aW3, ab3, out, ib, Bc);
  }
}